// Round 7
// baseline (1639.769 us; speedup 1.0000x reference)
//
#include <hip/hip_runtime.h>
#include <math.h>

#define B_ 32
#define N_ 4096

typedef __attribute__((ext_vector_type(8))) short short8;
typedef __attribute__((ext_vector_type(4))) float f32x4;

// fp32 -> bf16 round-to-nearest-even, and split x = hi + lo (both bf16).
__device__ __forceinline__ unsigned short f2bf(float f) {
    unsigned u = __float_as_uint(f);
    unsigned r = 0x7FFFu + ((u >> 16) & 1u);
    return (unsigned short)((u + r) >> 16);
}
__device__ __forceinline__ float bf2f(unsigned short h) {
    return __uint_as_float(((unsigned)h) << 16);
}
__device__ __forceinline__ void f2bfpair(float v, short& h, short& l) {
    unsigned short hh = f2bf(v);
    h = (short)hh;
    l = (short)f2bf(v - bf2f(hh));
}

// ---------------------------------------------------------------------------
// 5-field argmax payload reduction (max value, min index on tie), with the
// winning point's coordinates carried along so no LDS lookup is needed after.
// ---------------------------------------------------------------------------
template<int CTRL>
__device__ __forceinline__ void argmax5_dpp(float& bv, int& bi,
                                            float& bx, float& by, float& bz) {
    float ov = __int_as_float(__builtin_amdgcn_mov_dpp(__float_as_int(bv), CTRL, 0xf, 0xf, true));
    int   oi = __builtin_amdgcn_mov_dpp(bi, CTRL, 0xf, 0xf, true);
    float ox = __int_as_float(__builtin_amdgcn_mov_dpp(__float_as_int(bx), CTRL, 0xf, 0xf, true));
    float oy = __int_as_float(__builtin_amdgcn_mov_dpp(__float_as_int(by), CTRL, 0xf, 0xf, true));
    float oz = __int_as_float(__builtin_amdgcn_mov_dpp(__float_as_int(bz), CTRL, 0xf, 0xf, true));
    bool take = (ov > bv) || (ov == bv && oi < bi);
    bv = take ? ov : bv; bi = take ? oi : bi;
    bx = take ? ox : bx; by = take ? oy : by; bz = take ? oz : bz;
}
__device__ __forceinline__ void argmax5_xor(int off, float& bv, int& bi,
                                            float& bx, float& by, float& bz) {
    float ov = __shfl_xor(bv, off);
    int   oi = __shfl_xor(bi, off);
    float ox = __shfl_xor(bx, off);
    float oy = __shfl_xor(by, off);
    float oz = __shfl_xor(bz, off);
    bool take = (ov > bv) || (ov == bv && oi < bi);
    bv = take ? ov : bv; bi = take ? oi : bi;
    bx = take ? ox : bx; by = take ? oy : by; bz = take ? oz : bz;
}
__device__ __forceinline__ void wave_argmax5(float& bv, int& bi,
                                             float& bx, float& by, float& bz) {
    argmax5_dpp<0x128>(bv, bi, bx, by, bz);   // row_ror:8
    argmax5_dpp<0x124>(bv, bi, bx, by, bz);   // row_ror:4
    argmax5_dpp<0x122>(bv, bi, bx, by, bz);   // row_ror:2
    argmax5_dpp<0x121>(bv, bi, bx, by, bz);   // row_ror:1
    argmax5_xor(16, bv, bi, bx, by, bz);
    argmax5_xor(32, bv, bi, bx, by, bz);
}

// ---------------------------------------------------------------------------
// FPS v3: exact fp32 math (index-critical), zero LDS for points, barrier-free
// cross-wave exchange (parity-double-buffered slots + tag polling; wave lag
// is provably <=1 iteration so 2 buffers suffice). Winner coords carried in
// the reduction payload -> no dependent xs[last] load.
// ---------------------------------------------------------------------------
template<int N, int NPOINT, int NT>
__global__ __launch_bounds__(NT, 1) void fps_kernel(
    const float* __restrict__ xyz,
    int* __restrict__ outIdx,
    float* __restrict__ outXyz) {
#pragma clang fp contract(off)
    const int b = blockIdx.x;
    const int t = threadIdx.x;
    constexpr int PPT = N / NT;
    constexpr int NW = NT / 64;
    const int lane = t & 63, wv = t >> 6;
    const float* base = xyz + (size_t)b * N * 3;
    float px[PPT], py[PPT], pz[PPT], mind[PPT];
#pragma unroll
    for (int i = 0; i < PPT; i++) {
        const int p = t + i * NT;
        px[i] = base[p * 3 + 0];
        py[i] = base[p * 3 + 1];
        pz[i] = base[p * 3 + 2];
        mind[i] = 1e10f;
    }
#pragma unroll
    for (int i = 0; i < PPT; i++)
        asm volatile("" : "+v"(px[i]), "+v"(py[i]), "+v"(pz[i]));
    // exchange slots: [parity][wave][field]; fields 0..4 payload, 7 tag
    __shared__ int slab[2][NW][8];
    if constexpr (NW > 1) {
        if (t < 2 * NW) ((int*)slab)[t * 8 + 7] = 0;
        __syncthreads();
    }
    float lx = base[0], ly = base[1], lz = base[2];
    if (t == 0) {
        outIdx[b * NPOINT] = 0;
        outXyz[(size_t)b * NPOINT * 3 + 0] = lx;
        outXyz[(size_t)b * NPOINT * 3 + 1] = ly;
        outXyz[(size_t)b * NPOINT * 3 + 2] = lz;
    }
    for (int it = 1; it < NPOINT; it++) {
        float bv = -1.0f; int bi = 0;
        float bx = 0.f, by = 0.f, bz = 0.f;
#pragma unroll
        for (int i = 0; i < PPT; i++) {
            float dx = px[i] - lx, dy = py[i] - ly, dz = pz[i] - lz;
            float t0 = dx * dx, t1 = dy * dy, t2 = dz * dz;
            float d = (t0 + t1) + t2;
            float m = fminf(mind[i], d);
            mind[i] = m;
            bool take = (m > bv);           // ascending p => first-max kept
            bv = take ? m : bv;
            bi = take ? (t + i * NT) : bi;
            bx = take ? px[i] : bx;
            by = take ? py[i] : by;
            bz = take ? pz[i] : bz;
        }
        wave_argmax5(bv, bi, bx, by, bz);
        if constexpr (NW > 1) {
            const int par = it & 1;
            if (lane == 0) {
                slab[par][wv][0] = __float_as_int(bv);
                slab[par][wv][1] = bi;
                slab[par][wv][2] = __float_as_int(bx);
                slab[par][wv][3] = __float_as_int(by);
                slab[par][wv][4] = __float_as_int(bz);
                __threadfence_block();
                ((volatile int*)&slab[par][wv][7])[0] = it;
            }
            // poll all tags (uniform across lanes)
            for (;;) {
                bool ok = true;
#pragma unroll
                for (int w = 0; w < NW; w++)
                    ok &= (((volatile int*)&slab[par][w][7])[0] == it);
                if (ok) break;
            }
            asm volatile("" ::: "memory");
            float fv = __int_as_float(slab[par][0][0]);
            int   fi = slab[par][0][1];
            float fx = __int_as_float(slab[par][0][2]);
            float fy = __int_as_float(slab[par][0][3]);
            float fz = __int_as_float(slab[par][0][4]);
#pragma unroll
            for (int w = 1; w < NW; w++) {
                float ov = __int_as_float(slab[par][w][0]);
                int   oi = slab[par][w][1];
                bool take = (ov > fv) || (ov == fv && oi < fi);
                if (take) {
                    fv = ov; fi = oi;
                    fx = __int_as_float(slab[par][w][2]);
                    fy = __int_as_float(slab[par][w][3]);
                    fz = __int_as_float(slab[par][w][4]);
                }
            }
            lx = fx; ly = fy; lz = fz;
            if (t == 0) {
                outIdx[b * NPOINT + it] = fi;
                outXyz[((size_t)b * NPOINT + it) * 3 + 0] = fx;
                outXyz[((size_t)b * NPOINT + it) * 3 + 1] = fy;
                outXyz[((size_t)b * NPOINT + it) * 3 + 2] = fz;
            }
        } else {
            lx = bx; ly = by; lz = bz;
            if (t == 0) {
                outIdx[b * NPOINT + it] = bi;
                outXyz[((size_t)b * NPOINT + it) * 3 + 0] = bx;
                outXyz[((size_t)b * NPOINT + it) * 3 + 1] = by;
                outXyz[((size_t)b * NPOINT + it) * 3 + 2] = bz;
            }
        }
    }
}

// ---------------------------------------------------------------------------
// Ball query: wave-per-query (ballot/mbcnt), exact fp32 math.
// ---------------------------------------------------------------------------
template<int N, int NS>
__global__ __launch_bounds__(256) void ballquery_kernel(
    const float* __restrict__ xyz, const float* __restrict__ newXyz,
    int* __restrict__ outIdx, int S, float r2) {
#pragma clang fp contract(off)
    const int qid = blockIdx.x * 4 + (threadIdx.x >> 6);
    const int lane = threadIdx.x & 63;
    const int b = qid / S;
    const float* q = newXyz + (size_t)qid * 3;
    const float qx = q[0], qy = q[1], qz = q[2];
    const float qn = (qx * qx + qy * qy) + qz * qz;
    const float* base = xyz + (size_t)b * N * 3;
    int* dst = outIdx + (size_t)qid * NS;
    int cnt = 0, first = 0;
    for (int p0 = 0; p0 < N; p0 += 64) {
        const int p = p0 + lane;
        const float x = base[p * 3 + 0];
        const float y = base[p * 3 + 1];
        const float z = base[p * 3 + 2];
        const float pn = (x * x + y * y) + z * z;
        const float dot = (qx * x + qy * y) + qz * z;
        const float sqd = (qn + pn) - 2.0f * dot;
        const unsigned long long mask = __ballot(sqd <= r2);
        if (mask) {
            if (cnt == 0) first = p0 + __ffsll((unsigned long long)mask) - 1;
            const int prefix = __builtin_amdgcn_mbcnt_hi(
                (unsigned)(mask >> 32),
                __builtin_amdgcn_mbcnt_lo((unsigned)mask, 0));
            const bool in = (mask >> lane) & 1ull;
            const int pos = cnt + prefix;
            if (in && pos < NS) dst[pos] = p;
            cnt += __popcll(mask);
            if (cnt >= NS) break;
        }
    }
    for (int i = cnt + lane; i < NS; i += 64) dst[i] = first;
}

// ---------------------------------------------------------------------------
// Weight prep (merged): split 8 fp32 [R][C] mats into bf16 hi/lo [R][Cp].
// ---------------------------------------------------------------------------
struct WDesc { const float* src; short* dh; short* dl; int R, C, Cp, blk0; };
struct WDescs { WDesc d[8]; };

__global__ void wprep_all_kernel(WDescs W) {
    const int blk = blockIdx.x;
    int di = 0;
#pragma unroll
    for (int k = 1; k < 8; k++) di = (blk >= W.d[k].blk0) ? k : di;
    const WDesc D = W.d[di];
    const int i = (blk - D.blk0) * 256 + threadIdx.x;
    if (i >= D.R * D.Cp) return;
    const int r = i / D.Cp, c = i % D.Cp;
    float v = (c < D.C) ? D.src[r * D.C + c] : 0.f;
    short h, l;
    f2bfpair(v, h, l);
    D.dh[i] = h; D.dl[i] = l;
}

// ---------------------------------------------------------------------------
// MFMA helpers (verified gfx950 16x16x32 bf16 layouts).
// Split fp32 = hi+lo bf16: D += Ah*Bh + Ah*Bl + Al*Bh
// ---------------------------------------------------------------------------
template<int NT, int KS>
__device__ __forceinline__ void mfma_layer(
    const short* Aph, const short* Apl, const int sA,
    const short* __restrict__ Wph, const short* __restrict__ Wpl, const int sW,
    f32x4* acc, const int n0, const int mh, const int lr, const int lq) {
#pragma unroll
    for (int ks = 0; ks < KS; ks++) {
        const int ka = ks * 32 + lq * 8;
        short8 a_h[2], a_l[2];
#pragma unroll
        for (int mt = 0; mt < 2; mt++) {
            const int m = (mh * 2 + mt) * 16 + lr;
            a_h[mt] = *(const short8*)(Aph + m * sA + ka);
            a_l[mt] = *(const short8*)(Apl + m * sA + ka);
        }
#pragma unroll
        for (int nt = 0; nt < NT; nt++) {
            const int n = n0 + nt * 16 + lr;
            short8 b_h = *(const short8*)(Wph + (size_t)n * sW + ka);
            short8 b_l = *(const short8*)(Wpl + (size_t)n * sW + ka);
#pragma unroll
            for (int mt = 0; mt < 2; mt++) {
                f32x4 c = acc[mt * NT + nt];
                c = __builtin_amdgcn_mfma_f32_16x16x32_bf16(a_h[mt], b_h, c, 0, 0, 0);
                c = __builtin_amdgcn_mfma_f32_16x16x32_bf16(a_h[mt], b_l, c, 0, 0, 0);
                c = __builtin_amdgcn_mfma_f32_16x16x32_bf16(a_l[mt], b_h, c, 0, 0, 0);
                acc[mt * NT + nt] = c;
            }
        }
    }
}

template<int NT>
__device__ __forceinline__ void init_bias(f32x4* acc, const float* __restrict__ bias,
                                          const int n0, const int lr) {
#pragma unroll
    for (int nt = 0; nt < NT; nt++) {
        float bv = bias[n0 + nt * 16 + lr];
        f32x4 c = {bv, bv, bv, bv};
        acc[0 * NT + nt] = c;
        acc[1 * NT + nt] = c;
    }
}

template<int NT>
__device__ __forceinline__ void store_split(
    const f32x4* acc, short* Hp, short* Lp, const int stride,
    const int n0, const int mh, const int lr, const int lq) {
#pragma unroll
    for (int mt = 0; mt < 2; mt++)
#pragma unroll
        for (int nt = 0; nt < NT; nt++)
#pragma unroll
            for (int r = 0; r < 4; r++) {
                float v = fmaxf(acc[mt * NT + nt][r], 0.f);
                short h, l;
                f2bfpair(v, h, l);
                const int m = (mh * 2 + mt) * 16 + lq * 4 + r;
                const int n = n0 + nt * 16 + lr;
                Hp[m * stride + n] = h;
                Lp[m * stride + n] = l;
            }
}

// ---------------------------------------------------------------------------
// SA1 MFMA (unchanged)
// ---------------------------------------------------------------------------
#define T1 72
__global__ __launch_bounds__(256) void sa1_mfma_kernel(
    const float* __restrict__ x, const float* __restrict__ nxyz1,
    const int* __restrict__ idx,
    const float* __restrict__ w0, const float* __restrict__ b0,
    const short* __restrict__ w1h, const short* __restrict__ w1l,
    const float* __restrict__ b1,
    const short* __restrict__ w2h, const short* __restrict__ w2l,
    const float* __restrict__ b2,
    float* __restrict__ feat1) {
    const int g0 = blockIdx.x * 2;
    const int b = g0 >> 9;
    const int t = threadIdx.x;
    const int lane = t & 63, wv = t >> 6;
    const int lr = lane & 15, lq = lane >> 4;
    const int mh = wv & 1, nh = wv >> 1;
    __shared__ float gx[64][4];
    __shared__ short H1h[64 * T1], H1l[64 * T1];
    __shared__ short H2h[64 * T1], H2l[64 * T1];
    if (t < 64) {
        int g = g0 + (t >> 5);
        int id = idx[(size_t)g * 32 + (t & 31)];
        const float* pp = x + ((size_t)b * N_ + id) * 3;
        const float* cc = nxyz1 + (size_t)g * 3;
        gx[t][0] = pp[0] - cc[0];
        gx[t][1] = pp[1] - cc[1];
        gx[t][2] = pp[2] - cc[2];
    }
    __syncthreads();
    {   // layer1 K=3 via VALU
        const int m = t >> 2, oc = (t & 3) * 16;
        float a0 = gx[m][0], a1 = gx[m][1], a2 = gx[m][2];
        short8 hv0, hv1, lv0, lv1;
#pragma unroll
        for (int i = 0; i < 16; i++) {
            int o = oc + i;
            float v = fmaf(w0[o * 3 + 0], a0,
                      fmaf(w0[o * 3 + 1], a1,
                      fmaf(w0[o * 3 + 2], a2, b0[o])));
            v = fmaxf(v, 0.f);
            short h, l;
            f2bfpair(v, h, l);
            if (i < 8) { hv0[i] = h; lv0[i] = l; }
            else       { hv1[i - 8] = h; lv1[i - 8] = l; }
        }
        *(short8*)&H1h[m * T1 + oc]     = hv0;
        *(short8*)&H1h[m * T1 + oc + 8] = hv1;
        *(short8*)&H1l[m * T1 + oc]     = lv0;
        *(short8*)&H1l[m * T1 + oc + 8] = lv1;
    }
    __syncthreads();
    {   // layer2: K=64, N=64
        f32x4 acc[4];
        init_bias<2>(acc, b1, nh * 32, lr);
        mfma_layer<2, 2>(H1h, H1l, T1, w1h, w1l, 64, acc, nh * 32, mh, lr, lq);
        store_split<2>(acc, H2h, H2l, T1, nh * 32, mh, lr, lq);
    }
    __syncthreads();
    {   // layer3: K=64, N=128 + per-group max
        f32x4 acc[8];
        init_bias<4>(acc, b2, nh * 64, lr);
        mfma_layer<4, 2>(H2h, H2l, T1, w2h, w2l, 64, acc, nh * 64, mh, lr, lq);
#pragma unroll
        for (int nt = 0; nt < 4; nt++) {
            float v = 0.f;
#pragma unroll
            for (int mt = 0; mt < 2; mt++)
#pragma unroll
                for (int r = 0; r < 4; r++)
                    v = fmaxf(v, acc[mt * 4 + nt][r]);
            v = fmaxf(v, __shfl_xor(v, 16));
            v = fmaxf(v, __shfl_xor(v, 32));
            if (lane < 16)
                feat1[(size_t)(g0 + mh) * 128 + nh * 64 + nt * 16 + lane] = v;
        }
    }
}

// ---------------------------------------------------------------------------
// SA2 MFMA (unchanged)
// ---------------------------------------------------------------------------
#define S1 168
#define S2 136
__global__ __launch_bounds__(256) void sa2_mfma_kernel(
    const float* __restrict__ xyz1, const float* __restrict__ feat1,
    const float* __restrict__ newXyz, const int* __restrict__ idx,
    const short* __restrict__ w0h, const short* __restrict__ w0l,
    const float* __restrict__ b0,
    const short* __restrict__ w1h, const short* __restrict__ w1l,
    const float* __restrict__ b1,
    const short* __restrict__ w2h, const short* __restrict__ w2l,
    const float* __restrict__ b2,
    float* __restrict__ feat2) {
    const int g = blockIdx.x;
    const int b = g >> 7;
    const int t = threadIdx.x;
    const int lane = t & 63, wv = t >> 6;
    const int lr = lane & 15, lq = lane >> 4;
    const int mh = wv & 1, nh = wv >> 1;
    __shared__ short Ah[64 * S1], Al[64 * S1];
    __shared__ short Hh[64 * S2], Hl[64 * S2];
    __shared__ float pmax[2][256];
    __shared__ int ids[64];
    if (t < 64) ids[t] = idx[(size_t)g * 64 + t];
    __syncthreads();
    {
        const int m = t >> 2, q = t & 3, k0 = q * 40;
        const int id = ids[m];
        const float* frow = feat1 + ((size_t)b * 512 + id) * 128;
        const float* prow = xyz1 + ((size_t)b * 512 + id) * 3;
        const float* crow = newXyz + (size_t)g * 3;
#pragma unroll
        for (int c8 = 0; c8 < 5; c8++) {
            short8 hv, lv;
#pragma unroll
            for (int j = 0; j < 8; j++) {
                int k = k0 + c8 * 8 + j;
                float v = 0.f;
                if (k < 3) v = prow[k] - crow[k];
                else if (k < 131) v = frow[k - 3];
                short h, l;
                f2bfpair(v, h, l);
                hv[j] = h; lv[j] = l;
            }
            *(short8*)&Ah[m * S1 + k0 + c8 * 8] = hv;
            *(short8*)&Al[m * S1 + k0 + c8 * 8] = lv;
        }
    }
    __syncthreads();
    {   // layer1: K=160, N=128
        f32x4 acc[8];
        init_bias<4>(acc, b0, nh * 64, lr);
        mfma_layer<4, 5>(Ah, Al, S1, w0h, w0l, 160, acc, nh * 64, mh, lr, lq);
        store_split<4>(acc, Hh, Hl, S2, nh * 64, mh, lr, lq);
    }
    __syncthreads();
    {   // layer2: K=128, N=128
        f32x4 acc[8];
        init_bias<4>(acc, b1, nh * 64, lr);
        mfma_layer<4, 4>(Hh, Hl, S2, w1h, w1l, 128, acc, nh * 64, mh, lr, lq);
        store_split<4>(acc, Ah, Al, S2, nh * 64, mh, lr, lq);
    }
    __syncthreads();
    {   // layer3: K=128, N=256 + max over 64 rows
        f32x4 acc[16];
        init_bias<8>(acc, b2, nh * 128, lr);
        mfma_layer<8, 4>(Ah, Al, S2, w2h, w2l, 128, acc, nh * 128, mh, lr, lq);
#pragma unroll
        for (int nt = 0; nt < 8; nt++) {
            float v = 0.f;
#pragma unroll
            for (int mt = 0; mt < 2; mt++)
#pragma unroll
                for (int r = 0; r < 4; r++)
                    v = fmaxf(v, acc[mt * 8 + nt][r]);
            v = fmaxf(v, __shfl_xor(v, 16));
            v = fmaxf(v, __shfl_xor(v, 32));
            if (lane < 16) pmax[mh][nh * 128 + nt * 16 + lane] = v;
        }
    }
    __syncthreads();
    feat2[(size_t)g * 256 + t] = fmaxf(pmax[0][t], pmax[1][t]);
}

// ---------------------------------------------------------------------------
// concat [xyz2(3) | feat2(256) | zeros] -> A3 (4096 x 288, zero-padded K)
// ---------------------------------------------------------------------------
__global__ void concat3_kernel(const float* __restrict__ xyz2,
                               const float* __restrict__ feat2,
                               float* __restrict__ a3, int total) {
    int i = blockIdx.x * 256 + threadIdx.x;
    if (i >= total) return;
    int m = i / 288, c = i % 288;
    float v = 0.f;
    if (c < 3) v = xyz2[m * 3 + c];
    else if (c < 259) v = feat2[m * 256 + (c - 3)];
    a3[i] = v;
}

// ---------------------------------------------------------------------------
// MFMA GEMM (unchanged)
// ---------------------------------------------------------------------------
template<int RELU>
__global__ __launch_bounds__(256) void mfma_gemm_kernel(
    const float* __restrict__ A, const int Kp,
    const short* __restrict__ Wh, const short* __restrict__ Wl,
    const float* __restrict__ bias, float* __restrict__ out, const int N) {
    const int t = threadIdx.x;
    const int lane = t & 63, wv = t >> 6;
    const int lr = lane & 15, lq = lane >> 4;
    const int mh = wv & 1, nh = wv >> 1;
    const int m0 = blockIdx.y * 64;
    const int n0 = blockIdx.x * 128 + nh * 64;
    __shared__ short Ah[64 * 40], Al[64 * 40];
    f32x4 acc[8];
#pragma unroll
    for (int nt = 0; nt < 4; nt++) {
        float bv = bias[n0 + nt * 16 + lr];
        f32x4 c = {bv, bv, bv, bv};
        acc[nt] = c; acc[4 + nt] = c;
    }
    const int srow = t >> 2, sk = (t & 3) * 8;
    for (int kt = 0; kt < Kp; kt += 32) {
        {
            const float* ap = A + (size_t)(m0 + srow) * Kp + kt + sk;
            short8 hv, lv;
#pragma unroll
            for (int j = 0; j < 8; j++) {
                short h, l;
                f2bfpair(ap[j], h, l);
                hv[j] = h; lv[j] = l;
            }
            *(short8*)&Ah[srow * 40 + sk] = hv;
            *(short8*)&Al[srow * 40 + sk] = lv;
        }
        __syncthreads();
        short8 a_h[2], a_l[2];
#pragma unroll
        for (int mt = 0; mt < 2; mt++) {
            const int m = mh * 32 + mt * 16 + lr;
            a_h[mt] = *(const short8*)&Ah[m * 40 + lq * 8];
            a_l[mt] = *(const short8*)&Al[m * 40 + lq * 8];
        }
#pragma unroll
        for (int nt = 0; nt < 4; nt++) {
            const int n = n0 + nt * 16 + lr;
            short8 b_h = *(const short8*)(Wh + (size_t)n * Kp + kt + lq * 8);
            short8 b_l = *(const short8*)(Wl + (size_t)n * Kp + kt + lq * 8);
#pragma unroll
            for (int mt = 0; mt < 2; mt++) {
                f32x4 c = acc[mt * 4 + nt];
                c = __builtin_amdgcn_mfma_f32_16x16x32_bf16(a_h[mt], b_h, c, 0, 0, 0);
                c = __builtin_amdgcn_mfma_f32_16x16x32_bf16(a_h[mt], b_l, c, 0, 0, 0);
                c = __builtin_amdgcn_mfma_f32_16x16x32_bf16(a_l[mt], b_h, c, 0, 0, 0);
                acc[mt * 4 + nt] = c;
            }
        }
        __syncthreads();
    }
#pragma unroll
    for (int mt = 0; mt < 2; mt++)
#pragma unroll
        for (int nt = 0; nt < 4; nt++)
#pragma unroll
            for (int r = 0; r < 4; r++) {
                const int m = m0 + mh * 32 + mt * 16 + lq * 4 + r;
                const int n = n0 + nt * 16 + lr;
                float v = acc[mt * 4 + nt][r];
                if (RELU) v = fmaxf(v, 0.f);
                out[(size_t)m * N + n] = v;
            }
}

// ---------------------------------------------------------------------------
// max over 128 points: (32,128,1024) -> (32,1024)
// ---------------------------------------------------------------------------
__global__ void maxpool_kernel(const float* __restrict__ in,
                               float* __restrict__ out) {
    int b = blockIdx.x, t = threadIdx.x;
#pragma unroll
    for (int j = 0; j < 4; j++) {
        int o = t + j * 256;
        float m = -INFINITY;
        for (int k = 0; k < 128; k++)
            m = fmaxf(m, in[((size_t)b * 128 + k) * 1024 + o]);
        out[b * 1024 + o] = m;
    }
}

// ---------------------------------------------------------------------------
// FC layer: grid (O/(4*OPW), B), block 256.
// ---------------------------------------------------------------------------
template<int K, int OPW, int ACT>
__global__ __launch_bounds__(256) void fc_kernel(
    const float* __restrict__ in, const float* __restrict__ w,
    const float* __restrict__ bias, float* __restrict__ out, const int O) {
    const int batch = blockIdx.y;
    const int t = threadIdx.x, lane = t & 63, wv = t >> 6;
    __shared__ float f[K];
    for (int j = t; j < K; j += 256) f[j] = in[batch * K + j];
    __syncthreads();
    const int o0 = blockIdx.x * (4 * OPW) + wv * OPW;
#pragma unroll
    for (int i = 0; i < OPW; i++) {
        const int o = o0 + i;
        const float* wr = w + (size_t)o * K;
        float a = 0.f;
#pragma unroll
        for (int c = lane; c < K; c += 64) a = fmaf(wr[c], f[c], a);
#pragma unroll
        for (int off = 32; off > 0; off >>= 1) a += __shfl_xor(a, off);
        if (lane == 0) {
            float v = a + bias[o];
            out[batch * O + o] = ACT ? fmaxf(v, 0.f) : v;
        }
    }
}

// fc3 (256->40) + softmax fused; one block per batch.
__global__ __launch_bounds__(256) void fc3_softmax_kernel(
    const float* __restrict__ in, const float* __restrict__ w3,
    const float* __restrict__ b3, float* __restrict__ out) {
    const int b = blockIdx.x, t = threadIdx.x, lane = t & 63, wv = t >> 6;
    __shared__ float f[256];
    __shared__ float lg[40];
    f[t] = in[b * 256 + t];
    __syncthreads();
#pragma unroll
    for (int i = 0; i < 10; i++) {
        const int o = wv * 10 + i;
        const float* wr = w3 + (size_t)o * 256;
        float a = 0.f;
#pragma unroll
        for (int c = lane; c < 256; c += 64) a = fmaf(wr[c], f[c], a);
#pragma unroll
        for (int off = 32; off > 0; off >>= 1) a += __shfl_xor(a, off);
        if (lane == 0) lg[o] = a + b3[o];
    }
    __syncthreads();
    if (t < 64) {
        float v = (t < 40) ? lg[t] : -INFINITY;
        float m = v;
#pragma unroll
        for (int off = 32; off > 0; off >>= 1) m = fmaxf(m, __shfl_xor(m, off));
        float e = (t < 40) ? expf(v - m) : 0.f;
        float s = e;
#pragma unroll
        for (int off = 32; off > 0; off >>= 1) s += __shfl_xor(s, off);
        if (t < 40) out[b * 40 + t] = e / s;
    }
}

// ---------------------------------------------------------------------------
extern "C" void kernel_launch(void* const* d_in, const int* in_sizes, int n_in,
                              void* d_out, int out_size, void* d_ws, size_t ws_size,
                              hipStream_t stream) {
    (void)in_sizes; (void)n_in; (void)out_size; (void)ws_size;
    const float* x      = (const float*)d_in[0];
    const float* sa1w0  = (const float*)d_in[1];
    const float* sa1b0  = (const float*)d_in[2];
    const float* sa1w1  = (const float*)d_in[3];
    const float* sa1b1  = (const float*)d_in[4];
    const float* sa1w2  = (const float*)d_in[5];
    const float* sa1b2  = (const float*)d_in[6];
    const float* sa2w0  = (const float*)d_in[7];
    const float* sa2b0  = (const float*)d_in[8];
    const float* sa2w1  = (const float*)d_in[9];
    const float* sa2b1  = (const float*)d_in[10];
    const float* sa2w2  = (const float*)d_in[11];
    const float* sa2b2  = (const float*)d_in[12];
    const float* sa3w0  = (const float*)d_in[13];
    const float* sa3b0  = (const float*)d_in[14];
    const float* sa3w1  = (const float*)d_in[15];
    const float* sa3b1  = (const float*)d_in[16];
    const float* sa3w2  = (const float*)d_in[17];
    const float* sa3b2  = (const float*)d_in[18];
    const float* fc1w   = (const float*)d_in[19];
    const float* fc1b   = (const float*)d_in[20];
    const float* fc2w   = (const float*)d_in[21];
    const float* fc2b   = (const float*)d_in[22];
    const float* fc3w   = (const float*)d_in[23];
    const float* fc3b   = (const float*)d_in[24];
    float* outp = (float*)d_out;

    char* ws = (char*)d_ws;
    size_t off = 0;
    auto alloc = [&](size_t bytes) {
        void* p = ws + off;
        off += (bytes + 255) & ~(size_t)255;
        return p;
    };
    int*   fidx1   = (int*)  alloc((size_t)B_ * 512 * 4);
    float* nxyz1   = (float*)alloc((size_t)B_ * 512 * 3 * 4);
    int*   idx1    = (int*)  alloc((size_t)B_ * 512 * 32 * 4);
    float* feat1   = (float*)alloc((size_t)B_ * 512 * 128 * 4);
    int*   fidx2   = (int*)  alloc((size_t)B_ * 128 * 4);
    float* nxyz2   = (float*)alloc((size_t)B_ * 128 * 3 * 4);
    int*   idx2    = (int*)  alloc((size_t)B_ * 128 * 64 * 4);
    float* feat2   = (float*)alloc((size_t)B_ * 128 * 256 * 4);
    float* a3      = (float*)alloc((size_t)4096 * 288 * 4);
    float* h3a     = (float*)alloc((size_t)4096 * 256 * 4);
    float* h3b     = (float*)alloc((size_t)4096 * 512 * 4);
    float* h3c     = (float*)alloc((size_t)4096 * 1024 * 4);
    float* gfeat   = (float*)alloc((size_t)B_ * 1024 * 4);
    float* h1      = (float*)alloc((size_t)B_ * 512 * 4);
    float* h2      = (float*)alloc((size_t)B_ * 256 * 4);
    // split-bf16 weight planes
    short* w1h_s1 = (short*)alloc((size_t)64 * 64 * 2);
    short* w1l_s1 = (short*)alloc((size_t)64 * 64 * 2);
    short* w2h_s1 = (short*)alloc((size_t)128 * 64 * 2);
    short* w2l_s1 = (short*)alloc((size_t)128 * 64 * 2);
    short* w0h_s2 = (short*)alloc((size_t)128 * 160 * 2);
    short* w0l_s2 = (short*)alloc((size_t)128 * 160 * 2);
    short* w1h_s2 = (short*)alloc((size_t)128 * 128 * 2);
    short* w1l_s2 = (short*)alloc((size_t)128 * 128 * 2);
    short* w2h_s2 = (short*)alloc((size_t)256 * 128 * 2);
    short* w2l_s2 = (short*)alloc((size_t)256 * 128 * 2);
    short* w0h_s3 = (short*)alloc((size_t)256 * 288 * 2);
    short* w0l_s3 = (short*)alloc((size_t)256 * 288 * 2);
    short* w1h_s3 = (short*)alloc((size_t)512 * 256 * 2);
    short* w1l_s3 = (short*)alloc((size_t)512 * 256 * 2);
    short* w2h_s3 = (short*)alloc((size_t)1024 * 512 * 2);
    short* w2l_s3 = (short*)alloc((size_t)1024 * 512 * 2);

    // merged weight prep (one launch)
    {
        WDescs W;
        const float* srcs[8] = {sa1w1, sa1w2, sa2w0, sa2w1, sa2w2, sa3w0, sa3w1, sa3w2};
        short* dhs[8] = {w1h_s1, w2h_s1, w0h_s2, w1h_s2, w2h_s2, w0h_s3, w1h_s3, w2h_s3};
        short* dls[8] = {w1l_s1, w2l_s1, w0l_s2, w1l_s2, w2l_s2, w0l_s3, w1l_s3, w2l_s3};
        int Rs[8]  = {64, 128, 128, 128, 256, 256, 512, 1024};
        int Cs[8]  = {64, 64, 131, 128, 128, 259, 256, 512};
        int Cps[8] = {64, 64, 160, 128, 128, 288, 256, 512};
        int blk = 0;
        for (int k = 0; k < 8; k++) {
            W.d[k] = {srcs[k], dhs[k], dls[k], Rs[k], Cs[k], Cps[k], blk};
            blk += (Rs[k] * Cps[k] + 255) / 256;
        }
        wprep_all_kernel<<<blk, 256, 0, stream>>>(W);
    }

    // SA1
    fps_kernel<4096, 512, 256><<<B_, 256, 0, stream>>>(x, fidx1, nxyz1);
    ballquery_kernel<4096, 32><<<B_ * 512 / 4, 256, 0, stream>>>(
        x, nxyz1, idx1, 512, 0.04f);
    sa1_mfma_kernel<<<B_ * 512 / 2, 256, 0, stream>>>(
        x, nxyz1, idx1, sa1w0, sa1b0,
        w1h_s1, w1l_s1, sa1b1, w2h_s1, w2l_s1, sa1b2, feat1);
    // SA2
    fps_kernel<512, 128, 64><<<B_, 64, 0, stream>>>(nxyz1, fidx2, nxyz2);
    ballquery_kernel<512, 64><<<B_ * 128 / 4, 256, 0, stream>>>(
        nxyz1, nxyz2, idx2, 128, 0.16f);
    sa2_mfma_kernel<<<B_ * 128, 256, 0, stream>>>(
        nxyz1, feat1, nxyz2, idx2,
        w0h_s2, w0l_s2, sa2b0, w1h_s2, w1l_s2, sa2b1, w2h_s2, w2l_s2, sa2b2,
        feat2);
    // SA3 (group-all): concat + 3 MFMA GEMMs + maxpool
    concat3_kernel<<<(4096 * 288 + 255) / 256, 256, 0, stream>>>(
        nxyz2, feat2, a3, 4096 * 288);
    mfma_gemm_kernel<1><<<dim3(2, 64), 256, 0, stream>>>(
        a3, 288, w0h_s3, w0l_s3, sa3b0, h3a, 256);
    mfma_gemm_kernel<1><<<dim3(4, 64), 256, 0, stream>>>(
        h3a, 256, w1h_s3, w1l_s3, sa3b1, h3b, 512);
    mfma_gemm_kernel<1><<<dim3(8, 64), 256, 0, stream>>>(
        h3b, 512, w2h_s3, w2l_s3, sa3b2, h3c, 1024);
    maxpool_kernel<<<B_, 256, 0, stream>>>(h3c, gfeat);
    // FC head: fc1 (1024->512), fc2 (512->256), fc3+softmax
    fc_kernel<1024, 16, 1><<<dim3(8, B_), 256, 0, stream>>>(
        gfeat, fc1w, fc1b, h1, 512);
    fc_kernel<512, 16, 1><<<dim3(4, B_), 256, 0, stream>>>(
        h1, fc2w, fc2b, h2, 256);
    fc3_softmax_kernel<<<B_, 256, 0, stream>>>(h2, fc3w, fc3b, outp);
}

// Round 8
// 1468.494 us; speedup vs baseline: 1.1166x; 1.1166x over previous
//
#include <hip/hip_runtime.h>
#include <math.h>

#define B_ 32
#define N_ 4096

typedef __attribute__((ext_vector_type(8))) short short8;
typedef __attribute__((ext_vector_type(4))) float f32x4;

// fp32 -> bf16 round-to-nearest-even, and split x = hi + lo (both bf16).
__device__ __forceinline__ unsigned short f2bf(float f) {
    unsigned u = __float_as_uint(f);
    unsigned r = 0x7FFFu + ((u >> 16) & 1u);
    return (unsigned short)((u + r) >> 16);
}
__device__ __forceinline__ float bf2f(unsigned short h) {
    return __uint_as_float(((unsigned)h) << 16);
}
__device__ __forceinline__ void f2bfpair(float v, short& h, short& l) {
    unsigned short hh = f2bf(v);
    h = (short)hh;
    l = (short)f2bf(v - bf2f(hh));
}

// ---------------------------------------------------------------------------
// Wave argmax (max value, min index on tie): 4 DPP row_ror stages + 2 swizzle
// R7 lesson: keep the payload minimal (2 fields); 5-field payload carry and
// volatile-poll exchange both REGRESSED (751 vs 508 us) — s_barrier is cheap.
// ---------------------------------------------------------------------------
#define DPP_ARGMAX(ctrl)                                                      \
    {                                                                         \
        float ov = __int_as_float(__builtin_amdgcn_mov_dpp(                   \
            __float_as_int(bv), ctrl, 0xf, 0xf, true));                       \
        int oi = __builtin_amdgcn_mov_dpp(bi, ctrl, 0xf, 0xf, true);          \
        if (ov > bv || (ov == bv && oi < bi)) { bv = ov; bi = oi; }           \
    }

__device__ __forceinline__ void wave_argmax(float& bv, int& bi) {
    DPP_ARGMAX(0x128)   // row_ror:8
    DPP_ARGMAX(0x124)   // row_ror:4
    DPP_ARGMAX(0x122)   // row_ror:2
    DPP_ARGMAX(0x121)   // row_ror:1
#pragma unroll
    for (int off = 16; off <= 32; off <<= 1) {
        float ov = __shfl_xor(bv, off);
        int   oi = __shfl_xor(bi, off);
        if (ov > bv || (ov == bv && oi < bi)) { bv = ov; bi = oi; }
    }
}

// ---------------------------------------------------------------------------
// FPS (R6 structure, NT=128): one block per batch, exact fp32 math.
// One barrier per iteration (parity-double-buffered candidate slots).
// NT=128: exchange latency (barrier skew + slot scan) dominates over VALU
// issue, so fewer waves to synchronize beats fewer points per thread.
// ---------------------------------------------------------------------------
template<int N, int NPOINT, int NT>
__global__ __launch_bounds__(NT, 1) void fps_kernel(
    const float* __restrict__ xyz,
    int* __restrict__ outIdx,
    float* __restrict__ outXyz) {
#pragma clang fp contract(off)
    const int b = blockIdx.x;
    const int t = threadIdx.x;
    constexpr int PPT = N / NT;
    constexpr int NW = (NT + 63) / 64;
    __shared__ float xs[N], ys[N], zs[N];
    __shared__ float redV[2][NW];
    __shared__ int   redI[2][NW];
    __shared__ int   fidxS[NPOINT];
    const float* base = xyz + (size_t)b * N * 3;
    for (int j = t; j < N; j += NT) {
        xs[j] = base[j * 3 + 0];
        ys[j] = base[j * 3 + 1];
        zs[j] = base[j * 3 + 2];
    }
    __syncthreads();
    float px[PPT], py[PPT], pz[PPT], mind[PPT];
#pragma unroll
    for (int i = 0; i < PPT; i++) {
        int p = t + i * NT;
        px[i] = xs[p]; py[i] = ys[p]; pz[i] = zs[p];
        mind[i] = 1e10f;
    }
    // pin coordinate arrays in VGPRs (opaque to remat)
#pragma unroll
    for (int i = 0; i < PPT; i++)
        asm volatile("" : "+v"(px[i]), "+v"(py[i]), "+v"(pz[i]));
    if (t == 0) fidxS[0] = 0;
    int last = 0;
    for (int it = 1; it < NPOINT; it++) {
        float lx = xs[last], ly = ys[last], lz = zs[last];
        float bv = -1.0f; int bi = 0;
#pragma unroll
        for (int i = 0; i < PPT; i++) {
            float dx = px[i] - lx, dy = py[i] - ly, dz = pz[i] - lz;
            float t0 = dx * dx, t1 = dy * dy, t2 = dz * dz;
            float d = (t0 + t1) + t2;
            float m = fminf(mind[i], d);
            mind[i] = m;
            int p = t + i * NT;
            if (m > bv) { bv = m; bi = p; }   // ascending p => first-max kept
        }
        wave_argmax(bv, bi);
        if constexpr (NT > 64) {
            const int par = it & 1;
            if ((t & 63) == 0) { redV[par][t >> 6] = bv; redI[par][t >> 6] = bi; }
            __syncthreads();
            float fv = redV[par][0]; int fi = redI[par][0];
#pragma unroll
            for (int w = 1; w < NW; w++) {
                float ov = redV[par][w]; int oi = redI[par][w];
                if (ov > fv || (ov == fv && oi < fi)) { fv = ov; fi = oi; }
            }
            last = fi;
            if (t == 0) fidxS[it] = fi;
        } else {
            last = bi;
            if (t == 0) fidxS[it] = bi;
        }
    }
    __syncthreads();
    for (int s = t; s < NPOINT; s += NT) {
        int id = fidxS[s];
        outIdx[b * NPOINT + s] = id;
        outXyz[(b * NPOINT + s) * 3 + 0] = xs[id];
        outXyz[(b * NPOINT + s) * 3 + 1] = ys[id];
        outXyz[(b * NPOINT + s) * 3 + 2] = zs[id];
    }
}

// ---------------------------------------------------------------------------
// Ball query: wave-per-query (ballot/mbcnt), exact fp32 math.
// ---------------------------------------------------------------------------
template<int N, int NS>
__global__ __launch_bounds__(256) void ballquery_kernel(
    const float* __restrict__ xyz, const float* __restrict__ newXyz,
    int* __restrict__ outIdx, int S, float r2) {
#pragma clang fp contract(off)
    const int qid = blockIdx.x * 4 + (threadIdx.x >> 6);
    const int lane = threadIdx.x & 63;
    const int b = qid / S;
    const float* q = newXyz + (size_t)qid * 3;
    const float qx = q[0], qy = q[1], qz = q[2];
    const float qn = (qx * qx + qy * qy) + qz * qz;
    const float* base = xyz + (size_t)b * N * 3;
    int* dst = outIdx + (size_t)qid * NS;
    int cnt = 0, first = 0;
    for (int p0 = 0; p0 < N; p0 += 64) {
        const int p = p0 + lane;
        const float x = base[p * 3 + 0];
        const float y = base[p * 3 + 1];
        const float z = base[p * 3 + 2];
        const float pn = (x * x + y * y) + z * z;
        const float dot = (qx * x + qy * y) + qz * z;
        const float sqd = (qn + pn) - 2.0f * dot;
        const unsigned long long mask = __ballot(sqd <= r2);
        if (mask) {
            if (cnt == 0) first = p0 + __ffsll((unsigned long long)mask) - 1;
            const int prefix = __builtin_amdgcn_mbcnt_hi(
                (unsigned)(mask >> 32),
                __builtin_amdgcn_mbcnt_lo((unsigned)mask, 0));
            const bool in = (mask >> lane) & 1ull;
            const int pos = cnt + prefix;
            if (in && pos < NS) dst[pos] = p;
            cnt += __popcll(mask);
            if (cnt >= NS) break;
        }
    }
    for (int i = cnt + lane; i < NS; i += 64) dst[i] = first;
}

// ---------------------------------------------------------------------------
// Weight prep (merged): split 8 fp32 [R][C] mats into bf16 hi/lo [R][Cp].
// ---------------------------------------------------------------------------
struct WDesc { const float* src; short* dh; short* dl; int R, C, Cp, blk0; };
struct WDescs { WDesc d[8]; };

__global__ void wprep_all_kernel(WDescs W) {
    const int blk = blockIdx.x;
    int di = 0;
#pragma unroll
    for (int k = 1; k < 8; k++) di = (blk >= W.d[k].blk0) ? k : di;
    const WDesc D = W.d[di];
    const int i = (blk - D.blk0) * 256 + threadIdx.x;
    if (i >= D.R * D.Cp) return;
    const int r = i / D.Cp, c = i % D.Cp;
    float v = (c < D.C) ? D.src[r * D.C + c] : 0.f;
    short h, l;
    f2bfpair(v, h, l);
    D.dh[i] = h; D.dl[i] = l;
}

// ---------------------------------------------------------------------------
// MFMA helpers (verified gfx950 16x16x32 bf16 layouts).
// Split fp32 = hi+lo bf16: D += Ah*Bh + Ah*Bl + Al*Bh
// ---------------------------------------------------------------------------
template<int NT, int KS>
__device__ __forceinline__ void mfma_layer(
    const short* Aph, const short* Apl, const int sA,
    const short* __restrict__ Wph, const short* __restrict__ Wpl, const int sW,
    f32x4* acc, const int n0, const int mh, const int lr, const int lq) {
#pragma unroll
    for (int ks = 0; ks < KS; ks++) {
        const int ka = ks * 32 + lq * 8;
        short8 a_h[2], a_l[2];
#pragma unroll
        for (int mt = 0; mt < 2; mt++) {
            const int m = (mh * 2 + mt) * 16 + lr;
            a_h[mt] = *(const short8*)(Aph + m * sA + ka);
            a_l[mt] = *(const short8*)(Apl + m * sA + ka);
        }
#pragma unroll
        for (int nt = 0; nt < NT; nt++) {
            const int n = n0 + nt * 16 + lr;
            short8 b_h = *(const short8*)(Wph + (size_t)n * sW + ka);
            short8 b_l = *(const short8*)(Wpl + (size_t)n * sW + ka);
#pragma unroll
            for (int mt = 0; mt < 2; mt++) {
                f32x4 c = acc[mt * NT + nt];
                c = __builtin_amdgcn_mfma_f32_16x16x32_bf16(a_h[mt], b_h, c, 0, 0, 0);
                c = __builtin_amdgcn_mfma_f32_16x16x32_bf16(a_h[mt], b_l, c, 0, 0, 0);
                c = __builtin_amdgcn_mfma_f32_16x16x32_bf16(a_l[mt], b_h, c, 0, 0, 0);
                acc[mt * NT + nt] = c;
            }
        }
    }
}

template<int NT>
__device__ __forceinline__ void init_bias(f32x4* acc, const float* __restrict__ bias,
                                          const int n0, const int lr) {
#pragma unroll
    for (int nt = 0; nt < NT; nt++) {
        float bv = bias[n0 + nt * 16 + lr];
        f32x4 c = {bv, bv, bv, bv};
        acc[0 * NT + nt] = c;
        acc[1 * NT + nt] = c;
    }
}

template<int NT>
__device__ __forceinline__ void store_split(
    const f32x4* acc, short* Hp, short* Lp, const int stride,
    const int n0, const int mh, const int lr, const int lq) {
#pragma unroll
    for (int mt = 0; mt < 2; mt++)
#pragma unroll
        for (int nt = 0; nt < NT; nt++)
#pragma unroll
            for (int r = 0; r < 4; r++) {
                float v = fmaxf(acc[mt * NT + nt][r], 0.f);
                short h, l;
                f2bfpair(v, h, l);
                const int m = (mh * 2 + mt) * 16 + lq * 4 + r;
                const int n = n0 + nt * 16 + lr;
                Hp[m * stride + n] = h;
                Lp[m * stride + n] = l;
            }
}

// ---------------------------------------------------------------------------
// SA1 MFMA (unchanged)
// ---------------------------------------------------------------------------
#define T1 72
__global__ __launch_bounds__(256) void sa1_mfma_kernel(
    const float* __restrict__ x, const float* __restrict__ nxyz1,
    const int* __restrict__ idx,
    const float* __restrict__ w0, const float* __restrict__ b0,
    const short* __restrict__ w1h, const short* __restrict__ w1l,
    const float* __restrict__ b1,
    const short* __restrict__ w2h, const short* __restrict__ w2l,
    const float* __restrict__ b2,
    float* __restrict__ feat1) {
    const int g0 = blockIdx.x * 2;
    const int b = g0 >> 9;
    const int t = threadIdx.x;
    const int lane = t & 63, wv = t >> 6;
    const int lr = lane & 15, lq = lane >> 4;
    const int mh = wv & 1, nh = wv >> 1;
    __shared__ float gx[64][4];
    __shared__ short H1h[64 * T1], H1l[64 * T1];
    __shared__ short H2h[64 * T1], H2l[64 * T1];
    if (t < 64) {
        int g = g0 + (t >> 5);
        int id = idx[(size_t)g * 32 + (t & 31)];
        const float* pp = x + ((size_t)b * N_ + id) * 3;
        const float* cc = nxyz1 + (size_t)g * 3;
        gx[t][0] = pp[0] - cc[0];
        gx[t][1] = pp[1] - cc[1];
        gx[t][2] = pp[2] - cc[2];
    }
    __syncthreads();
    {   // layer1 K=3 via VALU
        const int m = t >> 2, oc = (t & 3) * 16;
        float a0 = gx[m][0], a1 = gx[m][1], a2 = gx[m][2];
        short8 hv0, hv1, lv0, lv1;
#pragma unroll
        for (int i = 0; i < 16; i++) {
            int o = oc + i;
            float v = fmaf(w0[o * 3 + 0], a0,
                      fmaf(w0[o * 3 + 1], a1,
                      fmaf(w0[o * 3 + 2], a2, b0[o])));
            v = fmaxf(v, 0.f);
            short h, l;
            f2bfpair(v, h, l);
            if (i < 8) { hv0[i] = h; lv0[i] = l; }
            else       { hv1[i - 8] = h; lv1[i - 8] = l; }
        }
        *(short8*)&H1h[m * T1 + oc]     = hv0;
        *(short8*)&H1h[m * T1 + oc + 8] = hv1;
        *(short8*)&H1l[m * T1 + oc]     = lv0;
        *(short8*)&H1l[m * T1 + oc + 8] = lv1;
    }
    __syncthreads();
    {   // layer2: K=64, N=64
        f32x4 acc[4];
        init_bias<2>(acc, b1, nh * 32, lr);
        mfma_layer<2, 2>(H1h, H1l, T1, w1h, w1l, 64, acc, nh * 32, mh, lr, lq);
        store_split<2>(acc, H2h, H2l, T1, nh * 32, mh, lr, lq);
    }
    __syncthreads();
    {   // layer3: K=64, N=128 + per-group max
        f32x4 acc[8];
        init_bias<4>(acc, b2, nh * 64, lr);
        mfma_layer<4, 2>(H2h, H2l, T1, w2h, w2l, 64, acc, nh * 64, mh, lr, lq);
#pragma unroll
        for (int nt = 0; nt < 4; nt++) {
            float v = 0.f;
#pragma unroll
            for (int mt = 0; mt < 2; mt++)
#pragma unroll
                for (int r = 0; r < 4; r++)
                    v = fmaxf(v, acc[mt * 4 + nt][r]);
            v = fmaxf(v, __shfl_xor(v, 16));
            v = fmaxf(v, __shfl_xor(v, 32));
            if (lane < 16)
                feat1[(size_t)(g0 + mh) * 128 + nh * 64 + nt * 16 + lane] = v;
        }
    }
}

// ---------------------------------------------------------------------------
// SA2 MFMA (unchanged)
// ---------------------------------------------------------------------------
#define S1 168
#define S2 136
__global__ __launch_bounds__(256) void sa2_mfma_kernel(
    const float* __restrict__ xyz1, const float* __restrict__ feat1,
    const float* __restrict__ newXyz, const int* __restrict__ idx,
    const short* __restrict__ w0h, const short* __restrict__ w0l,
    const float* __restrict__ b0,
    const short* __restrict__ w1h, const short* __restrict__ w1l,
    const float* __restrict__ b1,
    const short* __restrict__ w2h, const short* __restrict__ w2l,
    const float* __restrict__ b2,
    float* __restrict__ feat2) {
    const int g = blockIdx.x;
    const int b = g >> 7;
    const int t = threadIdx.x;
    const int lane = t & 63, wv = t >> 6;
    const int lr = lane & 15, lq = lane >> 4;
    const int mh = wv & 1, nh = wv >> 1;
    __shared__ short Ah[64 * S1], Al[64 * S1];
    __shared__ short Hh[64 * S2], Hl[64 * S2];
    __shared__ float pmax[2][256];
    __shared__ int ids[64];
    if (t < 64) ids[t] = idx[(size_t)g * 64 + t];
    __syncthreads();
    {
        const int m = t >> 2, q = t & 3, k0 = q * 40;
        const int id = ids[m];
        const float* frow = feat1 + ((size_t)b * 512 + id) * 128;
        const float* prow = xyz1 + ((size_t)b * 512 + id) * 3;
        const float* crow = newXyz + (size_t)g * 3;
#pragma unroll
        for (int c8 = 0; c8 < 5; c8++) {
            short8 hv, lv;
#pragma unroll
            for (int j = 0; j < 8; j++) {
                int k = k0 + c8 * 8 + j;
                float v = 0.f;
                if (k < 3) v = prow[k] - crow[k];
                else if (k < 131) v = frow[k - 3];
                short h, l;
                f2bfpair(v, h, l);
                hv[j] = h; lv[j] = l;
            }
            *(short8*)&Ah[m * S1 + k0 + c8 * 8] = hv;
            *(short8*)&Al[m * S1 + k0 + c8 * 8] = lv;
        }
    }
    __syncthreads();
    {   // layer1: K=160, N=128
        f32x4 acc[8];
        init_bias<4>(acc, b0, nh * 64, lr);
        mfma_layer<4, 5>(Ah, Al, S1, w0h, w0l, 160, acc, nh * 64, mh, lr, lq);
        store_split<4>(acc, Hh, Hl, S2, nh * 64, mh, lr, lq);
    }
    __syncthreads();
    {   // layer2: K=128, N=128
        f32x4 acc[8];
        init_bias<4>(acc, b1, nh * 64, lr);
        mfma_layer<4, 4>(Hh, Hl, S2, w1h, w1l, 128, acc, nh * 64, mh, lr, lq);
        store_split<4>(acc, Ah, Al, S2, nh * 64, mh, lr, lq);
    }
    __syncthreads();
    {   // layer3: K=128, N=256 + max over 64 rows
        f32x4 acc[16];
        init_bias<8>(acc, b2, nh * 128, lr);
        mfma_layer<8, 4>(Ah, Al, S2, w2h, w2l, 128, acc, nh * 128, mh, lr, lq);
#pragma unroll
        for (int nt = 0; nt < 8; nt++) {
            float v = 0.f;
#pragma unroll
            for (int mt = 0; mt < 2; mt++)
#pragma unroll
                for (int r = 0; r < 4; r++)
                    v = fmaxf(v, acc[mt * 8 + nt][r]);
            v = fmaxf(v, __shfl_xor(v, 16));
            v = fmaxf(v, __shfl_xor(v, 32));
            if (lane < 16) pmax[mh][nh * 128 + nt * 16 + lane] = v;
        }
    }
    __syncthreads();
    feat2[(size_t)g * 256 + t] = fmaxf(pmax[0][t], pmax[1][t]);
}

// ---------------------------------------------------------------------------
// concat [xyz2(3) | feat2(256) | zeros] -> A3 (4096 x 288, zero-padded K)
// ---------------------------------------------------------------------------
__global__ void concat3_kernel(const float* __restrict__ xyz2,
                               const float* __restrict__ feat2,
                               float* __restrict__ a3, int total) {
    int i = blockIdx.x * 256 + threadIdx.x;
    if (i >= total) return;
    int m = i / 288, c = i % 288;
    float v = 0.f;
    if (c < 3) v = xyz2[m * 3 + c];
    else if (c < 259) v = feat2[m * 256 + (c - 3)];
    a3[i] = v;
}

// ---------------------------------------------------------------------------
// MFMA GEMM (unchanged)
// ---------------------------------------------------------------------------
template<int RELU>
__global__ __launch_bounds__(256) void mfma_gemm_kernel(
    const float* __restrict__ A, const int Kp,
    const short* __restrict__ Wh, const short* __restrict__ Wl,
    const float* __restrict__ bias, float* __restrict__ out, const int N) {
    const int t = threadIdx.x;
    const int lane = t & 63, wv = t >> 6;
    const int lr = lane & 15, lq = lane >> 4;
    const int mh = wv & 1, nh = wv >> 1;
    const int m0 = blockIdx.y * 64;
    const int n0 = blockIdx.x * 128 + nh * 64;
    __shared__ short Ah[64 * 40], Al[64 * 40];
    f32x4 acc[8];
#pragma unroll
    for (int nt = 0; nt < 4; nt++) {
        float bv = bias[n0 + nt * 16 + lr];
        f32x4 c = {bv, bv, bv, bv};
        acc[nt] = c; acc[4 + nt] = c;
    }
    const int srow = t >> 2, sk = (t & 3) * 8;
    for (int kt = 0; kt < Kp; kt += 32) {
        {
            const float* ap = A + (size_t)(m0 + srow) * Kp + kt + sk;
            short8 hv, lv;
#pragma unroll
            for (int j = 0; j < 8; j++) {
                short h, l;
                f2bfpair(ap[j], h, l);
                hv[j] = h; lv[j] = l;
            }
            *(short8*)&Ah[srow * 40 + sk] = hv;
            *(short8*)&Al[srow * 40 + sk] = lv;
        }
        __syncthreads();
        short8 a_h[2], a_l[2];
#pragma unroll
        for (int mt = 0; mt < 2; mt++) {
            const int m = mh * 32 + mt * 16 + lr;
            a_h[mt] = *(const short8*)&Ah[m * 40 + lq * 8];
            a_l[mt] = *(const short8*)&Al[m * 40 + lq * 8];
        }
#pragma unroll
        for (int nt = 0; nt < 4; nt++) {
            const int n = n0 + nt * 16 + lr;
            short8 b_h = *(const short8*)(Wh + (size_t)n * Kp + kt + lq * 8);
            short8 b_l = *(const short8*)(Wl + (size_t)n * Kp + kt + lq * 8);
#pragma unroll
            for (int mt = 0; mt < 2; mt++) {
                f32x4 c = acc[mt * 4 + nt];
                c = __builtin_amdgcn_mfma_f32_16x16x32_bf16(a_h[mt], b_h, c, 0, 0, 0);
                c = __builtin_amdgcn_mfma_f32_16x16x32_bf16(a_h[mt], b_l, c, 0, 0, 0);
                c = __builtin_amdgcn_mfma_f32_16x16x32_bf16(a_l[mt], b_h, c, 0, 0, 0);
                acc[mt * 4 + nt] = c;
            }
        }
        __syncthreads();
    }
#pragma unroll
    for (int mt = 0; mt < 2; mt++)
#pragma unroll
        for (int nt = 0; nt < 4; nt++)
#pragma unroll
            for (int r = 0; r < 4; r++) {
                const int m = m0 + mh * 32 + mt * 16 + lq * 4 + r;
                const int n = n0 + nt * 16 + lr;
                float v = acc[mt * 4 + nt][r];
                if (RELU) v = fmaxf(v, 0.f);
                out[(size_t)m * N + n] = v;
            }
}

// ---------------------------------------------------------------------------
// max over 128 points: (32,128,1024) -> (32,1024)
// ---------------------------------------------------------------------------
__global__ void maxpool_kernel(const float* __restrict__ in,
                               float* __restrict__ out) {
    int b = blockIdx.x, t = threadIdx.x;
#pragma unroll
    for (int j = 0; j < 4; j++) {
        int o = t + j * 256;
        float m = -INFINITY;
        for (int k = 0; k < 128; k++)
            m = fmaxf(m, in[((size_t)b * 128 + k) * 1024 + o]);
        out[b * 1024 + o] = m;
    }
}

// ---------------------------------------------------------------------------
// FC layer: grid (O/(4*OPW), B), block 256.
// ---------------------------------------------------------------------------
template<int K, int OPW, int ACT>
__global__ __launch_bounds__(256) void fc_kernel(
    const float* __restrict__ in, const float* __restrict__ w,
    const float* __restrict__ bias, float* __restrict__ out, const int O) {
    const int batch = blockIdx.y;
    const int t = threadIdx.x, lane = t & 63, wv = t >> 6;
    __shared__ float f[K];
    for (int j = t; j < K; j += 256) f[j] = in[batch * K + j];
    __syncthreads();
    const int o0 = blockIdx.x * (4 * OPW) + wv * OPW;
#pragma unroll
    for (int i = 0; i < OPW; i++) {
        const int o = o0 + i;
        const float* wr = w + (size_t)o * K;
        float a = 0.f;
#pragma unroll
        for (int c = lane; c < K; c += 64) a = fmaf(wr[c], f[c], a);
#pragma unroll
        for (int off = 32; off > 0; off >>= 1) a += __shfl_xor(a, off);
        if (lane == 0) {
            float v = a + bias[o];
            out[batch * O + o] = ACT ? fmaxf(v, 0.f) : v;
        }
    }
}

// fc3 (256->40) + softmax fused; one block per batch.
__global__ __launch_bounds__(256) void fc3_softmax_kernel(
    const float* __restrict__ in, const float* __restrict__ w3,
    const float* __restrict__ b3, float* __restrict__ out) {
    const int b = blockIdx.x, t = threadIdx.x, lane = t & 63, wv = t >> 6;
    __shared__ float f[256];
    __shared__ float lg[40];
    f[t] = in[b * 256 + t];
    __syncthreads();
#pragma unroll
    for (int i = 0; i < 10; i++) {
        const int o = wv * 10 + i;
        const float* wr = w3 + (size_t)o * 256;
        float a = 0.f;
#pragma unroll
        for (int c = lane; c < 256; c += 64) a = fmaf(wr[c], f[c], a);
#pragma unroll
        for (int off = 32; off > 0; off >>= 1) a += __shfl_xor(a, off);
        if (lane == 0) lg[o] = a + b3[o];
    }
    __syncthreads();
    if (t < 64) {
        float v = (t < 40) ? lg[t] : -INFINITY;
        float m = v;
#pragma unroll
        for (int off = 32; off > 0; off >>= 1) m = fmaxf(m, __shfl_xor(m, off));
        float e = (t < 40) ? expf(v - m) : 0.f;
        float s = e;
#pragma unroll
        for (int off = 32; off > 0; off >>= 1) s += __shfl_xor(s, off);
        if (t < 40) out[b * 40 + t] = e / s;
    }
}

// ---------------------------------------------------------------------------
extern "C" void kernel_launch(void* const* d_in, const int* in_sizes, int n_in,
                              void* d_out, int out_size, void* d_ws, size_t ws_size,
                              hipStream_t stream) {
    (void)in_sizes; (void)n_in; (void)out_size; (void)ws_size;
    const float* x      = (const float*)d_in[0];
    const float* sa1w0  = (const float*)d_in[1];
    const float* sa1b0  = (const float*)d_in[2];
    const float* sa1w1  = (const float*)d_in[3];
    const float* sa1b1  = (const float*)d_in[4];
    const float* sa1w2  = (const float*)d_in[5];
    const float* sa1b2  = (const float*)d_in[6];
    const float* sa2w0  = (const float*)d_in[7];
    const float* sa2b0  = (const float*)d_in[8];
    const float* sa2w1  = (const float*)d_in[9];
    const float* sa2b1  = (const float*)d_in[10];
    const float* sa2w2  = (const float*)d_in[11];
    const float* sa2b2  = (const float*)d_in[12];
    const float* sa3w0  = (const float*)d_in[13];
    const float* sa3b0  = (const float*)d_in[14];
    const float* sa3w1  = (const float*)d_in[15];
    const float* sa3b1  = (const float*)d_in[16];
    const float* sa3w2  = (const float*)d_in[17];
    const float* sa3b2  = (const float*)d_in[18];
    const float* fc1w   = (const float*)d_in[19];
    const float* fc1b   = (const float*)d_in[20];
    const float* fc2w   = (const float*)d_in[21];
    const float* fc2b   = (const float*)d_in[22];
    const float* fc3w   = (const float*)d_in[23];
    const float* fc3b   = (const float*)d_in[24];
    float* outp = (float*)d_out;

    char* ws = (char*)d_ws;
    size_t off = 0;
    auto alloc = [&](size_t bytes) {
        void* p = ws + off;
        off += (bytes + 255) & ~(size_t)255;
        return p;
    };
    int*   fidx1   = (int*)  alloc((size_t)B_ * 512 * 4);
    float* nxyz1   = (float*)alloc((size_t)B_ * 512 * 3 * 4);
    int*   idx1    = (int*)  alloc((size_t)B_ * 512 * 32 * 4);
    float* feat1   = (float*)alloc((size_t)B_ * 512 * 128 * 4);
    int*   fidx2   = (int*)  alloc((size_t)B_ * 128 * 4);
    float* nxyz2   = (float*)alloc((size_t)B_ * 128 * 3 * 4);
    int*   idx2    = (int*)  alloc((size_t)B_ * 128 * 64 * 4);
    float* feat2   = (float*)alloc((size_t)B_ * 128 * 256 * 4);
    float* a3      = (float*)alloc((size_t)4096 * 288 * 4);
    float* h3a     = (float*)alloc((size_t)4096 * 256 * 4);
    float* h3b     = (float*)alloc((size_t)4096 * 512 * 4);
    float* h3c     = (float*)alloc((size_t)4096 * 1024 * 4);
    float* gfeat   = (float*)alloc((size_t)B_ * 1024 * 4);
    float* h1      = (float*)alloc((size_t)B_ * 512 * 4);
    float* h2      = (float*)alloc((size_t)B_ * 256 * 4);
    // split-bf16 weight planes
    short* w1h_s1 = (short*)alloc((size_t)64 * 64 * 2);
    short* w1l_s1 = (short*)alloc((size_t)64 * 64 * 2);
    short* w2h_s1 = (short*)alloc((size_t)128 * 64 * 2);
    short* w2l_s1 = (short*)alloc((size_t)128 * 64 * 2);
    short* w0h_s2 = (short*)alloc((size_t)128 * 160 * 2);
    short* w0l_s2 = (short*)alloc((size_t)128 * 160 * 2);
    short* w1h_s2 = (short*)alloc((size_t)128 * 128 * 2);
    short* w1l_s2 = (short*)alloc((size_t)128 * 128 * 2);
    short* w2h_s2 = (short*)alloc((size_t)256 * 128 * 2);
    short* w2l_s2 = (short*)alloc((size_t)256 * 128 * 2);
    short* w0h_s3 = (short*)alloc((size_t)256 * 288 * 2);
    short* w0l_s3 = (short*)alloc((size_t)256 * 288 * 2);
    short* w1h_s3 = (short*)alloc((size_t)512 * 256 * 2);
    short* w1l_s3 = (short*)alloc((size_t)512 * 256 * 2);
    short* w2h_s3 = (short*)alloc((size_t)1024 * 512 * 2);
    short* w2l_s3 = (short*)alloc((size_t)1024 * 512 * 2);

    // merged weight prep (one launch)
    {
        WDescs W;
        const float* srcs[8] = {sa1w1, sa1w2, sa2w0, sa2w1, sa2w2, sa3w0, sa3w1, sa3w2};
        short* dhs[8] = {w1h_s1, w2h_s1, w0h_s2, w1h_s2, w2h_s2, w0h_s3, w1h_s3, w2h_s3};
        short* dls[8] = {w1l_s1, w2l_s1, w0l_s2, w1l_s2, w2l_s2, w0l_s3, w1l_s3, w2l_s3};
        int Rs[8]  = {64, 128, 128, 128, 256, 256, 512, 1024};
        int Cs[8]  = {64, 64, 131, 128, 128, 259, 256, 512};
        int Cps[8] = {64, 64, 160, 128, 128, 288, 256, 512};
        int blk = 0;
        for (int k = 0; k < 8; k++) {
            W.d[k] = {srcs[k], dhs[k], dls[k], Rs[k], Cs[k], Cps[k], blk};
            blk += (Rs[k] * Cps[k] + 255) / 256;
        }
        wprep_all_kernel<<<blk, 256, 0, stream>>>(W);
    }

    // SA1
    fps_kernel<4096, 512, 128><<<B_, 128, 0, stream>>>(x, fidx1, nxyz1);
    ballquery_kernel<4096, 32><<<B_ * 512 / 4, 256, 0, stream>>>(
        x, nxyz1, idx1, 512, 0.04f);
    sa1_mfma_kernel<<<B_ * 512 / 2, 256, 0, stream>>>(
        x, nxyz1, idx1, sa1w0, sa1b0,
        w1h_s1, w1l_s1, sa1b1, w2h_s1, w2l_s1, sa1b2, feat1);
    // SA2
    fps_kernel<512, 128, 64><<<B_, 64, 0, stream>>>(nxyz1, fidx2, nxyz2);
    ballquery_kernel<512, 64><<<B_ * 128 / 4, 256, 0, stream>>>(
        nxyz1, nxyz2, idx2, 128, 0.16f);
    sa2_mfma_kernel<<<B_ * 128, 256, 0, stream>>>(
        nxyz1, feat1, nxyz2, idx2,
        w0h_s2, w0l_s2, sa2b0, w1h_s2, w1l_s2, sa2b1, w2h_s2, w2l_s2, sa2b2,
        feat2);
    // SA3 (group-all): concat + 3 MFMA GEMMs + maxpool
    concat3_kernel<<<(4096 * 288 + 255) / 256, 256, 0, stream>>>(
        nxyz2, feat2, a3, 4096 * 288);
    mfma_gemm_kernel<1><<<dim3(2, 64), 256, 0, stream>>>(
        a3, 288, w0h_s3, w0l_s3, sa3b0, h3a, 256);
    mfma_gemm_kernel<1><<<dim3(4, 64), 256, 0, stream>>>(
        h3a, 256, w1h_s3, w1l_s3, sa3b1, h3b, 512);
    mfma_gemm_kernel<1><<<dim3(8, 64), 256, 0, stream>>>(
        h3b, 512, w2h_s3, w2l_s3, sa3b2, h3c, 1024);
    maxpool_kernel<<<B_, 256, 0, stream>>>(h3c, gfeat);
    // FC head: fc1 (1024->512), fc2 (512->256), fc3+softmax
    fc_kernel<1024, 16, 1><<<dim3(8, B_), 256, 0, stream>>>(
        gfeat, fc1w, fc1b, h1, 512);
    fc_kernel<512, 16, 1><<<dim3(4, B_), 256, 0, stream>>>(
        h1, fc2w, fc2b, h2, 256);
    fc3_softmax_kernel<<<B_, 256, 0, stream>>>(h2, fc3w, fc3b, outp);
}

// Round 9
// 1195.470 us; speedup vs baseline: 1.3717x; 1.2284x over previous
//
#include <hip/hip_runtime.h>
#include <math.h>

#define B_ 32
#define N_ 4096

typedef __attribute__((ext_vector_type(8))) short short8;
typedef __attribute__((ext_vector_type(4))) float f32x4;

// fp32 -> bf16 round-to-nearest-even, and split x = hi + lo (both bf16).
__device__ __forceinline__ unsigned short f2bf(float f) {
    unsigned u = __float_as_uint(f);
    unsigned r = 0x7FFFu + ((u >> 16) & 1u);
    return (unsigned short)((u + r) >> 16);
}
__device__ __forceinline__ float bf2f(unsigned short h) {
    return __uint_as_float(((unsigned)h) << 16);
}
__device__ __forceinline__ void f2bfpair(float v, short& h, short& l) {
    unsigned short hh = f2bf(v);
    h = (short)hh;
    l = (short)f2bf(v - bf2f(hh));
}

// ---------------------------------------------------------------------------
// Packed argmax: key = (float_bits(dist) << 32) | ~idx.  dist >= 0 so float
// bits are monotone as unsigned; u64 max picks max dist, min idx on tie —
// bit-identical to reference first-index argmax. R7/R8 lessons: minimal
// payload, s_barrier exchange, NT=256.
// ---------------------------------------------------------------------------
__device__ __forceinline__ unsigned long long u64max(unsigned long long a,
                                                     unsigned long long b) {
    return a > b ? a : b;
}
template<int CTRL>
__device__ __forceinline__ unsigned long long dpp_u64(unsigned long long k) {
    int lo = __builtin_amdgcn_mov_dpp((int)(unsigned)k, CTRL, 0xf, 0xf, true);
    int hi = __builtin_amdgcn_mov_dpp((int)(unsigned)(k >> 32), CTRL, 0xf, 0xf, true);
    return ((unsigned long long)(unsigned)hi << 32) | (unsigned)lo;
}
__device__ __forceinline__ unsigned long long wave_argmax_u64(unsigned long long key) {
    key = u64max(key, dpp_u64<0x128>(key));   // row_ror:8
    key = u64max(key, dpp_u64<0x124>(key));   // row_ror:4
    key = u64max(key, dpp_u64<0x122>(key));   // row_ror:2
    key = u64max(key, dpp_u64<0x121>(key));   // row_ror:1
    key = u64max(key, __shfl_xor(key, 16));
    key = u64max(key, __shfl_xor(key, 32));
    return key;
}

// ---------------------------------------------------------------------------
// FPS: one block per batch, exact fp32 math (index-critical). NT=256 (best
// measured), packed-u64 reduction, one barrier per iteration with parity
// double-buffered candidate slots. launch_bounds(NT,1)+asm pin: grid is only
// 32 blocks so occupancy can never exceed 1 block/CU; keep coords in VGPRs.
// ---------------------------------------------------------------------------
template<int N, int NPOINT, int NT>
__global__ __launch_bounds__(NT, 1) void fps_kernel(
    const float* __restrict__ xyz,
    int* __restrict__ outIdx,
    float* __restrict__ outXyz) {
#pragma clang fp contract(off)
    const int b = blockIdx.x;
    const int t = threadIdx.x;
    constexpr int PPT = N / NT;
    constexpr int NW = (NT + 63) / 64;
    __shared__ float xs[N], ys[N], zs[N];
    __shared__ unsigned long long red[2][NW];
    __shared__ int fidxS[NPOINT];
    const float* base = xyz + (size_t)b * N * 3;
    for (int j = t; j < N; j += NT) {
        xs[j] = base[j * 3 + 0];
        ys[j] = base[j * 3 + 1];
        zs[j] = base[j * 3 + 2];
    }
    __syncthreads();
    float px[PPT], py[PPT], pz[PPT], mind[PPT];
    unsigned notp[PPT];
#pragma unroll
    for (int i = 0; i < PPT; i++) {
        int p = t + i * NT;
        px[i] = xs[p]; py[i] = ys[p]; pz[i] = zs[p];
        mind[i] = 1e10f;
        notp[i] = ~(unsigned)p;
    }
    // pin coordinate arrays in VGPRs (opaque to remat)
#pragma unroll
    for (int i = 0; i < PPT; i++)
        asm volatile("" : "+v"(px[i]), "+v"(py[i]), "+v"(pz[i]));
    if (t == 0) fidxS[0] = 0;
    float lx = xs[0], ly = ys[0], lz = zs[0];
    for (int it = 1; it < NPOINT; it++) {
        unsigned long long key = 0;
#pragma unroll
        for (int i = 0; i < PPT; i++) {
            float dx = px[i] - lx, dy = py[i] - ly, dz = pz[i] - lz;
            float t0 = dx * dx, t1 = dy * dy, t2 = dz * dz;
            float d = (t0 + t1) + t2;
            float m = fminf(mind[i], d);
            mind[i] = m;
            unsigned long long k =
                ((unsigned long long)__float_as_uint(m) << 32) | notp[i];
            key = u64max(key, k);
        }
        key = wave_argmax_u64(key);
        int fi;
        if constexpr (NT > 64) {
            const int par = it & 1;
            if ((t & 63) == 0) red[par][t >> 6] = key;
            __syncthreads();
            unsigned long long best = red[par][0];
#pragma unroll
            for (int w = 1; w < NW; w++) best = u64max(best, red[par][w]);
            fi = (int)(~(unsigned)best);
        } else {
            fi = (int)(~(unsigned)key);
        }
        lx = xs[fi]; ly = ys[fi]; lz = zs[fi];
        if (t == 0) fidxS[it] = fi;
    }
    __syncthreads();
    for (int s = t; s < NPOINT; s += NT) {
        int id = fidxS[s];
        outIdx[b * NPOINT + s] = id;
        outXyz[(b * NPOINT + s) * 3 + 0] = xs[id];
        outXyz[(b * NPOINT + s) * 3 + 1] = ys[id];
        outXyz[(b * NPOINT + s) * 3 + 2] = zs[id];
    }
}

// ---------------------------------------------------------------------------
// Ball query: wave-per-query (ballot/mbcnt), exact fp32 math.
// ---------------------------------------------------------------------------
template<int N, int NS>
__global__ __launch_bounds__(256) void ballquery_kernel(
    const float* __restrict__ xyz, const float* __restrict__ newXyz,
    int* __restrict__ outIdx, int S, float r2) {
#pragma clang fp contract(off)
    const int qid = blockIdx.x * 4 + (threadIdx.x >> 6);
    const int lane = threadIdx.x & 63;
    const int b = qid / S;
    const float* q = newXyz + (size_t)qid * 3;
    const float qx = q[0], qy = q[1], qz = q[2];
    const float qn = (qx * qx + qy * qy) + qz * qz;
    const float* base = xyz + (size_t)b * N * 3;
    int* dst = outIdx + (size_t)qid * NS;
    int cnt = 0, first = 0;
    for (int p0 = 0; p0 < N; p0 += 64) {
        const int p = p0 + lane;
        const float x = base[p * 3 + 0];
        const float y = base[p * 3 + 1];
        const float z = base[p * 3 + 2];
        const float pn = (x * x + y * y) + z * z;
        const float dot = (qx * x + qy * y) + qz * z;
        const float sqd = (qn + pn) - 2.0f * dot;
        const unsigned long long mask = __ballot(sqd <= r2);
        if (mask) {
            if (cnt == 0) first = p0 + __ffsll((unsigned long long)mask) - 1;
            const int prefix = __builtin_amdgcn_mbcnt_hi(
                (unsigned)(mask >> 32),
                __builtin_amdgcn_mbcnt_lo((unsigned)mask, 0));
            const bool in = (mask >> lane) & 1ull;
            const int pos = cnt + prefix;
            if (in && pos < NS) dst[pos] = p;
            cnt += __popcll(mask);
            if (cnt >= NS) break;
        }
    }
    for (int i = cnt + lane; i < NS; i += 64) dst[i] = first;
}

// ---------------------------------------------------------------------------
// Weight prep (merged): split 8 fp32 [R][C] mats into bf16 hi/lo [R][Cp].
// ---------------------------------------------------------------------------
struct WDesc { const float* src; short* dh; short* dl; int R, C, Cp, blk0; };
struct WDescs { WDesc d[8]; };

__global__ void wprep_all_kernel(WDescs W) {
    const int blk = blockIdx.x;
    int di = 0;
#pragma unroll
    for (int k = 1; k < 8; k++) di = (blk >= W.d[k].blk0) ? k : di;
    const WDesc D = W.d[di];
    const int i = (blk - D.blk0) * 256 + threadIdx.x;
    if (i >= D.R * D.Cp) return;
    const int r = i / D.Cp, c = i % D.Cp;
    float v = (c < D.C) ? D.src[r * D.C + c] : 0.f;
    short h, l;
    f2bfpair(v, h, l);
    D.dh[i] = h; D.dl[i] = l;
}

// ---------------------------------------------------------------------------
// MFMA helpers (verified gfx950 16x16x32 bf16 layouts).
// Split fp32 = hi+lo bf16: D += Ah*Bh + Ah*Bl + Al*Bh
// ---------------------------------------------------------------------------
template<int NT, int KS>
__device__ __forceinline__ void mfma_layer(
    const short* Aph, const short* Apl, const int sA,
    const short* __restrict__ Wph, const short* __restrict__ Wpl, const int sW,
    f32x4* acc, const int n0, const int mh, const int lr, const int lq) {
#pragma unroll
    for (int ks = 0; ks < KS; ks++) {
        const int ka = ks * 32 + lq * 8;
        short8 a_h[2], a_l[2];
#pragma unroll
        for (int mt = 0; mt < 2; mt++) {
            const int m = (mh * 2 + mt) * 16 + lr;
            a_h[mt] = *(const short8*)(Aph + m * sA + ka);
            a_l[mt] = *(const short8*)(Apl + m * sA + ka);
        }
#pragma unroll
        for (int nt = 0; nt < NT; nt++) {
            const int n = n0 + nt * 16 + lr;
            short8 b_h = *(const short8*)(Wph + (size_t)n * sW + ka);
            short8 b_l = *(const short8*)(Wpl + (size_t)n * sW + ka);
#pragma unroll
            for (int mt = 0; mt < 2; mt++) {
                f32x4 c = acc[mt * NT + nt];
                c = __builtin_amdgcn_mfma_f32_16x16x32_bf16(a_h[mt], b_h, c, 0, 0, 0);
                c = __builtin_amdgcn_mfma_f32_16x16x32_bf16(a_h[mt], b_l, c, 0, 0, 0);
                c = __builtin_amdgcn_mfma_f32_16x16x32_bf16(a_l[mt], b_h, c, 0, 0, 0);
                acc[mt * NT + nt] = c;
            }
        }
    }
}

template<int NT>
__device__ __forceinline__ void init_bias(f32x4* acc, const float* __restrict__ bias,
                                          const int n0, const int lr) {
#pragma unroll
    for (int nt = 0; nt < NT; nt++) {
        float bv = bias[n0 + nt * 16 + lr];
        f32x4 c = {bv, bv, bv, bv};
        acc[0 * NT + nt] = c;
        acc[1 * NT + nt] = c;
    }
}

template<int NT>
__device__ __forceinline__ void store_split(
    const f32x4* acc, short* Hp, short* Lp, const int stride,
    const int n0, const int mh, const int lr, const int lq) {
#pragma unroll
    for (int mt = 0; mt < 2; mt++)
#pragma unroll
        for (int nt = 0; nt < NT; nt++)
#pragma unroll
            for (int r = 0; r < 4; r++) {
                float v = fmaxf(acc[mt * NT + nt][r], 0.f);
                short h, l;
                f2bfpair(v, h, l);
                const int m = (mh * 2 + mt) * 16 + lq * 4 + r;
                const int n = n0 + nt * 16 + lr;
                Hp[m * stride + n] = h;
                Lp[m * stride + n] = l;
            }
}

// ---------------------------------------------------------------------------
// SA1 MFMA (unchanged)
// ---------------------------------------------------------------------------
#define T1 72
__global__ __launch_bounds__(256) void sa1_mfma_kernel(
    const float* __restrict__ x, const float* __restrict__ nxyz1,
    const int* __restrict__ idx,
    const float* __restrict__ w0, const float* __restrict__ b0,
    const short* __restrict__ w1h, const short* __restrict__ w1l,
    const float* __restrict__ b1,
    const short* __restrict__ w2h, const short* __restrict__ w2l,
    const float* __restrict__ b2,
    float* __restrict__ feat1) {
    const int g0 = blockIdx.x * 2;
    const int b = g0 >> 9;
    const int t = threadIdx.x;
    const int lane = t & 63, wv = t >> 6;
    const int lr = lane & 15, lq = lane >> 4;
    const int mh = wv & 1, nh = wv >> 1;
    __shared__ float gx[64][4];
    __shared__ short H1h[64 * T1], H1l[64 * T1];
    __shared__ short H2h[64 * T1], H2l[64 * T1];
    if (t < 64) {
        int g = g0 + (t >> 5);
        int id = idx[(size_t)g * 32 + (t & 31)];
        const float* pp = x + ((size_t)b * N_ + id) * 3;
        const float* cc = nxyz1 + (size_t)g * 3;
        gx[t][0] = pp[0] - cc[0];
        gx[t][1] = pp[1] - cc[1];
        gx[t][2] = pp[2] - cc[2];
    }
    __syncthreads();
    {   // layer1 K=3 via VALU
        const int m = t >> 2, oc = (t & 3) * 16;
        float a0 = gx[m][0], a1 = gx[m][1], a2 = gx[m][2];
        short8 hv0, hv1, lv0, lv1;
#pragma unroll
        for (int i = 0; i < 16; i++) {
            int o = oc + i;
            float v = fmaf(w0[o * 3 + 0], a0,
                      fmaf(w0[o * 3 + 1], a1,
                      fmaf(w0[o * 3 + 2], a2, b0[o])));
            v = fmaxf(v, 0.f);
            short h, l;
            f2bfpair(v, h, l);
            if (i < 8) { hv0[i] = h; lv0[i] = l; }
            else       { hv1[i - 8] = h; lv1[i - 8] = l; }
        }
        *(short8*)&H1h[m * T1 + oc]     = hv0;
        *(short8*)&H1h[m * T1 + oc + 8] = hv1;
        *(short8*)&H1l[m * T1 + oc]     = lv0;
        *(short8*)&H1l[m * T1 + oc + 8] = lv1;
    }
    __syncthreads();
    {   // layer2: K=64, N=64
        f32x4 acc[4];
        init_bias<2>(acc, b1, nh * 32, lr);
        mfma_layer<2, 2>(H1h, H1l, T1, w1h, w1l, 64, acc, nh * 32, mh, lr, lq);
        store_split<2>(acc, H2h, H2l, T1, nh * 32, mh, lr, lq);
    }
    __syncthreads();
    {   // layer3: K=64, N=128 + per-group max
        f32x4 acc[8];
        init_bias<4>(acc, b2, nh * 64, lr);
        mfma_layer<4, 2>(H2h, H2l, T1, w2h, w2l, 64, acc, nh * 64, mh, lr, lq);
#pragma unroll
        for (int nt = 0; nt < 4; nt++) {
            float v = 0.f;
#pragma unroll
            for (int mt = 0; mt < 2; mt++)
#pragma unroll
                for (int r = 0; r < 4; r++)
                    v = fmaxf(v, acc[mt * 4 + nt][r]);
            v = fmaxf(v, __shfl_xor(v, 16));
            v = fmaxf(v, __shfl_xor(v, 32));
            if (lane < 16)
                feat1[(size_t)(g0 + mh) * 128 + nh * 64 + nt * 16 + lane] = v;
        }
    }
}

// ---------------------------------------------------------------------------
// SA2 MFMA (unchanged)
// ---------------------------------------------------------------------------
#define S1 168
#define S2 136
__global__ __launch_bounds__(256) void sa2_mfma_kernel(
    const float* __restrict__ xyz1, const float* __restrict__ feat1,
    const float* __restrict__ newXyz, const int* __restrict__ idx,
    const short* __restrict__ w0h, const short* __restrict__ w0l,
    const float* __restrict__ b0,
    const short* __restrict__ w1h, const short* __restrict__ w1l,
    const float* __restrict__ b1,
    const short* __restrict__ w2h, const short* __restrict__ w2l,
    const float* __restrict__ b2,
    float* __restrict__ feat2) {
    const int g = blockIdx.x;
    const int b = g >> 7;
    const int t = threadIdx.x;
    const int lane = t & 63, wv = t >> 6;
    const int lr = lane & 15, lq = lane >> 4;
    const int mh = wv & 1, nh = wv >> 1;
    __shared__ short Ah[64 * S1], Al[64 * S1];
    __shared__ short Hh[64 * S2], Hl[64 * S2];
    __shared__ float pmax[2][256];
    __shared__ int ids[64];
    if (t < 64) ids[t] = idx[(size_t)g * 64 + t];
    __syncthreads();
    {
        const int m = t >> 2, q = t & 3, k0 = q * 40;
        const int id = ids[m];
        const float* frow = feat1 + ((size_t)b * 512 + id) * 128;
        const float* prow = xyz1 + ((size_t)b * 512 + id) * 3;
        const float* crow = newXyz + (size_t)g * 3;
#pragma unroll
        for (int c8 = 0; c8 < 5; c8++) {
            short8 hv, lv;
#pragma unroll
            for (int j = 0; j < 8; j++) {
                int k = k0 + c8 * 8 + j;
                float v = 0.f;
                if (k < 3) v = prow[k] - crow[k];
                else if (k < 131) v = frow[k - 3];
                short h, l;
                f2bfpair(v, h, l);
                hv[j] = h; lv[j] = l;
            }
            *(short8*)&Ah[m * S1 + k0 + c8 * 8] = hv;
            *(short8*)&Al[m * S1 + k0 + c8 * 8] = lv;
        }
    }
    __syncthreads();
    {   // layer1: K=160, N=128
        f32x4 acc[8];
        init_bias<4>(acc, b0, nh * 64, lr);
        mfma_layer<4, 5>(Ah, Al, S1, w0h, w0l, 160, acc, nh * 64, mh, lr, lq);
        store_split<4>(acc, Hh, Hl, S2, nh * 64, mh, lr, lq);
    }
    __syncthreads();
    {   // layer2: K=128, N=128
        f32x4 acc[8];
        init_bias<4>(acc, b1, nh * 64, lr);
        mfma_layer<4, 4>(Hh, Hl, S2, w1h, w1l, 128, acc, nh * 64, mh, lr, lq);
        store_split<4>(acc, Ah, Al, S2, nh * 64, mh, lr, lq);
    }
    __syncthreads();
    {   // layer3: K=128, N=256 + max over 64 rows
        f32x4 acc[16];
        init_bias<8>(acc, b2, nh * 128, lr);
        mfma_layer<8, 4>(Ah, Al, S2, w2h, w2l, 128, acc, nh * 128, mh, lr, lq);
#pragma unroll
        for (int nt = 0; nt < 8; nt++) {
            float v = 0.f;
#pragma unroll
            for (int mt = 0; mt < 2; mt++)
#pragma unroll
                for (int r = 0; r < 4; r++)
                    v = fmaxf(v, acc[mt * 8 + nt][r]);
            v = fmaxf(v, __shfl_xor(v, 16));
            v = fmaxf(v, __shfl_xor(v, 32));
            if (lane < 16) pmax[mh][nh * 128 + nt * 16 + lane] = v;
        }
    }
    __syncthreads();
    feat2[(size_t)g * 256 + t] = fmaxf(pmax[0][t], pmax[1][t]);
}

// ---------------------------------------------------------------------------
// concat [xyz2(3) | feat2(256) | zeros] -> A3 (4096 x 288, zero-padded K)
// ---------------------------------------------------------------------------
__global__ void concat3_kernel(const float* __restrict__ xyz2,
                               const float* __restrict__ feat2,
                               float* __restrict__ a3, int total) {
    int i = blockIdx.x * 256 + threadIdx.x;
    if (i >= total) return;
    int m = i / 288, c = i % 288;
    float v = 0.f;
    if (c < 3) v = xyz2[m * 3 + c];
    else if (c < 259) v = feat2[m * 256 + (c - 3)];
    a3[i] = v;
}

// ---------------------------------------------------------------------------
// MFMA GEMM (unchanged)
// ---------------------------------------------------------------------------
template<int RELU>
__global__ __launch_bounds__(256) void mfma_gemm_kernel(
    const float* __restrict__ A, const int Kp,
    const short* __restrict__ Wh, const short* __restrict__ Wl,
    const float* __restrict__ bias, float* __restrict__ out, const int N) {
    const int t = threadIdx.x;
    const int lane = t & 63, wv = t >> 6;
    const int lr = lane & 15, lq = lane >> 4;
    const int mh = wv & 1, nh = wv >> 1;
    const int m0 = blockIdx.y * 64;
    const int n0 = blockIdx.x * 128 + nh * 64;
    __shared__ short Ah[64 * 40], Al[64 * 40];
    f32x4 acc[8];
#pragma unroll
    for (int nt = 0; nt < 4; nt++) {
        float bv = bias[n0 + nt * 16 + lr];
        f32x4 c = {bv, bv, bv, bv};
        acc[nt] = c; acc[4 + nt] = c;
    }
    const int srow = t >> 2, sk = (t & 3) * 8;
    for (int kt = 0; kt < Kp; kt += 32) {
        {
            const float* ap = A + (size_t)(m0 + srow) * Kp + kt + sk;
            short8 hv, lv;
#pragma unroll
            for (int j = 0; j < 8; j++) {
                short h, l;
                f2bfpair(ap[j], h, l);
                hv[j] = h; lv[j] = l;
            }
            *(short8*)&Ah[srow * 40 + sk] = hv;
            *(short8*)&Al[srow * 40 + sk] = lv;
        }
        __syncthreads();
        short8 a_h[2], a_l[2];
#pragma unroll
        for (int mt = 0; mt < 2; mt++) {
            const int m = mh * 32 + mt * 16 + lr;
            a_h[mt] = *(const short8*)&Ah[m * 40 + lq * 8];
            a_l[mt] = *(const short8*)&Al[m * 40 + lq * 8];
        }
#pragma unroll
        for (int nt = 0; nt < 4; nt++) {
            const int n = n0 + nt * 16 + lr;
            short8 b_h = *(const short8*)(Wh + (size_t)n * Kp + kt + lq * 8);
            short8 b_l = *(const short8*)(Wl + (size_t)n * Kp + kt + lq * 8);
#pragma unroll
            for (int mt = 0; mt < 2; mt++) {
                f32x4 c = acc[mt * 4 + nt];
                c = __builtin_amdgcn_mfma_f32_16x16x32_bf16(a_h[mt], b_h, c, 0, 0, 0);
                c = __builtin_amdgcn_mfma_f32_16x16x32_bf16(a_h[mt], b_l, c, 0, 0, 0);
                c = __builtin_amdgcn_mfma_f32_16x16x32_bf16(a_l[mt], b_h, c, 0, 0, 0);
                acc[mt * 4 + nt] = c;
            }
        }
        __syncthreads();
    }
#pragma unroll
    for (int mt = 0; mt < 2; mt++)
#pragma unroll
        for (int nt = 0; nt < 4; nt++)
#pragma unroll
            for (int r = 0; r < 4; r++) {
                const int m = m0 + mh * 32 + mt * 16 + lq * 4 + r;
                const int n = n0 + nt * 16 + lr;
                float v = acc[mt * 4 + nt][r];
                if (RELU) v = fmaxf(v, 0.f);
                out[(size_t)m * N + n] = v;
            }
}

// ---------------------------------------------------------------------------
// max over 128 points: (32,128,1024) -> (32,1024)
// ---------------------------------------------------------------------------
__global__ void maxpool_kernel(const float* __restrict__ in,
                               float* __restrict__ out) {
    int b = blockIdx.x, t = threadIdx.x;
#pragma unroll
    for (int j = 0; j < 4; j++) {
        int o = t + j * 256;
        float m = -INFINITY;
        for (int k = 0; k < 128; k++)
            m = fmaxf(m, in[((size_t)b * 128 + k) * 1024 + o]);
        out[b * 1024 + o] = m;
    }
}

// ---------------------------------------------------------------------------
// FC layer: grid (O/(4*OPW), B), block 256.
// ---------------------------------------------------------------------------
template<int K, int OPW, int ACT>
__global__ __launch_bounds__(256) void fc_kernel(
    const float* __restrict__ in, const float* __restrict__ w,
    const float* __restrict__ bias, float* __restrict__ out, const int O) {
    const int batch = blockIdx.y;
    const int t = threadIdx.x, lane = t & 63, wv = t >> 6;
    __shared__ float f[K];
    for (int j = t; j < K; j += 256) f[j] = in[batch * K + j];
    __syncthreads();
    const int o0 = blockIdx.x * (4 * OPW) + wv * OPW;
#pragma unroll
    for (int i = 0; i < OPW; i++) {
        const int o = o0 + i;
        const float* wr = w + (size_t)o * K;
        float a = 0.f;
#pragma unroll
        for (int c = lane; c < K; c += 64) a = fmaf(wr[c], f[c], a);
#pragma unroll
        for (int off = 32; off > 0; off >>= 1) a += __shfl_xor(a, off);
        if (lane == 0) {
            float v = a + bias[o];
            out[batch * O + o] = ACT ? fmaxf(v, 0.f) : v;
        }
    }
}

// fc3 (256->40) + softmax fused; one block per batch.
__global__ __launch_bounds__(256) void fc3_softmax_kernel(
    const float* __restrict__ in, const float* __restrict__ w3,
    const float* __restrict__ b3, float* __restrict__ out) {
    const int b = blockIdx.x, t = threadIdx.x, lane = t & 63, wv = t >> 6;
    __shared__ float f[256];
    __shared__ float lg[40];
    f[t] = in[b * 256 + t];
    __syncthreads();
#pragma unroll
    for (int i = 0; i < 10; i++) {
        const int o = wv * 10 + i;
        const float* wr = w3 + (size_t)o * 256;
        float a = 0.f;
#pragma unroll
        for (int c = lane; c < 256; c += 64) a = fmaf(wr[c], f[c], a);
#pragma unroll
        for (int off = 32; off > 0; off >>= 1) a += __shfl_xor(a, off);
        if (lane == 0) lg[o] = a + b3[o];
    }
    __syncthreads();
    if (t < 64) {
        float v = (t < 40) ? lg[t] : -INFINITY;
        float m = v;
#pragma unroll
        for (int off = 32; off > 0; off >>= 1) m = fmaxf(m, __shfl_xor(m, off));
        float e = (t < 40) ? expf(v - m) : 0.f;
        float s = e;
#pragma unroll
        for (int off = 32; off > 0; off >>= 1) s += __shfl_xor(s, off);
        if (t < 40) out[b * 40 + t] = e / s;
    }
}

// ---------------------------------------------------------------------------
extern "C" void kernel_launch(void* const* d_in, const int* in_sizes, int n_in,
                              void* d_out, int out_size, void* d_ws, size_t ws_size,
                              hipStream_t stream) {
    (void)in_sizes; (void)n_in; (void)out_size; (void)ws_size;
    const float* x      = (const float*)d_in[0];
    const float* sa1w0  = (const float*)d_in[1];
    const float* sa1b0  = (const float*)d_in[2];
    const float* sa1w1  = (const float*)d_in[3];
    const float* sa1b1  = (const float*)d_in[4];
    const float* sa1w2  = (const float*)d_in[5];
    const float* sa1b2  = (const float*)d_in[6];
    const float* sa2w0  = (const float*)d_in[7];
    const float* sa2b0  = (const float*)d_in[8];
    const float* sa2w1  = (const float*)d_in[9];
    const float* sa2b1  = (const float*)d_in[10];
    const float* sa2w2  = (const float*)d_in[11];
    const float* sa2b2  = (const float*)d_in[12];
    const float* sa3w0  = (const float*)d_in[13];
    const float* sa3b0  = (const float*)d_in[14];
    const float* sa3w1  = (const float*)d_in[15];
    const float* sa3b1  = (const float*)d_in[16];
    const float* sa3w2  = (const float*)d_in[17];
    const float* sa3b2  = (const float*)d_in[18];
    const float* fc1w   = (const float*)d_in[19];
    const float* fc1b   = (const float*)d_in[20];
    const float* fc2w   = (const float*)d_in[21];
    const float* fc2b   = (const float*)d_in[22];
    const float* fc3w   = (const float*)d_in[23];
    const float* fc3b   = (const float*)d_in[24];
    float* outp = (float*)d_out;

    char* ws = (char*)d_ws;
    size_t off = 0;
    auto alloc = [&](size_t bytes) {
        void* p = ws + off;
        off += (bytes + 255) & ~(size_t)255;
        return p;
    };
    int*   fidx1   = (int*)  alloc((size_t)B_ * 512 * 4);
    float* nxyz1   = (float*)alloc((size_t)B_ * 512 * 3 * 4);
    int*   idx1    = (int*)  alloc((size_t)B_ * 512 * 32 * 4);
    float* feat1   = (float*)alloc((size_t)B_ * 512 * 128 * 4);
    int*   fidx2   = (int*)  alloc((size_t)B_ * 128 * 4);
    float* nxyz2   = (float*)alloc((size_t)B_ * 128 * 3 * 4);
    int*   idx2    = (int*)  alloc((size_t)B_ * 128 * 64 * 4);
    float* feat2   = (float*)alloc((size_t)B_ * 128 * 256 * 4);
    float* a3      = (float*)alloc((size_t)4096 * 288 * 4);
    float* h3a     = (float*)alloc((size_t)4096 * 256 * 4);
    float* h3b     = (float*)alloc((size_t)4096 * 512 * 4);
    float* h3c     = (float*)alloc((size_t)4096 * 1024 * 4);
    float* gfeat   = (float*)alloc((size_t)B_ * 1024 * 4);
    float* h1      = (float*)alloc((size_t)B_ * 512 * 4);
    float* h2      = (float*)alloc((size_t)B_ * 256 * 4);
    // split-bf16 weight planes
    short* w1h_s1 = (short*)alloc((size_t)64 * 64 * 2);
    short* w1l_s1 = (short*)alloc((size_t)64 * 64 * 2);
    short* w2h_s1 = (short*)alloc((size_t)128 * 64 * 2);
    short* w2l_s1 = (short*)alloc((size_t)128 * 64 * 2);
    short* w0h_s2 = (short*)alloc((size_t)128 * 160 * 2);
    short* w0l_s2 = (short*)alloc((size_t)128 * 160 * 2);
    short* w1h_s2 = (short*)alloc((size_t)128 * 128 * 2);
    short* w1l_s2 = (short*)alloc((size_t)128 * 128 * 2);
    short* w2h_s2 = (short*)alloc((size_t)256 * 128 * 2);
    short* w2l_s2 = (short*)alloc((size_t)256 * 128 * 2);
    short* w0h_s3 = (short*)alloc((size_t)256 * 288 * 2);
    short* w0l_s3 = (short*)alloc((size_t)256 * 288 * 2);
    short* w1h_s3 = (short*)alloc((size_t)512 * 256 * 2);
    short* w1l_s3 = (short*)alloc((size_t)512 * 256 * 2);
    short* w2h_s3 = (short*)alloc((size_t)1024 * 512 * 2);
    short* w2l_s3 = (short*)alloc((size_t)1024 * 512 * 2);

    // merged weight prep (one launch)
    {
        WDescs W;
        const float* srcs[8] = {sa1w1, sa1w2, sa2w0, sa2w1, sa2w2, sa3w0, sa3w1, sa3w2};
        short* dhs[8] = {w1h_s1, w2h_s1, w0h_s2, w1h_s2, w2h_s2, w0h_s3, w1h_s3, w2h_s3};
        short* dls[8] = {w1l_s1, w2l_s1, w0l_s2, w1l_s2, w2l_s2, w0l_s3, w1l_s3, w2l_s3};
        int Rs[8]  = {64, 128, 128, 128, 256, 256, 512, 1024};
        int Cs[8]  = {64, 64, 131, 128, 128, 259, 256, 512};
        int Cps[8] = {64, 64, 160, 128, 128, 288, 256, 512};
        int blk = 0;
        for (int k = 0; k < 8; k++) {
            W.d[k] = {srcs[k], dhs[k], dls[k], Rs[k], Cs[k], Cps[k], blk};
            blk += (Rs[k] * Cps[k] + 255) / 256;
        }
        wprep_all_kernel<<<blk, 256, 0, stream>>>(W);
    }

    // SA1
    fps_kernel<4096, 512, 256><<<B_, 256, 0, stream>>>(x, fidx1, nxyz1);
    ballquery_kernel<4096, 32><<<B_ * 512 / 4, 256, 0, stream>>>(
        x, nxyz1, idx1, 512, 0.04f);
    sa1_mfma_kernel<<<B_ * 512 / 2, 256, 0, stream>>>(
        x, nxyz1, idx1, sa1w0, sa1b0,
        w1h_s1, w1l_s1, sa1b1, w2h_s1, w2l_s1, sa1b2, feat1);
    // SA2
    fps_kernel<512, 128, 64><<<B_, 64, 0, stream>>>(nxyz1, fidx2, nxyz2);
    ballquery_kernel<512, 64><<<B_ * 128 / 4, 256, 0, stream>>>(
        nxyz1, nxyz2, idx2, 128, 0.16f);
    sa2_mfma_kernel<<<B_ * 128, 256, 0, stream>>>(
        nxyz1, feat1, nxyz2, idx2,
        w0h_s2, w0l_s2, sa2b0, w1h_s2, w1l_s2, sa2b1, w2h_s2, w2l_s2, sa2b2,
        feat2);
    // SA3 (group-all): concat + 3 MFMA GEMMs + maxpool
    concat3_kernel<<<(4096 * 288 + 255) / 256, 256, 0, stream>>>(
        nxyz2, feat2, a3, 4096 * 288);
    mfma_gemm_kernel<1><<<dim3(2, 64), 256, 0, stream>>>(
        a3, 288, w0h_s3, w0l_s3, sa3b0, h3a, 256);
    mfma_gemm_kernel<1><<<dim3(4, 64), 256, 0, stream>>>(
        h3a, 256, w1h_s3, w1l_s3, sa3b1, h3b, 512);
    mfma_gemm_kernel<1><<<dim3(8, 64), 256, 0, stream>>>(
        h3b, 512, w2h_s3, w2l_s3, sa3b2, h3c, 1024);
    maxpool_kernel<<<B_, 256, 0, stream>>>(h3c, gfeat);
    // FC head: fc1 (1024->512), fc2 (512->256), fc3+softmax
    fc_kernel<1024, 16, 1><<<dim3(8, B_), 256, 0, stream>>>(
        gfeat, fc1w, fc1b, h1, 512);
    fc_kernel<512, 16, 1><<<dim3(4, B_), 256, 0, stream>>>(
        h1, fc2w, fc2b, h2, 256);
    fc3_softmax_kernel<<<B_, 256, 0, stream>>>(h2, fc3w, fc3b, outp);
}

// Round 10
// 1165.988 us; speedup vs baseline: 1.4063x; 1.0253x over previous
//
#include <hip/hip_runtime.h>
#include <math.h>

#define B_ 32
#define N_ 4096

typedef __attribute__((ext_vector_type(8))) short short8;
typedef __attribute__((ext_vector_type(4))) float f32x4;

// fp32 -> bf16 round-to-nearest-even, and split x = hi + lo (both bf16).
__device__ __forceinline__ unsigned short f2bf(float f) {
    unsigned u = __float_as_uint(f);
    unsigned r = 0x7FFFu + ((u >> 16) & 1u);
    return (unsigned short)((u + r) >> 16);
}
__device__ __forceinline__ float bf2f(unsigned short h) {
    return __uint_as_float(((unsigned)h) << 16);
}
__device__ __forceinline__ void f2bfpair(float v, short& h, short& l) {
    unsigned short hh = f2bf(v);
    h = (short)hh;
    l = (short)f2bf(v - bf2f(hh));
}

// ---------------------------------------------------------------------------
// Packed argmax: key = (float_bits(dist) << 32) | ~idx (R9 win: 591->344us).
// ---------------------------------------------------------------------------
__device__ __forceinline__ unsigned long long u64max(unsigned long long a,
                                                     unsigned long long b) {
    return a > b ? a : b;
}
template<int CTRL>
__device__ __forceinline__ unsigned long long dpp_u64(unsigned long long k) {
    int lo = __builtin_amdgcn_mov_dpp((int)(unsigned)k, CTRL, 0xf, 0xf, true);
    int hi = __builtin_amdgcn_mov_dpp((int)(unsigned)(k >> 32), CTRL, 0xf, 0xf, true);
    return ((unsigned long long)(unsigned)hi << 32) | (unsigned)lo;
}
__device__ __forceinline__ unsigned long long wave_argmax_u64(unsigned long long key) {
    key = u64max(key, dpp_u64<0x128>(key));   // row_ror:8
    key = u64max(key, dpp_u64<0x124>(key));   // row_ror:4
    key = u64max(key, dpp_u64<0x122>(key));   // row_ror:2
    key = u64max(key, dpp_u64<0x121>(key));   // row_ror:1
    key = u64max(key, __shfl_xor(key, 16));
    key = u64max(key, __shfl_xor(key, 32));
    return key;
}

// ---------------------------------------------------------------------------
// FPS: one block per batch, exact fp32 math (index-critical). NT=512 (R8
// showed per-iter cost tracks per-thread distance work; exchange is nearly
// wave-count-invariant -> PPT=8 shaves ~208 cyc/iter).
// ---------------------------------------------------------------------------
template<int N, int NPOINT, int NT>
__global__ __launch_bounds__(NT, 1) void fps_kernel(
    const float* __restrict__ xyz,
    int* __restrict__ outIdx,
    float* __restrict__ outXyz) {
#pragma clang fp contract(off)
    const int b = blockIdx.x;
    const int t = threadIdx.x;
    constexpr int PPT = N / NT;
    constexpr int NW = (NT + 63) / 64;
    __shared__ float xs[N], ys[N], zs[N];
    __shared__ unsigned long long red[2][NW];
    __shared__ int fidxS[NPOINT];
    const float* base = xyz + (size_t)b * N * 3;
    for (int j = t; j < N; j += NT) {
        xs[j] = base[j * 3 + 0];
        ys[j] = base[j * 3 + 1];
        zs[j] = base[j * 3 + 2];
    }
    __syncthreads();
    float px[PPT], py[PPT], pz[PPT], mind[PPT];
    unsigned notp[PPT];
#pragma unroll
    for (int i = 0; i < PPT; i++) {
        int p = t + i * NT;
        px[i] = xs[p]; py[i] = ys[p]; pz[i] = zs[p];
        mind[i] = 1e10f;
        notp[i] = ~(unsigned)p;
    }
#pragma unroll
    for (int i = 0; i < PPT; i++)
        asm volatile("" : "+v"(px[i]), "+v"(py[i]), "+v"(pz[i]));
    if (t == 0) fidxS[0] = 0;
    float lx = xs[0], ly = ys[0], lz = zs[0];
    for (int it = 1; it < NPOINT; it++) {
        unsigned long long key = 0;
#pragma unroll
        for (int i = 0; i < PPT; i++) {
            float dx = px[i] - lx, dy = py[i] - ly, dz = pz[i] - lz;
            float t0 = dx * dx, t1 = dy * dy, t2 = dz * dz;
            float d = (t0 + t1) + t2;
            float m = fminf(mind[i], d);
            mind[i] = m;
            unsigned long long k =
                ((unsigned long long)__float_as_uint(m) << 32) | notp[i];
            key = u64max(key, k);
        }
        key = wave_argmax_u64(key);
        int fi;
        if constexpr (NT > 64) {
            const int par = it & 1;
            if ((t & 63) == 0) red[par][t >> 6] = key;
            __syncthreads();
            unsigned long long best = red[par][0];
#pragma unroll
            for (int w = 1; w < NW; w++) best = u64max(best, red[par][w]);
            fi = (int)(~(unsigned)best);
        } else {
            fi = (int)(~(unsigned)key);
        }
        lx = xs[fi]; ly = ys[fi]; lz = zs[fi];
        if (t == 0) fidxS[it] = fi;
    }
    __syncthreads();
    for (int s = t; s < NPOINT; s += NT) {
        int id = fidxS[s];
        outIdx[b * NPOINT + s] = id;
        outXyz[(b * NPOINT + s) * 3 + 0] = xs[id];
        outXyz[(b * NPOINT + s) * 3 + 1] = ys[id];
        outXyz[(b * NPOINT + s) * 3 + 2] = zs[id];
    }
}

// ---------------------------------------------------------------------------
// Ball query: wave-per-query (ballot/mbcnt), exact fp32 math.
// ---------------------------------------------------------------------------
template<int N, int NS>
__global__ __launch_bounds__(256) void ballquery_kernel(
    const float* __restrict__ xyz, const float* __restrict__ newXyz,
    int* __restrict__ outIdx, int S, float r2) {
#pragma clang fp contract(off)
    const int qid = blockIdx.x * 4 + (threadIdx.x >> 6);
    const int lane = threadIdx.x & 63;
    const int b = qid / S;
    const float* q = newXyz + (size_t)qid * 3;
    const float qx = q[0], qy = q[1], qz = q[2];
    const float qn = (qx * qx + qy * qy) + qz * qz;
    const float* base = xyz + (size_t)b * N * 3;
    int* dst = outIdx + (size_t)qid * NS;
    int cnt = 0, first = 0;
    for (int p0 = 0; p0 < N; p0 += 64) {
        const int p = p0 + lane;
        const float x = base[p * 3 + 0];
        const float y = base[p * 3 + 1];
        const float z = base[p * 3 + 2];
        const float pn = (x * x + y * y) + z * z;
        const float dot = (qx * x + qy * y) + qz * z;
        const float sqd = (qn + pn) - 2.0f * dot;
        const unsigned long long mask = __ballot(sqd <= r2);
        if (mask) {
            if (cnt == 0) first = p0 + __ffsll((unsigned long long)mask) - 1;
            const int prefix = __builtin_amdgcn_mbcnt_hi(
                (unsigned)(mask >> 32),
                __builtin_amdgcn_mbcnt_lo((unsigned)mask, 0));
            const bool in = (mask >> lane) & 1ull;
            const int pos = cnt + prefix;
            if (in && pos < NS) dst[pos] = p;
            cnt += __popcll(mask);
            if (cnt >= NS) break;
        }
    }
    for (int i = cnt + lane; i < NS; i += 64) dst[i] = first;
}

// ---------------------------------------------------------------------------
// Weight prep (merged): split 8 fp32 [R][C] mats into bf16 hi/lo [R][Cp].
// perm=1 (sa2w0): column remap feat-first (dst k<128 -> src k+3; 128..130 ->
// src k-128 (xyz); else zero) to make sa2 activation loads 16B-aligned.
// ---------------------------------------------------------------------------
struct WDesc { const float* src; short* dh; short* dl; int R, C, Cp, blk0, perm; };
struct WDescs { WDesc d[8]; };

__global__ void wprep_all_kernel(WDescs W) {
    const int blk = blockIdx.x;
    int di = 0;
#pragma unroll
    for (int k = 1; k < 8; k++) di = (blk >= W.d[k].blk0) ? k : di;
    const WDesc D = W.d[di];
    const int i = (blk - D.blk0) * 256 + threadIdx.x;
    if (i >= D.R * D.Cp) return;
    const int r = i / D.Cp, c = i % D.Cp;
    int cs;
    if (D.perm) cs = (c < 128) ? c + 3 : (c < 131 ? c - 128 : -1);
    else        cs = (c < D.C) ? c : -1;
    float v = (cs >= 0) ? D.src[r * D.C + cs] : 0.f;
    short h, l;
    f2bfpair(v, h, l);
    D.dh[i] = h; D.dl[i] = l;
}

// ---------------------------------------------------------------------------
// MFMA helpers (verified gfx950 16x16x32 bf16 layouts).
// Split fp32 = hi+lo bf16: D += Ah*Bh + Ah*Bl + Al*Bh
// ---------------------------------------------------------------------------
template<int NT, int KS>
__device__ __forceinline__ void mfma_layer(
    const short* Aph, const short* Apl, const int sA,
    const short* __restrict__ Wph, const short* __restrict__ Wpl, const int sW,
    f32x4* acc, const int n0, const int mh, const int lr, const int lq) {
#pragma unroll
    for (int ks = 0; ks < KS; ks++) {
        const int ka = ks * 32 + lq * 8;
        short8 a_h[2], a_l[2];
#pragma unroll
        for (int mt = 0; mt < 2; mt++) {
            const int m = (mh * 2 + mt) * 16 + lr;
            a_h[mt] = *(const short8*)(Aph + m * sA + ka);
            a_l[mt] = *(const short8*)(Apl + m * sA + ka);
        }
#pragma unroll
        for (int nt = 0; nt < NT; nt++) {
            const int n = n0 + nt * 16 + lr;
            short8 b_h = *(const short8*)(Wph + (size_t)n * sW + ka);
            short8 b_l = *(const short8*)(Wpl + (size_t)n * sW + ka);
#pragma unroll
            for (int mt = 0; mt < 2; mt++) {
                f32x4 c = acc[mt * NT + nt];
                c = __builtin_amdgcn_mfma_f32_16x16x32_bf16(a_h[mt], b_h, c, 0, 0, 0);
                c = __builtin_amdgcn_mfma_f32_16x16x32_bf16(a_h[mt], b_l, c, 0, 0, 0);
                c = __builtin_amdgcn_mfma_f32_16x16x32_bf16(a_l[mt], b_h, c, 0, 0, 0);
                acc[mt * NT + nt] = c;
            }
        }
    }
}

template<int NT>
__device__ __forceinline__ void init_bias(f32x4* acc, const float* __restrict__ bias,
                                          const int n0, const int lr) {
#pragma unroll
    for (int nt = 0; nt < NT; nt++) {
        float bv = bias[n0 + nt * 16 + lr];
        f32x4 c = {bv, bv, bv, bv};
        acc[0 * NT + nt] = c;
        acc[1 * NT + nt] = c;
    }
}

template<int NT>
__device__ __forceinline__ void store_split(
    const f32x4* acc, short* Hp, short* Lp, const int stride,
    const int n0, const int mh, const int lr, const int lq) {
#pragma unroll
    for (int mt = 0; mt < 2; mt++)
#pragma unroll
        for (int nt = 0; nt < NT; nt++)
#pragma unroll
            for (int r = 0; r < 4; r++) {
                float v = fmaxf(acc[mt * NT + nt][r], 0.f);
                short h, l;
                f2bfpair(v, h, l);
                const int m = (mh * 2 + mt) * 16 + lq * 4 + r;
                const int n = n0 + nt * 16 + lr;
                Hp[m * stride + n] = h;
                Lp[m * stride + n] = l;
            }
}

// ---------------------------------------------------------------------------
// SA1 MFMA: outputs feat1 as split bf16 planes (producer-side split).
// ---------------------------------------------------------------------------
#define T1 72
__global__ __launch_bounds__(256) void sa1_mfma_kernel(
    const float* __restrict__ x, const float* __restrict__ nxyz1,
    const int* __restrict__ idx,
    const float* __restrict__ w0, const float* __restrict__ b0,
    const short* __restrict__ w1h, const short* __restrict__ w1l,
    const float* __restrict__ b1,
    const short* __restrict__ w2h, const short* __restrict__ w2l,
    const float* __restrict__ b2,
    short* __restrict__ feat1h, short* __restrict__ feat1l) {
    const int g0 = blockIdx.x * 2;
    const int b = g0 >> 9;
    const int t = threadIdx.x;
    const int lane = t & 63, wv = t >> 6;
    const int lr = lane & 15, lq = lane >> 4;
    const int mh = wv & 1, nh = wv >> 1;
    __shared__ float gx[64][4];
    __shared__ short H1h[64 * T1], H1l[64 * T1];
    __shared__ short H2h[64 * T1], H2l[64 * T1];
    if (t < 64) {
        int g = g0 + (t >> 5);
        int id = idx[(size_t)g * 32 + (t & 31)];
        const float* pp = x + ((size_t)b * N_ + id) * 3;
        const float* cc = nxyz1 + (size_t)g * 3;
        gx[t][0] = pp[0] - cc[0];
        gx[t][1] = pp[1] - cc[1];
        gx[t][2] = pp[2] - cc[2];
    }
    __syncthreads();
    {   // layer1 K=3 via VALU
        const int m = t >> 2, oc = (t & 3) * 16;
        float a0 = gx[m][0], a1 = gx[m][1], a2 = gx[m][2];
        short8 hv0, hv1, lv0, lv1;
#pragma unroll
        for (int i = 0; i < 16; i++) {
            int o = oc + i;
            float v = fmaf(w0[o * 3 + 0], a0,
                      fmaf(w0[o * 3 + 1], a1,
                      fmaf(w0[o * 3 + 2], a2, b0[o])));
            v = fmaxf(v, 0.f);
            short h, l;
            f2bfpair(v, h, l);
            if (i < 8) { hv0[i] = h; lv0[i] = l; }
            else       { hv1[i - 8] = h; lv1[i - 8] = l; }
        }
        *(short8*)&H1h[m * T1 + oc]     = hv0;
        *(short8*)&H1h[m * T1 + oc + 8] = hv1;
        *(short8*)&H1l[m * T1 + oc]     = lv0;
        *(short8*)&H1l[m * T1 + oc + 8] = lv1;
    }
    __syncthreads();
    {   // layer2: K=64, N=64
        f32x4 acc[4];
        init_bias<2>(acc, b1, nh * 32, lr);
        mfma_layer<2, 2>(H1h, H1l, T1, w1h, w1l, 64, acc, nh * 32, mh, lr, lq);
        store_split<2>(acc, H2h, H2l, T1, nh * 32, mh, lr, lq);
    }
    __syncthreads();
    {   // layer3: K=64, N=128 + per-group max, split output
        f32x4 acc[8];
        init_bias<4>(acc, b2, nh * 64, lr);
        mfma_layer<4, 2>(H2h, H2l, T1, w2h, w2l, 64, acc, nh * 64, mh, lr, lq);
#pragma unroll
        for (int nt = 0; nt < 4; nt++) {
            float v = 0.f;
#pragma unroll
            for (int mt = 0; mt < 2; mt++)
#pragma unroll
                for (int r = 0; r < 4; r++)
                    v = fmaxf(v, acc[mt * 4 + nt][r]);
            v = fmaxf(v, __shfl_xor(v, 16));
            v = fmaxf(v, __shfl_xor(v, 32));
            if (lane < 16) {
                short h, l;
                f2bfpair(v, h, l);
                size_t o = (size_t)(g0 + mh) * 128 + nh * 64 + nt * 16 + lane;
                feat1h[o] = h;
                feat1l[o] = l;
            }
        }
    }
}

// ---------------------------------------------------------------------------
// SA2 MFMA: consumes feat1 planes (feat-first layout: k 0..127 feat,
// 128..130 xyz, 131..159 zero — matches permuted w0 planes). Outputs a3
// split planes directly ([4096][288]: cols 0..2 xyz, 3..258 feat, pad 0).
// ---------------------------------------------------------------------------
#define S1 168
#define S2 136
__global__ __launch_bounds__(256) void sa2_mfma_kernel(
    const float* __restrict__ xyz1,
    const short* __restrict__ feat1h, const short* __restrict__ feat1l,
    const float* __restrict__ newXyz, const int* __restrict__ idx,
    const short* __restrict__ w0h, const short* __restrict__ w0l,
    const float* __restrict__ b0,
    const short* __restrict__ w1h, const short* __restrict__ w1l,
    const float* __restrict__ b1,
    const short* __restrict__ w2h, const short* __restrict__ w2l,
    const float* __restrict__ b2,
    short* __restrict__ a3h, short* __restrict__ a3l) {
    const int g = blockIdx.x;
    const int b = g >> 7;
    const int t = threadIdx.x;
    const int lane = t & 63, wv = t >> 6;
    const int lr = lane & 15, lq = lane >> 4;
    const int mh = wv & 1, nh = wv >> 1;
    __shared__ short Ah[64 * S1], Al[64 * S1];
    __shared__ short Hh[64 * S2], Hl[64 * S2];
    __shared__ float pmax[2][256];
    __shared__ int ids[64];
    if (t < 64) ids[t] = idx[(size_t)g * 64 + t];
    __syncthreads();
    {   // gather: feat cols 0..127 via b128 plane copies; xyz at 128..130
        const int m = t >> 2, q = t & 3;
        const int id = ids[m];
        const size_t frow = ((size_t)b * 512 + id) * 128;
#pragma unroll
        for (int c8 = 0; c8 < 4; c8++) {
            const int k = q * 32 + c8 * 8;
            *(short8*)&Ah[m * S1 + k] = *(const short8*)(feat1h + frow + k);
            *(short8*)&Al[m * S1 + k] = *(const short8*)(feat1l + frow + k);
        }
        if (t < 64) {
            const int id2 = ids[t];
            // zero cols 128..159 (two b128 per plane), then write xyz
            short8 zz = {0, 0, 0, 0, 0, 0, 0, 0};
            *(short8*)&Ah[t * S1 + 128] = zz;
            *(short8*)&Ah[t * S1 + 136] = zz;
            *(short8*)&Ah[t * S1 + 144] = zz;
            *(short8*)&Ah[t * S1 + 152] = zz;
            *(short8*)&Al[t * S1 + 128] = zz;
            *(short8*)&Al[t * S1 + 136] = zz;
            *(short8*)&Al[t * S1 + 144] = zz;
            *(short8*)&Al[t * S1 + 152] = zz;
            const float* prow = xyz1 + ((size_t)b * 512 + id2) * 3;
            const float* crow = newXyz + (size_t)g * 3;
#pragma unroll
            for (int c = 0; c < 3; c++) {
                short h, l;
                f2bfpair(prow[c] - crow[c], h, l);
                Ah[t * S1 + 128 + c] = h;
                Al[t * S1 + 128 + c] = l;
            }
        }
    }
    __syncthreads();
    {   // layer1: K=160, N=128
        f32x4 acc[8];
        init_bias<4>(acc, b0, nh * 64, lr);
        mfma_layer<4, 5>(Ah, Al, S1, w0h, w0l, 160, acc, nh * 64, mh, lr, lq);
        store_split<4>(acc, Hh, Hl, S2, nh * 64, mh, lr, lq);
    }
    __syncthreads();
    {   // layer2: K=128, N=128
        f32x4 acc[8];
        init_bias<4>(acc, b1, nh * 64, lr);
        mfma_layer<4, 4>(Hh, Hl, S2, w1h, w1l, 128, acc, nh * 64, mh, lr, lq);
        store_split<4>(acc, Ah, Al, S2, nh * 64, mh, lr, lq);
    }
    __syncthreads();
    {   // layer3: K=128, N=256 + max over 64 rows
        f32x4 acc[16];
        init_bias<8>(acc, b2, nh * 128, lr);
        mfma_layer<8, 4>(Ah, Al, S2, w2h, w2l, 128, acc, nh * 128, mh, lr, lq);
#pragma unroll
        for (int nt = 0; nt < 8; nt++) {
            float v = 0.f;
#pragma unroll
            for (int mt = 0; mt < 2; mt++)
#pragma unroll
                for (int r = 0; r < 4; r++)
                    v = fmaxf(v, acc[mt * 8 + nt][r]);
            v = fmaxf(v, __shfl_xor(v, 16));
            v = fmaxf(v, __shfl_xor(v, 32));
            if (lane < 16) pmax[mh][nh * 128 + nt * 16 + lane] = v;
        }
    }
    __syncthreads();
    {   // write a3 row g: col 3+t = feat, cols 0..2 xyz, 259..287 zero
        float v = fmaxf(pmax[0][t], pmax[1][t]);
        short h, l;
        f2bfpair(v, h, l);
        a3h[(size_t)g * 288 + 3 + t] = h;
        a3l[(size_t)g * 288 + 3 + t] = l;
        if (t < 3) {
            f2bfpair(newXyz[(size_t)g * 3 + t], h, l);
            a3h[(size_t)g * 288 + t] = h;
            a3l[(size_t)g * 288 + t] = l;
        }
        if (t >= 227) {
            a3h[(size_t)g * 288 + t + 32] = 0;
            a3l[(size_t)g * 288 + t + 32] = 0;
        }
    }
}

// ---------------------------------------------------------------------------
// MFMA GEMM: A pre-split planes [M][Kp]; weights pre-split planes [N][Kp].
// OUT_PLANES=1 -> relu + split-plane output; 0 -> relu + fp32 output.
// ---------------------------------------------------------------------------
template<int OUT_PLANES>
__global__ __launch_bounds__(256) void mfma_gemm_kernel(
    const short* __restrict__ Agh, const short* __restrict__ Agl, const int Kp,
    const short* __restrict__ Wh, const short* __restrict__ Wl,
    const float* __restrict__ bias,
    float* __restrict__ outF, short* __restrict__ outH,
    short* __restrict__ outL, const int N) {
    const int t = threadIdx.x;
    const int lane = t & 63, wv = t >> 6;
    const int lr = lane & 15, lq = lane >> 4;
    const int mh = wv & 1, nh = wv >> 1;
    const int m0 = blockIdx.y * 64;
    const int n0 = blockIdx.x * 128 + nh * 64;
    __shared__ short Ah[64 * 40], Al[64 * 40];
    f32x4 acc[8];
#pragma unroll
    for (int nt = 0; nt < 4; nt++) {
        float bv = bias[n0 + nt * 16 + lr];
        f32x4 c = {bv, bv, bv, bv};
        acc[nt] = c; acc[4 + nt] = c;
    }
    const int srow = t >> 2, sk = (t & 3) * 8;
    for (int kt = 0; kt < Kp; kt += 32) {
        {   // stage A chunk: pure b128 copies (no conversion)
            const size_t src = (size_t)(m0 + srow) * Kp + kt + sk;
            *(short8*)&Ah[srow * 40 + sk] = *(const short8*)(Agh + src);
            *(short8*)&Al[srow * 40 + sk] = *(const short8*)(Agl + src);
        }
        __syncthreads();
        short8 a_h[2], a_l[2];
#pragma unroll
        for (int mt = 0; mt < 2; mt++) {
            const int m = mh * 32 + mt * 16 + lr;
            a_h[mt] = *(const short8*)&Ah[m * 40 + lq * 8];
            a_l[mt] = *(const short8*)&Al[m * 40 + lq * 8];
        }
#pragma unroll
        for (int nt = 0; nt < 4; nt++) {
            const int n = n0 + nt * 16 + lr;
            short8 b_h = *(const short8*)(Wh + (size_t)n * Kp + kt + lq * 8);
            short8 b_l = *(const short8*)(Wl + (size_t)n * Kp + kt + lq * 8);
#pragma unroll
            for (int mt = 0; mt < 2; mt++) {
                f32x4 c = acc[mt * 4 + nt];
                c = __builtin_amdgcn_mfma_f32_16x16x32_bf16(a_h[mt], b_h, c, 0, 0, 0);
                c = __builtin_amdgcn_mfma_f32_16x16x32_bf16(a_h[mt], b_l, c, 0, 0, 0);
                c = __builtin_amdgcn_mfma_f32_16x16x32_bf16(a_l[mt], b_h, c, 0, 0, 0);
                acc[mt * 4 + nt] = c;
            }
        }
        __syncthreads();
    }
#pragma unroll
    for (int mt = 0; mt < 2; mt++)
#pragma unroll
        for (int nt = 0; nt < 4; nt++)
#pragma unroll
            for (int r = 0; r < 4; r++) {
                const int m = m0 + mh * 32 + mt * 16 + lq * 4 + r;
                const int n = n0 + nt * 16 + lr;
                float v = fmaxf(acc[mt * 4 + nt][r], 0.f);
                if (OUT_PLANES) {
                    short h, l;
                    f2bfpair(v, h, l);
                    outH[(size_t)m * N + n] = h;
                    outL[(size_t)m * N + n] = l;
                } else {
                    outF[(size_t)m * N + n] = v;
                }
            }
}

// ---------------------------------------------------------------------------
// max over 128 points: (32,128,1024) -> (32,1024)
// ---------------------------------------------------------------------------
__global__ void maxpool_kernel(const float* __restrict__ in,
                               float* __restrict__ out) {
    int b = blockIdx.x, t = threadIdx.x;
#pragma unroll
    for (int j = 0; j < 4; j++) {
        int o = t + j * 256;
        float m = -INFINITY;
        for (int k = 0; k < 128; k++)
            m = fmaxf(m, in[((size_t)b * 128 + k) * 1024 + o]);
        out[b * 1024 + o] = m;
    }
}

// ---------------------------------------------------------------------------
// FC layer: grid (O/(4*OPW), B), block 256.
// ---------------------------------------------------------------------------
template<int K, int OPW, int ACT>
__global__ __launch_bounds__(256) void fc_kernel(
    const float* __restrict__ in, const float* __restrict__ w,
    const float* __restrict__ bias, float* __restrict__ out, const int O) {
    const int batch = blockIdx.y;
    const int t = threadIdx.x, lane = t & 63, wv = t >> 6;
    __shared__ float f[K];
    for (int j = t; j < K; j += 256) f[j] = in[batch * K + j];
    __syncthreads();
    const int o0 = blockIdx.x * (4 * OPW) + wv * OPW;
#pragma unroll
    for (int i = 0; i < OPW; i++) {
        const int o = o0 + i;
        const float* wr = w + (size_t)o * K;
        float a = 0.f;
#pragma unroll
        for (int c = lane; c < K; c += 64) a = fmaf(wr[c], f[c], a);
#pragma unroll
        for (int off = 32; off > 0; off >>= 1) a += __shfl_xor(a, off);
        if (lane == 0) {
            float v = a + bias[o];
            out[batch * O + o] = ACT ? fmaxf(v, 0.f) : v;
        }
    }
}

// fc3 (256->40) + softmax fused; one block per batch.
__global__ __launch_bounds__(256) void fc3_softmax_kernel(
    const float* __restrict__ in, const float* __restrict__ w3,
    const float* __restrict__ b3, float* __restrict__ out) {
    const int b = blockIdx.x, t = threadIdx.x, lane = t & 63, wv = t >> 6;
    __shared__ float f[256];
    __shared__ float lg[40];
    f[t] = in[b * 256 + t];
    __syncthreads();
#pragma unroll
    for (int i = 0; i < 10; i++) {
        const int o = wv * 10 + i;
        const float* wr = w3 + (size_t)o * 256;
        float a = 0.f;
#pragma unroll
        for (int c = lane; c < 256; c += 64) a = fmaf(wr[c], f[c], a);
#pragma unroll
        for (int off = 32; off > 0; off >>= 1) a += __shfl_xor(a, off);
        if (lane == 0) lg[o] = a + b3[o];
    }
    __syncthreads();
    if (t < 64) {
        float v = (t < 40) ? lg[t] : -INFINITY;
        float m = v;
#pragma unroll
        for (int off = 32; off > 0; off >>= 1) m = fmaxf(m, __shfl_xor(m, off));
        float e = (t < 40) ? expf(v - m) : 0.f;
        float s = e;
#pragma unroll
        for (int off = 32; off > 0; off >>= 1) s += __shfl_xor(s, off);
        if (t < 40) out[b * 40 + t] = e / s;
    }
}

// ---------------------------------------------------------------------------
extern "C" void kernel_launch(void* const* d_in, const int* in_sizes, int n_in,
                              void* d_out, int out_size, void* d_ws, size_t ws_size,
                              hipStream_t stream) {
    (void)in_sizes; (void)n_in; (void)out_size; (void)ws_size;
    const float* x      = (const float*)d_in[0];
    const float* sa1w0  = (const float*)d_in[1];
    const float* sa1b0  = (const float*)d_in[2];
    const float* sa1w1  = (const float*)d_in[3];
    const float* sa1b1  = (const float*)d_in[4];
    const float* sa1w2  = (const float*)d_in[5];
    const float* sa1b2  = (const float*)d_in[6];
    const float* sa2w0  = (const float*)d_in[7];
    const float* sa2b0  = (const float*)d_in[8];
    const float* sa2w1  = (const float*)d_in[9];
    const float* sa2b1  = (const float*)d_in[10];
    const float* sa2w2  = (const float*)d_in[11];
    const float* sa2b2  = (const float*)d_in[12];
    const float* sa3w0  = (const float*)d_in[13];
    const float* sa3b0  = (const float*)d_in[14];
    const float* sa3w1  = (const float*)d_in[15];
    const float* sa3b1  = (const float*)d_in[16];
    const float* sa3w2  = (const float*)d_in[17];
    const float* sa3b2  = (const float*)d_in[18];
    const float* fc1w   = (const float*)d_in[19];
    const float* fc1b   = (const float*)d_in[20];
    const float* fc2w   = (const float*)d_in[21];
    const float* fc2b   = (const float*)d_in[22];
    const float* fc3w   = (const float*)d_in[23];
    const float* fc3b   = (const float*)d_in[24];
    float* outp = (float*)d_out;

    char* ws = (char*)d_ws;
    size_t off = 0;
    auto alloc = [&](size_t bytes) {
        void* p = ws + off;
        off += (bytes + 255) & ~(size_t)255;
        return p;
    };
    int*   fidx1   = (int*)  alloc((size_t)B_ * 512 * 4);
    float* nxyz1   = (float*)alloc((size_t)B_ * 512 * 3 * 4);
    int*   idx1    = (int*)  alloc((size_t)B_ * 512 * 32 * 4);
    short* feat1h  = (short*)alloc((size_t)B_ * 512 * 128 * 2);
    short* feat1l  = (short*)alloc((size_t)B_ * 512 * 128 * 2);
    int*   fidx2   = (int*)  alloc((size_t)B_ * 128 * 4);
    float* nxyz2   = (float*)alloc((size_t)B_ * 128 * 3 * 4);
    int*   idx2    = (int*)  alloc((size_t)B_ * 128 * 64 * 4);
    short* a3h     = (short*)alloc((size_t)4096 * 288 * 2);
    short* a3l     = (short*)alloc((size_t)4096 * 288 * 2);
    short* h3ah    = (short*)alloc((size_t)4096 * 256 * 2);
    short* h3al    = (short*)alloc((size_t)4096 * 256 * 2);
    short* h3bh    = (short*)alloc((size_t)4096 * 512 * 2);
    short* h3bl    = (short*)alloc((size_t)4096 * 512 * 2);
    float* h3c     = (float*)alloc((size_t)4096 * 1024 * 4);
    float* gfeat   = (float*)alloc((size_t)B_ * 1024 * 4);
    float* h1      = (float*)alloc((size_t)B_ * 512 * 4);
    float* h2      = (float*)alloc((size_t)B_ * 256 * 4);
    // split-bf16 weight planes
    short* w1h_s1 = (short*)alloc((size_t)64 * 64 * 2);
    short* w1l_s1 = (short*)alloc((size_t)64 * 64 * 2);
    short* w2h_s1 = (short*)alloc((size_t)128 * 64 * 2);
    short* w2l_s1 = (short*)alloc((size_t)128 * 64 * 2);
    short* w0h_s2 = (short*)alloc((size_t)128 * 160 * 2);
    short* w0l_s2 = (short*)alloc((size_t)128 * 160 * 2);
    short* w1h_s2 = (short*)alloc((size_t)128 * 128 * 2);
    short* w1l_s2 = (short*)alloc((size_t)128 * 128 * 2);
    short* w2h_s2 = (short*)alloc((size_t)256 * 128 * 2);
    short* w2l_s2 = (short*)alloc((size_t)256 * 128 * 2);
    short* w0h_s3 = (short*)alloc((size_t)256 * 288 * 2);
    short* w0l_s3 = (short*)alloc((size_t)256 * 288 * 2);
    short* w1h_s3 = (short*)alloc((size_t)512 * 256 * 2);
    short* w1l_s3 = (short*)alloc((size_t)512 * 256 * 2);
    short* w2h_s3 = (short*)alloc((size_t)1024 * 512 * 2);
    short* w2l_s3 = (short*)alloc((size_t)1024 * 512 * 2);

    // merged weight prep (one launch); entry 2 (sa2w0) uses feat-first perm
    {
        WDescs W;
        const float* srcs[8] = {sa1w1, sa1w2, sa2w0, sa2w1, sa2w2, sa3w0, sa3w1, sa3w2};
        short* dhs[8] = {w1h_s1, w2h_s1, w0h_s2, w1h_s2, w2h_s2, w0h_s3, w1h_s3, w2h_s3};
        short* dls[8] = {w1l_s1, w2l_s1, w0l_s2, w1l_s2, w2l_s2, w0l_s3, w1l_s3, w2l_s3};
        int Rs[8]  = {64, 128, 128, 128, 256, 256, 512, 1024};
        int Cs[8]  = {64, 64, 131, 128, 128, 259, 256, 512};
        int Cps[8] = {64, 64, 160, 128, 128, 288, 256, 512};
        int blk = 0;
        for (int k = 0; k < 8; k++) {
            W.d[k] = {srcs[k], dhs[k], dls[k], Rs[k], Cs[k], Cps[k], blk,
                      (k == 2) ? 1 : 0};
            blk += (Rs[k] * Cps[k] + 255) / 256;
        }
        wprep_all_kernel<<<blk, 256, 0, stream>>>(W);
    }

    // SA1
    fps_kernel<4096, 512, 512><<<B_, 512, 0, stream>>>(x, fidx1, nxyz1);
    ballquery_kernel<4096, 32><<<B_ * 512 / 4, 256, 0, stream>>>(
        x, nxyz1, idx1, 512, 0.04f);
    sa1_mfma_kernel<<<B_ * 512 / 2, 256, 0, stream>>>(
        x, nxyz1, idx1, sa1w0, sa1b0,
        w1h_s1, w1l_s1, sa1b1, w2h_s1, w2l_s1, sa1b2, feat1h, feat1l);
    // SA2
    fps_kernel<512, 128, 64><<<B_, 64, 0, stream>>>(nxyz1, fidx2, nxyz2);
    ballquery_kernel<512, 64><<<B_ * 128 / 4, 256, 0, stream>>>(
        nxyz1, nxyz2, idx2, 128, 0.16f);
    sa2_mfma_kernel<<<B_ * 128, 256, 0, stream>>>(
        nxyz1, feat1h, feat1l, nxyz2, idx2,
        w0h_s2, w0l_s2, sa2b0, w1h_s2, w1l_s2, sa2b1, w2h_s2, w2l_s2, sa2b2,
        a3h, a3l);
    // SA3 (group-all): 3 MFMA GEMMs on planes + maxpool
    mfma_gemm_kernel<1><<<dim3(2, 64), 256, 0, stream>>>(
        a3h, a3l, 288, w0h_s3, w0l_s3, sa3b0, nullptr, h3ah, h3al, 256);
    mfma_gemm_kernel<1><<<dim3(4, 64), 256, 0, stream>>>(
        h3ah, h3al, 256, w1h_s3, w1l_s3, sa3b1, nullptr, h3bh, h3bl, 512);
    mfma_gemm_kernel<0><<<dim3(8, 64), 256, 0, stream>>>(
        h3bh, h3bl, 512, w2h_s3, w2l_s3, sa3b2, h3c, nullptr, nullptr, 1024);
    maxpool_kernel<<<B_, 256, 0, stream>>>(h3c, gfeat);
    // FC head: fc1 (1024->512), fc2 (512->256), fc3+softmax
    fc_kernel<1024, 16, 1><<<dim3(8, B_), 256, 0, stream>>>(
        gfeat, fc1w, fc1b, h1, 512);
    fc_kernel<512, 16, 1><<<dim3(4, B_), 256, 0, stream>>>(
        h1, fc2w, fc2b, h2, 256);
    fc3_softmax_kernel<<<B_, 256, 0, stream>>>(h2, fc3w, fc3b, outp);
}

// Round 11
// 1062.528 us; speedup vs baseline: 1.5433x; 1.0974x over previous
//
#include <hip/hip_runtime.h>
#include <math.h>

#define B_ 32
#define N_ 4096

typedef __attribute__((ext_vector_type(8))) short short8;
typedef __attribute__((ext_vector_type(4))) float f32x4;

// fp32 -> bf16 round-to-nearest-even, and split x = hi + lo (both bf16).
__device__ __forceinline__ unsigned short f2bf(float f) {
    unsigned u = __float_as_uint(f);
    unsigned r = 0x7FFFu + ((u >> 16) & 1u);
    return (unsigned short)((u + r) >> 16);
}
__device__ __forceinline__ float bf2f(unsigned short h) {
    return __uint_as_float(((unsigned)h) << 16);
}
__device__ __forceinline__ void f2bfpair(float v, short& h, short& l) {
    unsigned short hh = f2bf(v);
    h = (short)hh;
    l = (short)f2bf(v - bf2f(hh));
}

// ---------------------------------------------------------------------------
// Packed argmax: key = (float_bits(dist) << 32) | ~idx (R9 win: 591->344us).
// ---------------------------------------------------------------------------
__device__ __forceinline__ unsigned long long u64max(unsigned long long a,
                                                     unsigned long long b) {
    return a > b ? a : b;
}
template<int CTRL>
__device__ __forceinline__ unsigned long long dpp_u64(unsigned long long k) {
    int lo = __builtin_amdgcn_mov_dpp((int)(unsigned)k, CTRL, 0xf, 0xf, true);
    int hi = __builtin_amdgcn_mov_dpp((int)(unsigned)(k >> 32), CTRL, 0xf, 0xf, true);
    return ((unsigned long long)(unsigned)hi << 32) | (unsigned)lo;
}
__device__ __forceinline__ unsigned long long wave_argmax_u64(unsigned long long key) {
    key = u64max(key, dpp_u64<0x128>(key));   // row_ror:8
    key = u64max(key, dpp_u64<0x124>(key));   // row_ror:4
    key = u64max(key, dpp_u64<0x122>(key));   // row_ror:2
    key = u64max(key, dpp_u64<0x121>(key));   // row_ror:1
    key = u64max(key, __shfl_xor(key, 16));
    key = u64max(key, __shfl_xor(key, 32));
    return key;
}

// ---------------------------------------------------------------------------
// FPS: one block per batch, exact fp32 math (index-critical). NT ladder
// measured: 128=591, 256=344 (best), 512=363 -> NT=256.
// ---------------------------------------------------------------------------
template<int N, int NPOINT, int NT>
__global__ __launch_bounds__(NT, 1) void fps_kernel(
    const float* __restrict__ xyz,
    int* __restrict__ outIdx,
    float* __restrict__ outXyz) {
#pragma clang fp contract(off)
    const int b = blockIdx.x;
    const int t = threadIdx.x;
    constexpr int PPT = N / NT;
    constexpr int NW = (NT + 63) / 64;
    __shared__ float xs[N], ys[N], zs[N];
    __shared__ unsigned long long red[2][NW];
    __shared__ int fidxS[NPOINT];
    const float* base = xyz + (size_t)b * N * 3;
    for (int j = t; j < N; j += NT) {
        xs[j] = base[j * 3 + 0];
        ys[j] = base[j * 3 + 1];
        zs[j] = base[j * 3 + 2];
    }
    __syncthreads();
    float px[PPT], py[PPT], pz[PPT], mind[PPT];
    unsigned notp[PPT];
#pragma unroll
    for (int i = 0; i < PPT; i++) {
        int p = t + i * NT;
        px[i] = xs[p]; py[i] = ys[p]; pz[i] = zs[p];
        mind[i] = 1e10f;
        notp[i] = ~(unsigned)p;
    }
#pragma unroll
    for (int i = 0; i < PPT; i++)
        asm volatile("" : "+v"(px[i]), "+v"(py[i]), "+v"(pz[i]));
    if (t == 0) fidxS[0] = 0;
    float lx = xs[0], ly = ys[0], lz = zs[0];
    for (int it = 1; it < NPOINT; it++) {
        unsigned long long key = 0;
#pragma unroll
        for (int i = 0; i < PPT; i++) {
            float dx = px[i] - lx, dy = py[i] - ly, dz = pz[i] - lz;
            float t0 = dx * dx, t1 = dy * dy, t2 = dz * dz;
            float d = (t0 + t1) + t2;
            float m = fminf(mind[i], d);
            mind[i] = m;
            unsigned long long k =
                ((unsigned long long)__float_as_uint(m) << 32) | notp[i];
            key = u64max(key, k);
        }
        key = wave_argmax_u64(key);
        int fi;
        if constexpr (NT > 64) {
            const int par = it & 1;
            if ((t & 63) == 0) red[par][t >> 6] = key;
            __syncthreads();
            unsigned long long best = red[par][0];
#pragma unroll
            for (int w = 1; w < NW; w++) best = u64max(best, red[par][w]);
            fi = (int)(~(unsigned)best);
        } else {
            fi = (int)(~(unsigned)key);
        }
        lx = xs[fi]; ly = ys[fi]; lz = zs[fi];
        if (t == 0) fidxS[it] = fi;
    }
    __syncthreads();
    for (int s = t; s < NPOINT; s += NT) {
        int id = fidxS[s];
        outIdx[b * NPOINT + s] = id;
        outXyz[(b * NPOINT + s) * 3 + 0] = xs[id];
        outXyz[(b * NPOINT + s) * 3 + 1] = ys[id];
        outXyz[(b * NPOINT + s) * 3 + 2] = zs[id];
    }
}

// ---------------------------------------------------------------------------
// Ball query: wave-per-query (ballot/mbcnt), exact fp32 math.
// ---------------------------------------------------------------------------
template<int N, int NS>
__global__ __launch_bounds__(256) void ballquery_kernel(
    const float* __restrict__ xyz, const float* __restrict__ newXyz,
    int* __restrict__ outIdx, int S, float r2) {
#pragma clang fp contract(off)
    const int qid = blockIdx.x * 4 + (threadIdx.x >> 6);
    const int lane = threadIdx.x & 63;
    const int b = qid / S;
    const float* q = newXyz + (size_t)qid * 3;
    const float qx = q[0], qy = q[1], qz = q[2];
    const float qn = (qx * qx + qy * qy) + qz * qz;
    const float* base = xyz + (size_t)b * N * 3;
    int* dst = outIdx + (size_t)qid * NS;
    int cnt = 0, first = 0;
    for (int p0 = 0; p0 < N; p0 += 64) {
        const int p = p0 + lane;
        const float x = base[p * 3 + 0];
        const float y = base[p * 3 + 1];
        const float z = base[p * 3 + 2];
        const float pn = (x * x + y * y) + z * z;
        const float dot = (qx * x + qy * y) + qz * z;
        const float sqd = (qn + pn) - 2.0f * dot;
        const unsigned long long mask = __ballot(sqd <= r2);
        if (mask) {
            if (cnt == 0) first = p0 + __ffsll((unsigned long long)mask) - 1;
            const int prefix = __builtin_amdgcn_mbcnt_hi(
                (unsigned)(mask >> 32),
                __builtin_amdgcn_mbcnt_lo((unsigned)mask, 0));
            const bool in = (mask >> lane) & 1ull;
            const int pos = cnt + prefix;
            if (in && pos < NS) dst[pos] = p;
            cnt += __popcll(mask);
            if (cnt >= NS) break;
        }
    }
    for (int i = cnt + lane; i < NS; i += 64) dst[i] = first;
}

// ---------------------------------------------------------------------------
// Weight prep (merged): split 8 fp32 [R][C] mats into bf16 hi/lo [R][Cp].
// perm=1 (sa2w0): column remap feat-first to match sa2's activation layout.
// ---------------------------------------------------------------------------
struct WDesc { const float* src; short* dh; short* dl; int R, C, Cp, blk0, perm; };
struct WDescs { WDesc d[8]; };

__global__ void wprep_all_kernel(WDescs W) {
    const int blk = blockIdx.x;
    int di = 0;
#pragma unroll
    for (int k = 1; k < 8; k++) di = (blk >= W.d[k].blk0) ? k : di;
    const WDesc D = W.d[di];
    const int i = (blk - D.blk0) * 256 + threadIdx.x;
    if (i >= D.R * D.Cp) return;
    const int r = i / D.Cp, c = i % D.Cp;
    int cs;
    if (D.perm) cs = (c < 128) ? c + 3 : (c < 131 ? c - 128 : -1);
    else        cs = (c < D.C) ? c : -1;
    float v = (cs >= 0) ? D.src[r * D.C + cs] : 0.f;
    short h, l;
    f2bfpair(v, h, l);
    D.dh[i] = h; D.dl[i] = l;
}

// ---------------------------------------------------------------------------
// MFMA helpers (verified gfx950 16x16x32 bf16 layouts).
// Split fp32 = hi+lo bf16: D += Ah*Bh + Ah*Bl + Al*Bh
// ---------------------------------------------------------------------------
template<int NT, int KS>
__device__ __forceinline__ void mfma_layer(
    const short* Aph, const short* Apl, const int sA,
    const short* __restrict__ Wph, const short* __restrict__ Wpl, const int sW,
    f32x4* acc, const int n0, const int mh, const int lr, const int lq) {
#pragma unroll
    for (int ks = 0; ks < KS; ks++) {
        const int ka = ks * 32 + lq * 8;
        short8 a_h[2], a_l[2];
#pragma unroll
        for (int mt = 0; mt < 2; mt++) {
            const int m = (mh * 2 + mt) * 16 + lr;
            a_h[mt] = *(const short8*)(Aph + m * sA + ka);
            a_l[mt] = *(const short8*)(Apl + m * sA + ka);
        }
#pragma unroll
        for (int nt = 0; nt < NT; nt++) {
            const int n = n0 + nt * 16 + lr;
            short8 b_h = *(const short8*)(Wph + (size_t)n * sW + ka);
            short8 b_l = *(const short8*)(Wpl + (size_t)n * sW + ka);
#pragma unroll
            for (int mt = 0; mt < 2; mt++) {
                f32x4 c = acc[mt * NT + nt];
                c = __builtin_amdgcn_mfma_f32_16x16x32_bf16(a_h[mt], b_h, c, 0, 0, 0);
                c = __builtin_amdgcn_mfma_f32_16x16x32_bf16(a_h[mt], b_l, c, 0, 0, 0);
                c = __builtin_amdgcn_mfma_f32_16x16x32_bf16(a_l[mt], b_h, c, 0, 0, 0);
                acc[mt * NT + nt] = c;
            }
        }
    }
}

template<int NT>
__device__ __forceinline__ void init_bias(f32x4* acc, const float* __restrict__ bias,
                                          const int n0, const int lr) {
#pragma unroll
    for (int nt = 0; nt < NT; nt++) {
        float bv = bias[n0 + nt * 16 + lr];
        f32x4 c = {bv, bv, bv, bv};
        acc[0 * NT + nt] = c;
        acc[1 * NT + nt] = c;
    }
}

template<int NT>
__device__ __forceinline__ void store_split(
    const f32x4* acc, short* Hp, short* Lp, const int stride,
    const int n0, const int mh, const int lr, const int lq) {
#pragma unroll
    for (int mt = 0; mt < 2; mt++)
#pragma unroll
        for (int nt = 0; nt < NT; nt++)
#pragma unroll
            for (int r = 0; r < 4; r++) {
                float v = fmaxf(acc[mt * NT + nt][r], 0.f);
                short h, l;
                f2bfpair(v, h, l);
                const int m = (mh * 2 + mt) * 16 + lq * 4 + r;
                const int n = n0 + nt * 16 + lr;
                Hp[m * stride + n] = h;
                Lp[m * stride + n] = l;
            }
}

// ---------------------------------------------------------------------------
// SA1 MFMA: outputs feat1 as split bf16 planes (producer-side split).
// ---------------------------------------------------------------------------
#define T1 72
__global__ __launch_bounds__(256) void sa1_mfma_kernel(
    const float* __restrict__ x, const float* __restrict__ nxyz1,
    const int* __restrict__ idx,
    const float* __restrict__ w0, const float* __restrict__ b0,
    const short* __restrict__ w1h, const short* __restrict__ w1l,
    const float* __restrict__ b1,
    const short* __restrict__ w2h, const short* __restrict__ w2l,
    const float* __restrict__ b2,
    short* __restrict__ feat1h, short* __restrict__ feat1l) {
    const int g0 = blockIdx.x * 2;
    const int b = g0 >> 9;
    const int t = threadIdx.x;
    const int lane = t & 63, wv = t >> 6;
    const int lr = lane & 15, lq = lane >> 4;
    const int mh = wv & 1, nh = wv >> 1;
    __shared__ float gx[64][4];
    __shared__ short H1h[64 * T1], H1l[64 * T1];
    __shared__ short H2h[64 * T1], H2l[64 * T1];
    if (t < 64) {
        int g = g0 + (t >> 5);
        int id = idx[(size_t)g * 32 + (t & 31)];
        const float* pp = x + ((size_t)b * N_ + id) * 3;
        const float* cc = nxyz1 + (size_t)g * 3;
        gx[t][0] = pp[0] - cc[0];
        gx[t][1] = pp[1] - cc[1];
        gx[t][2] = pp[2] - cc[2];
    }
    __syncthreads();
    {   // layer1 K=3 via VALU
        const int m = t >> 2, oc = (t & 3) * 16;
        float a0 = gx[m][0], a1 = gx[m][1], a2 = gx[m][2];
        short8 hv0, hv1, lv0, lv1;
#pragma unroll
        for (int i = 0; i < 16; i++) {
            int o = oc + i;
            float v = fmaf(w0[o * 3 + 0], a0,
                      fmaf(w0[o * 3 + 1], a1,
                      fmaf(w0[o * 3 + 2], a2, b0[o])));
            v = fmaxf(v, 0.f);
            short h, l;
            f2bfpair(v, h, l);
            if (i < 8) { hv0[i] = h; lv0[i] = l; }
            else       { hv1[i - 8] = h; lv1[i - 8] = l; }
        }
        *(short8*)&H1h[m * T1 + oc]     = hv0;
        *(short8*)&H1h[m * T1 + oc + 8] = hv1;
        *(short8*)&H1l[m * T1 + oc]     = lv0;
        *(short8*)&H1l[m * T1 + oc + 8] = lv1;
    }
    __syncthreads();
    {   // layer2: K=64, N=64
        f32x4 acc[4];
        init_bias<2>(acc, b1, nh * 32, lr);
        mfma_layer<2, 2>(H1h, H1l, T1, w1h, w1l, 64, acc, nh * 32, mh, lr, lq);
        store_split<2>(acc, H2h, H2l, T1, nh * 32, mh, lr, lq);
    }
    __syncthreads();
    {   // layer3: K=64, N=128 + per-group max, split output
        f32x4 acc[8];
        init_bias<4>(acc, b2, nh * 64, lr);
        mfma_layer<4, 2>(H2h, H2l, T1, w2h, w2l, 64, acc, nh * 64, mh, lr, lq);
#pragma unroll
        for (int nt = 0; nt < 4; nt++) {
            float v = 0.f;
#pragma unroll
            for (int mt = 0; mt < 2; mt++)
#pragma unroll
                for (int r = 0; r < 4; r++)
                    v = fmaxf(v, acc[mt * 4 + nt][r]);
            v = fmaxf(v, __shfl_xor(v, 16));
            v = fmaxf(v, __shfl_xor(v, 32));
            if (lane < 16) {
                short h, l;
                f2bfpair(v, h, l);
                size_t o = (size_t)(g0 + mh) * 128 + nh * 64 + nt * 16 + lane;
                feat1h[o] = h;
                feat1l[o] = l;
            }
        }
    }
}

// ---------------------------------------------------------------------------
// SA2 MFMA: consumes feat1 planes (feat-first layout), outputs a3 planes.
// ---------------------------------------------------------------------------
#define S1 168
#define S2 136
__global__ __launch_bounds__(256) void sa2_mfma_kernel(
    const float* __restrict__ xyz1,
    const short* __restrict__ feat1h, const short* __restrict__ feat1l,
    const float* __restrict__ newXyz, const int* __restrict__ idx,
    const short* __restrict__ w0h, const short* __restrict__ w0l,
    const float* __restrict__ b0,
    const short* __restrict__ w1h, const short* __restrict__ w1l,
    const float* __restrict__ b1,
    const short* __restrict__ w2h, const short* __restrict__ w2l,
    const float* __restrict__ b2,
    short* __restrict__ a3h, short* __restrict__ a3l) {
    const int g = blockIdx.x;
    const int b = g >> 7;
    const int t = threadIdx.x;
    const int lane = t & 63, wv = t >> 6;
    const int lr = lane & 15, lq = lane >> 4;
    const int mh = wv & 1, nh = wv >> 1;
    __shared__ short Ah[64 * S1], Al[64 * S1];
    __shared__ short Hh[64 * S2], Hl[64 * S2];
    __shared__ float pmax[2][256];
    __shared__ int ids[64];
    if (t < 64) ids[t] = idx[(size_t)g * 64 + t];
    __syncthreads();
    {   // gather: feat cols 0..127 via b128 plane copies; xyz at 128..130
        const int m = t >> 2, q = t & 3;
        const int id = ids[m];
        const size_t frow = ((size_t)b * 512 + id) * 128;
#pragma unroll
        for (int c8 = 0; c8 < 4; c8++) {
            const int k = q * 32 + c8 * 8;
            *(short8*)&Ah[m * S1 + k] = *(const short8*)(feat1h + frow + k);
            *(short8*)&Al[m * S1 + k] = *(const short8*)(feat1l + frow + k);
        }
        if (t < 64) {
            const int id2 = ids[t];
            short8 zz = {0, 0, 0, 0, 0, 0, 0, 0};
            *(short8*)&Ah[t * S1 + 128] = zz;
            *(short8*)&Ah[t * S1 + 136] = zz;
            *(short8*)&Ah[t * S1 + 144] = zz;
            *(short8*)&Ah[t * S1 + 152] = zz;
            *(short8*)&Al[t * S1 + 128] = zz;
            *(short8*)&Al[t * S1 + 136] = zz;
            *(short8*)&Al[t * S1 + 144] = zz;
            *(short8*)&Al[t * S1 + 152] = zz;
            const float* prow = xyz1 + ((size_t)b * 512 + id2) * 3;
            const float* crow = newXyz + (size_t)g * 3;
#pragma unroll
            for (int c = 0; c < 3; c++) {
                short h, l;
                f2bfpair(prow[c] - crow[c], h, l);
                Ah[t * S1 + 128 + c] = h;
                Al[t * S1 + 128 + c] = l;
            }
        }
    }
    __syncthreads();
    {   // layer1: K=160, N=128
        f32x4 acc[8];
        init_bias<4>(acc, b0, nh * 64, lr);
        mfma_layer<4, 5>(Ah, Al, S1, w0h, w0l, 160, acc, nh * 64, mh, lr, lq);
        store_split<4>(acc, Hh, Hl, S2, nh * 64, mh, lr, lq);
    }
    __syncthreads();
    {   // layer2: K=128, N=128
        f32x4 acc[8];
        init_bias<4>(acc, b1, nh * 64, lr);
        mfma_layer<4, 4>(Hh, Hl, S2, w1h, w1l, 128, acc, nh * 64, mh, lr, lq);
        store_split<4>(acc, Ah, Al, S2, nh * 64, mh, lr, lq);
    }
    __syncthreads();
    {   // layer3: K=128, N=256 + max over 64 rows
        f32x4 acc[16];
        init_bias<8>(acc, b2, nh * 128, lr);
        mfma_layer<8, 4>(Ah, Al, S2, w2h, w2l, 128, acc, nh * 128, mh, lr, lq);
#pragma unroll
        for (int nt = 0; nt < 8; nt++) {
            float v = 0.f;
#pragma unroll
            for (int mt = 0; mt < 2; mt++)
#pragma unroll
                for (int r = 0; r < 4; r++)
                    v = fmaxf(v, acc[mt * 8 + nt][r]);
            v = fmaxf(v, __shfl_xor(v, 16));
            v = fmaxf(v, __shfl_xor(v, 32));
            if (lane < 16) pmax[mh][nh * 128 + nt * 16 + lane] = v;
        }
    }
    __syncthreads();
    {   // write a3 row g: col 3+t = feat, cols 0..2 xyz, 259..287 zero
        float v = fmaxf(pmax[0][t], pmax[1][t]);
        short h, l;
        f2bfpair(v, h, l);
        a3h[(size_t)g * 288 + 3 + t] = h;
        a3l[(size_t)g * 288 + 3 + t] = l;
        if (t < 3) {
            f2bfpair(newXyz[(size_t)g * 3 + t], h, l);
            a3h[(size_t)g * 288 + t] = h;
            a3l[(size_t)g * 288 + t] = l;
        }
        if (t >= 227) {
            a3h[(size_t)g * 288 + t + 32] = 0;
            a3l[(size_t)g * 288 + t + 32] = 0;
        }
    }
}

// ---------------------------------------------------------------------------
// MFMA GEMM: A pre-split planes [M][Kp]; weights pre-split planes [N][Kp].
// OUT_MODE 1: relu + split-plane output.
// OUT_MODE 2: relu + per-column block max + atomicMax into gfeat (fused
//   maxpool; values >=0 so int-compare on float bits is order-correct;
//   gfeat zero-initialized via hipMemsetAsync).
// ---------------------------------------------------------------------------
template<int OUT_MODE>
__global__ __launch_bounds__(256) void mfma_gemm_kernel(
    const short* __restrict__ Agh, const short* __restrict__ Agl, const int Kp,
    const short* __restrict__ Wh, const short* __restrict__ Wl,
    const float* __restrict__ bias,
    float* __restrict__ outF, short* __restrict__ outH,
    short* __restrict__ outL, const int N) {
    const int t = threadIdx.x;
    const int lane = t & 63, wv = t >> 6;
    const int lr = lane & 15, lq = lane >> 4;
    const int mh = wv & 1, nh = wv >> 1;
    const int m0 = blockIdx.y * 64;
    const int n0 = blockIdx.x * 128 + nh * 64;
    __shared__ short Ah[64 * 40], Al[64 * 40];
    f32x4 acc[8];
#pragma unroll
    for (int nt = 0; nt < 4; nt++) {
        float bv = bias[n0 + nt * 16 + lr];
        f32x4 c = {bv, bv, bv, bv};
        acc[nt] = c; acc[4 + nt] = c;
    }
    const int srow = t >> 2, sk = (t & 3) * 8;
    for (int kt = 0; kt < Kp; kt += 32) {
        {   // stage A chunk: pure b128 copies (no conversion)
            const size_t src = (size_t)(m0 + srow) * Kp + kt + sk;
            *(short8*)&Ah[srow * 40 + sk] = *(const short8*)(Agh + src);
            *(short8*)&Al[srow * 40 + sk] = *(const short8*)(Agl + src);
        }
        __syncthreads();
        short8 a_h[2], a_l[2];
#pragma unroll
        for (int mt = 0; mt < 2; mt++) {
            const int m = mh * 32 + mt * 16 + lr;
            a_h[mt] = *(const short8*)&Ah[m * 40 + lq * 8];
            a_l[mt] = *(const short8*)&Al[m * 40 + lq * 8];
        }
#pragma unroll
        for (int nt = 0; nt < 4; nt++) {
            const int n = n0 + nt * 16 + lr;
            short8 b_h = *(const short8*)(Wh + (size_t)n * Kp + kt + lq * 8);
            short8 b_l = *(const short8*)(Wl + (size_t)n * Kp + kt + lq * 8);
#pragma unroll
            for (int mt = 0; mt < 2; mt++) {
                f32x4 c = acc[mt * 4 + nt];
                c = __builtin_amdgcn_mfma_f32_16x16x32_bf16(a_h[mt], b_h, c, 0, 0, 0);
                c = __builtin_amdgcn_mfma_f32_16x16x32_bf16(a_h[mt], b_l, c, 0, 0, 0);
                c = __builtin_amdgcn_mfma_f32_16x16x32_bf16(a_l[mt], b_h, c, 0, 0, 0);
                acc[mt * 4 + nt] = c;
            }
        }
        __syncthreads();
    }
    if (OUT_MODE == 2) {
        // fused maxpool: column max over this block's 64 rows -> atomicMax
        const int batch = blockIdx.y >> 1;   // 128 rows per batch, 64/block
#pragma unroll
        for (int nt = 0; nt < 4; nt++) {
            float v = 0.f;   // relu floor
#pragma unroll
            for (int mt = 0; mt < 2; mt++)
#pragma unroll
                for (int r = 0; r < 4; r++)
                    v = fmaxf(v, acc[mt * 4 + nt][r]);
            v = fmaxf(v, __shfl_xor(v, 16));   // reduce across lq (rows)
            v = fmaxf(v, __shfl_xor(v, 32));
            if (lane < 16)
                atomicMax((int*)&outF[(size_t)batch * N + n0 + nt * 16 + lane],
                          __float_as_int(v));
        }
        return;
    }
#pragma unroll
    for (int mt = 0; mt < 2; mt++)
#pragma unroll
        for (int nt = 0; nt < 4; nt++)
#pragma unroll
            for (int r = 0; r < 4; r++) {
                const int m = m0 + mh * 32 + mt * 16 + lq * 4 + r;
                const int n = n0 + nt * 16 + lr;
                float v = fmaxf(acc[mt * 4 + nt][r], 0.f);
                short h, l;
                f2bfpair(v, h, l);
                outH[(size_t)m * N + n] = h;
                outL[(size_t)m * N + n] = l;
            }
}

// ---------------------------------------------------------------------------
// FC layer: grid (O/(4*OPW), B), block 256.
// ---------------------------------------------------------------------------
template<int K, int OPW, int ACT>
__global__ __launch_bounds__(256) void fc_kernel(
    const float* __restrict__ in, const float* __restrict__ w,
    const float* __restrict__ bias, float* __restrict__ out, const int O) {
    const int batch = blockIdx.y;
    const int t = threadIdx.x, lane = t & 63, wv = t >> 6;
    __shared__ float f[K];
    for (int j = t; j < K; j += 256) f[j] = in[batch * K + j];
    __syncthreads();
    const int o0 = blockIdx.x * (4 * OPW) + wv * OPW;
#pragma unroll
    for (int i = 0; i < OPW; i++) {
        const int o = o0 + i;
        const float* wr = w + (size_t)o * K;
        float a = 0.f;
#pragma unroll
        for (int c = lane; c < K; c += 64) a = fmaf(wr[c], f[c], a);
#pragma unroll
        for (int off = 32; off > 0; off >>= 1) a += __shfl_xor(a, off);
        if (lane == 0) {
            float v = a + bias[o];
            out[batch * O + o] = ACT ? fmaxf(v, 0.f) : v;
        }
    }
}

// fc3 (256->40) + softmax fused; one block per batch.
__global__ __launch_bounds__(256) void fc3_softmax_kernel(
    const float* __restrict__ in, const float* __restrict__ w3,
    const float* __restrict__ b3, float* __restrict__ out) {
    const int b = blockIdx.x, t = threadIdx.x, lane = t & 63, wv = t >> 6;
    __shared__ float f[256];
    __shared__ float lg[40];
    f[t] = in[b * 256 + t];
    __syncthreads();
#pragma unroll
    for (int i = 0; i < 10; i++) {
        const int o = wv * 10 + i;
        const float* wr = w3 + (size_t)o * 256;
        float a = 0.f;
#pragma unroll
        for (int c = lane; c < 256; c += 64) a = fmaf(wr[c], f[c], a);
#pragma unroll
        for (int off = 32; off > 0; off >>= 1) a += __shfl_xor(a, off);
        if (lane == 0) lg[o] = a + b3[o];
    }
    __syncthreads();
    if (t < 64) {
        float v = (t < 40) ? lg[t] : -INFINITY;
        float m = v;
#pragma unroll
        for (int off = 32; off > 0; off >>= 1) m = fmaxf(m, __shfl_xor(m, off));
        float e = (t < 40) ? expf(v - m) : 0.f;
        float s = e;
#pragma unroll
        for (int off = 32; off > 0; off >>= 1) s += __shfl_xor(s, off);
        if (t < 40) out[b * 40 + t] = e / s;
    }
}

// ---------------------------------------------------------------------------
extern "C" void kernel_launch(void* const* d_in, const int* in_sizes, int n_in,
                              void* d_out, int out_size, void* d_ws, size_t ws_size,
                              hipStream_t stream) {
    (void)in_sizes; (void)n_in; (void)out_size; (void)ws_size;
    const float* x      = (const float*)d_in[0];
    const float* sa1w0  = (const float*)d_in[1];
    const float* sa1b0  = (const float*)d_in[2];
    const float* sa1w1  = (const float*)d_in[3];
    const float* sa1b1  = (const float*)d_in[4];
    const float* sa1w2  = (const float*)d_in[5];
    const float* sa1b2  = (const float*)d_in[6];
    const float* sa2w0  = (const float*)d_in[7];
    const float* sa2b0  = (const float*)d_in[8];
    const float* sa2w1  = (const float*)d_in[9];
    const float* sa2b1  = (const float*)d_in[10];
    const float* sa2w2  = (const float*)d_in[11];
    const float* sa2b2  = (const float*)d_in[12];
    const float* sa3w0  = (const float*)d_in[13];
    const float* sa3b0  = (const float*)d_in[14];
    const float* sa3w1  = (const float*)d_in[15];
    const float* sa3b1  = (const float*)d_in[16];
    const float* sa3w2  = (const float*)d_in[17];
    const float* sa3b2  = (const float*)d_in[18];
    const float* fc1w   = (const float*)d_in[19];
    const float* fc1b   = (const float*)d_in[20];
    const float* fc2w   = (const float*)d_in[21];
    const float* fc2b   = (const float*)d_in[22];
    const float* fc3w   = (const float*)d_in[23];
    const float* fc3b   = (const float*)d_in[24];
    float* outp = (float*)d_out;

    char* ws = (char*)d_ws;
    size_t off = 0;
    auto alloc = [&](size_t bytes) {
        void* p = ws + off;
        off += (bytes + 255) & ~(size_t)255;
        return p;
    };
    int*   fidx1   = (int*)  alloc((size_t)B_ * 512 * 4);
    float* nxyz1   = (float*)alloc((size_t)B_ * 512 * 3 * 4);
    int*   idx1    = (int*)  alloc((size_t)B_ * 512 * 32 * 4);
    short* feat1h  = (short*)alloc((size_t)B_ * 512 * 128 * 2);
    short* feat1l  = (short*)alloc((size_t)B_ * 512 * 128 * 2);
    int*   fidx2   = (int*)  alloc((size_t)B_ * 128 * 4);
    float* nxyz2   = (float*)alloc((size_t)B_ * 128 * 3 * 4);
    int*   idx2    = (int*)  alloc((size_t)B_ * 128 * 64 * 4);
    short* a3h     = (short*)alloc((size_t)4096 * 288 * 2);
    short* a3l     = (short*)alloc((size_t)4096 * 288 * 2);
    short* h3ah    = (short*)alloc((size_t)4096 * 256 * 2);
    short* h3al    = (short*)alloc((size_t)4096 * 256 * 2);
    short* h3bh    = (short*)alloc((size_t)4096 * 512 * 2);
    short* h3bl    = (short*)alloc((size_t)4096 * 512 * 2);
    float* gfeat   = (float*)alloc((size_t)B_ * 1024 * 4);
    float* h1      = (float*)alloc((size_t)B_ * 512 * 4);
    float* h2      = (float*)alloc((size_t)B_ * 256 * 4);
    // split-bf16 weight planes
    short* w1h_s1 = (short*)alloc((size_t)64 * 64 * 2);
    short* w1l_s1 = (short*)alloc((size_t)64 * 64 * 2);
    short* w2h_s1 = (short*)alloc((size_t)128 * 64 * 2);
    short* w2l_s1 = (short*)alloc((size_t)128 * 64 * 2);
    short* w0h_s2 = (short*)alloc((size_t)128 * 160 * 2);
    short* w0l_s2 = (short*)alloc((size_t)128 * 160 * 2);
    short* w1h_s2 = (short*)alloc((size_t)128 * 128 * 2);
    short* w1l_s2 = (short*)alloc((size_t)128 * 128 * 2);
    short* w2h_s2 = (short*)alloc((size_t)256 * 128 * 2);
    short* w2l_s2 = (short*)alloc((size_t)256 * 128 * 2);
    short* w0h_s3 = (short*)alloc((size_t)256 * 288 * 2);
    short* w0l_s3 = (short*)alloc((size_t)256 * 288 * 2);
    short* w1h_s3 = (short*)alloc((size_t)512 * 256 * 2);
    short* w1l_s3 = (short*)alloc((size_t)512 * 256 * 2);
    short* w2h_s3 = (short*)alloc((size_t)1024 * 512 * 2);
    short* w2l_s3 = (short*)alloc((size_t)1024 * 512 * 2);

    // merged weight prep (one launch); entry 2 (sa2w0) uses feat-first perm
    {
        WDescs W;
        const float* srcs[8] = {sa1w1, sa1w2, sa2w0, sa2w1, sa2w2, sa3w0, sa3w1, sa3w2};
        short* dhs[8] = {w1h_s1, w2h_s1, w0h_s2, w1h_s2, w2h_s2, w0h_s3, w1h_s3, w2h_s3};
        short* dls[8] = {w1l_s1, w2l_s1, w0l_s2, w1l_s2, w2l_s2, w0l_s3, w1l_s3, w2l_s3};
        int Rs[8]  = {64, 128, 128, 128, 256, 256, 512, 1024};
        int Cs[8]  = {64, 64, 131, 128, 128, 259, 256, 512};
        int Cps[8] = {64, 64, 160, 128, 128, 288, 256, 512};
        int blk = 0;
        for (int k = 0; k < 8; k++) {
            W.d[k] = {srcs[k], dhs[k], dls[k], Rs[k], Cs[k], Cps[k], blk,
                      (k == 2) ? 1 : 0};
            blk += (Rs[k] * Cps[k] + 255) / 256;
        }
        wprep_all_kernel<<<blk, 256, 0, stream>>>(W);
    }
    // zero gfeat for the fused-maxpool atomics (0x0 == 0.0f)
    hipMemsetAsync(gfeat, 0, (size_t)B_ * 1024 * 4, stream);

    // SA1
    fps_kernel<4096, 512, 256><<<B_, 256, 0, stream>>>(x, fidx1, nxyz1);
    ballquery_kernel<4096, 32><<<B_ * 512 / 4, 256, 0, stream>>>(
        x, nxyz1, idx1, 512, 0.04f);
    sa1_mfma_kernel<<<B_ * 512 / 2, 256, 0, stream>>>(
        x, nxyz1, idx1, sa1w0, sa1b0,
        w1h_s1, w1l_s1, sa1b1, w2h_s1, w2l_s1, sa1b2, feat1h, feat1l);
    // SA2
    fps_kernel<512, 128, 64><<<B_, 64, 0, stream>>>(nxyz1, fidx2, nxyz2);
    ballquery_kernel<512, 64><<<B_ * 128 / 4, 256, 0, stream>>>(
        nxyz1, nxyz2, idx2, 128, 0.16f);
    sa2_mfma_kernel<<<B_ * 128, 256, 0, stream>>>(
        nxyz1, feat1h, feat1l, nxyz2, idx2,
        w0h_s2, w0l_s2, sa2b0, w1h_s2, w1l_s2, sa2b1, w2h_s2, w2l_s2, sa2b2,
        a3h, a3l);
    // SA3 (group-all): 3 MFMA GEMMs on planes; gemm3 fuses the maxpool
    mfma_gemm_kernel<1><<<dim3(2, 64), 256, 0, stream>>>(
        a3h, a3l, 288, w0h_s3, w0l_s3, sa3b0, nullptr, h3ah, h3al, 256);
    mfma_gemm_kernel<1><<<dim3(4, 64), 256, 0, stream>>>(
        h3ah, h3al, 256, w1h_s3, w1l_s3, sa3b1, nullptr, h3bh, h3bl, 512);
    mfma_gemm_kernel<2><<<dim3(8, 64), 256, 0, stream>>>(
        h3bh, h3bl, 512, w2h_s3, w2l_s3, sa3b2, gfeat, nullptr, nullptr, 1024);
    // FC head: fc1 (1024->512), fc2 (512->256), fc3+softmax
    fc_kernel<1024, 16, 1><<<dim3(8, B_), 256, 0, stream>>>(
        gfeat, fc1w, fc1b, h1, 512);
    fc_kernel<512, 16, 1><<<dim3(4, B_), 256, 0, stream>>>(
        h1, fc2w, fc2b, h2, 256);
    fc3_softmax_kernel<<<B_, 256, 0, stream>>>(h2, fc3w, fc3b, outp);
}

// Round 12
// 1032.011 us; speedup vs baseline: 1.5889x; 1.0296x over previous
//
#include <hip/hip_runtime.h>
#include <math.h>

#define B_ 32
#define N_ 4096

typedef __attribute__((ext_vector_type(8))) short short8;
typedef __attribute__((ext_vector_type(4))) float f32x4;

// fp32 -> bf16 round-to-nearest-even, and split x = hi + lo (both bf16).
__device__ __forceinline__ unsigned short f2bf(float f) {
    unsigned u = __float_as_uint(f);
    unsigned r = 0x7FFFu + ((u >> 16) & 1u);
    return (unsigned short)((u + r) >> 16);
}
__device__ __forceinline__ float bf2f(unsigned short h) {
    return __uint_as_float(((unsigned)h) << 16);
}
__device__ __forceinline__ void f2bfpair(float v, short& h, short& l) {
    unsigned short hh = f2bf(v);
    h = (short)hh;
    l = (short)f2bf(v - bf2f(hh));
}

// ---------------------------------------------------------------------------
// Packed argmax: key = (float_bits(dist) << 32) | ~idx. dist >= 0 so float
// bits are monotone as unsigned; u64 max picks max dist, min idx on tie —
// bit-identical to reference first-index argmax. Keys are always > 0, so
// u64max with 0 (DPP bound_ctrl fill) is identity.
// ---------------------------------------------------------------------------
__device__ __forceinline__ unsigned long long u64max(unsigned long long a,
                                                     unsigned long long b) {
    return a > b ? a : b;
}
template<int CTRL>
__device__ __forceinline__ unsigned long long dpp_u64(unsigned long long k) {
    int lo = __builtin_amdgcn_mov_dpp((int)(unsigned)k, CTRL, 0xf, 0xf, true);
    int hi = __builtin_amdgcn_mov_dpp((int)(unsigned)(k >> 32), CTRL, 0xf, 0xf, true);
    return ((unsigned long long)(unsigned)hi << 32) | (unsigned)lo;
}
// All-lanes result (xor stages are ds_swizzle round-trips; used only where
// every lane needs the answer, i.e. single-wave fps2).
__device__ __forceinline__ unsigned long long wave_argmax_u64(unsigned long long key) {
    key = u64max(key, dpp_u64<0x128>(key));   // row_ror:8
    key = u64max(key, dpp_u64<0x124>(key));   // row_ror:4
    key = u64max(key, dpp_u64<0x122>(key));   // row_ror:2
    key = u64max(key, dpp_u64<0x121>(key));   // row_ror:1
    key = u64max(key, __shfl_xor(key, 16));
    key = u64max(key, __shfl_xor(key, 32));
    return key;
}
// Leader-only result in LANE 63, pure DPP (no LDS swizzle on the serial
// path): row_ror reduce within rows, then row_bcast15/31 across rows.
__device__ __forceinline__ unsigned long long wave_argmax_u64_leader(unsigned long long key) {
    key = u64max(key, dpp_u64<0x128>(key));   // row_ror:8
    key = u64max(key, dpp_u64<0x124>(key));   // row_ror:4
    key = u64max(key, dpp_u64<0x122>(key));   // row_ror:2
    key = u64max(key, dpp_u64<0x121>(key));   // row_ror:1
    key = u64max(key, dpp_u64<0x142>(key));   // row_bcast15
    key = u64max(key, dpp_u64<0x143>(key));   // row_bcast31 -> lane 63
    return key;
}

// ---------------------------------------------------------------------------
// FPS: one block per batch, exact fp32 math (index-critical). NT ladder
// measured: 128=591, 256=344 (best), 512=363. Interleaved ps[N][4] LDS:
// winner coords via one broadcast ds_read_b128. Leader (lane 63) posts the
// wave key; one barrier per iteration; t==0 streams outputs.
// ---------------------------------------------------------------------------
template<int N, int NPOINT, int NT>
__global__ __launch_bounds__(NT, 1) void fps_kernel(
    const float* __restrict__ xyz,
    int* __restrict__ outIdx,
    float* __restrict__ outXyz) {
#pragma clang fp contract(off)
    const int b = blockIdx.x;
    const int t = threadIdx.x;
    constexpr int PPT = N / NT;
    constexpr int NW = (NT + 63) / 64;
    __shared__ float ps[N][4];
    __shared__ unsigned long long red[2][NW];
    const float* base = xyz + (size_t)b * N * 3;
    for (int j = t; j < N; j += NT) {
        ps[j][0] = base[j * 3 + 0];
        ps[j][1] = base[j * 3 + 1];
        ps[j][2] = base[j * 3 + 2];
    }
    __syncthreads();
    float px[PPT], py[PPT], pz[PPT], mind[PPT];
    unsigned notp[PPT];
#pragma unroll
    for (int i = 0; i < PPT; i++) {
        int p = t + i * NT;
        f32x4 c4 = *(const f32x4*)&ps[p][0];
        px[i] = c4[0]; py[i] = c4[1]; pz[i] = c4[2];
        mind[i] = 1e10f;
        notp[i] = ~(unsigned)p;
    }
#pragma unroll
    for (int i = 0; i < PPT; i++)
        asm volatile("" : "+v"(px[i]), "+v"(py[i]), "+v"(pz[i]));
    float lx = ps[0][0], ly = ps[0][1], lz = ps[0][2];
    if (t == 0) {
        outIdx[b * NPOINT] = 0;
        outXyz[(size_t)b * NPOINT * 3 + 0] = lx;
        outXyz[(size_t)b * NPOINT * 3 + 1] = ly;
        outXyz[(size_t)b * NPOINT * 3 + 2] = lz;
    }
    for (int it = 1; it < NPOINT; it++) {
        unsigned long long key = 0;
#pragma unroll
        for (int i = 0; i < PPT; i++) {
            float dx = px[i] - lx, dy = py[i] - ly, dz = pz[i] - lz;
            float t0 = dx * dx, t1 = dy * dy, t2 = dz * dz;
            float d = (t0 + t1) + t2;
            float m = fminf(mind[i], d);
            mind[i] = m;
            unsigned long long k =
                ((unsigned long long)__float_as_uint(m) << 32) | notp[i];
            key = u64max(key, k);
        }
        int fi;
        if constexpr (NT > 64) {
            key = wave_argmax_u64_leader(key);
            const int par = it & 1;
            if ((t & 63) == 63) red[par][t >> 6] = key;
            __syncthreads();
            unsigned long long best = red[par][0];
#pragma unroll
            for (int w = 1; w < NW; w++) best = u64max(best, red[par][w]);
            fi = (int)(~(unsigned)best);
        } else {
            key = wave_argmax_u64(key);
            fi = (int)(~(unsigned)key);
        }
        f32x4 c4 = *(const f32x4*)&ps[fi][0];
        lx = c4[0]; ly = c4[1]; lz = c4[2];
        if (t == 0) {
            outIdx[b * NPOINT + it] = fi;
            outXyz[((size_t)b * NPOINT + it) * 3 + 0] = lx;
            outXyz[((size_t)b * NPOINT + it) * 3 + 1] = ly;
            outXyz[((size_t)b * NPOINT + it) * 3 + 2] = lz;
        }
    }
}

// ---------------------------------------------------------------------------
// Ball query: wave-per-query (ballot/mbcnt), exact fp32 math.
// ---------------------------------------------------------------------------
template<int N, int NS>
__global__ __launch_bounds__(256) void ballquery_kernel(
    const float* __restrict__ xyz, const float* __restrict__ newXyz,
    int* __restrict__ outIdx, int S, float r2) {
#pragma clang fp contract(off)
    const int qid = blockIdx.x * 4 + (threadIdx.x >> 6);
    const int lane = threadIdx.x & 63;
    const int b = qid / S;
    const float* q = newXyz + (size_t)qid * 3;
    const float qx = q[0], qy = q[1], qz = q[2];
    const float qn = (qx * qx + qy * qy) + qz * qz;
    const float* base = xyz + (size_t)b * N * 3;
    int* dst = outIdx + (size_t)qid * NS;
    int cnt = 0, first = 0;
    for (int p0 = 0; p0 < N; p0 += 64) {
        const int p = p0 + lane;
        const float x = base[p * 3 + 0];
        const float y = base[p * 3 + 1];
        const float z = base[p * 3 + 2];
        const float pn = (x * x + y * y) + z * z;
        const float dot = (qx * x + qy * y) + qz * z;
        const float sqd = (qn + pn) - 2.0f * dot;
        const unsigned long long mask = __ballot(sqd <= r2);
        if (mask) {
            if (cnt == 0) first = p0 + __ffsll((unsigned long long)mask) - 1;
            const int prefix = __builtin_amdgcn_mbcnt_hi(
                (unsigned)(mask >> 32),
                __builtin_amdgcn_mbcnt_lo((unsigned)mask, 0));
            const bool in = (mask >> lane) & 1ull;
            const int pos = cnt + prefix;
            if (in && pos < NS) dst[pos] = p;
            cnt += __popcll(mask);
            if (cnt >= NS) break;
        }
    }
    for (int i = cnt + lane; i < NS; i += 64) dst[i] = first;
}

// ---------------------------------------------------------------------------
// Weight prep (merged): split 8 fp32 [R][C] mats into bf16 hi/lo [R][Cp].
// perm=1 (sa2w0): column remap feat-first to match sa2's activation layout.
// ---------------------------------------------------------------------------
struct WDesc { const float* src; short* dh; short* dl; int R, C, Cp, blk0, perm; };
struct WDescs { WDesc d[8]; };

__global__ void wprep_all_kernel(WDescs W) {
    const int blk = blockIdx.x;
    int di = 0;
#pragma unroll
    for (int k = 1; k < 8; k++) di = (blk >= W.d[k].blk0) ? k : di;
    const WDesc D = W.d[di];
    const int i = (blk - D.blk0) * 256 + threadIdx.x;
    if (i >= D.R * D.Cp) return;
    const int r = i / D.Cp, c = i % D.Cp;
    int cs;
    if (D.perm) cs = (c < 128) ? c + 3 : (c < 131 ? c - 128 : -1);
    else        cs = (c < D.C) ? c : -1;
    float v = (cs >= 0) ? D.src[r * D.C + cs] : 0.f;
    short h, l;
    f2bfpair(v, h, l);
    D.dh[i] = h; D.dl[i] = l;
}

// ---------------------------------------------------------------------------
// MFMA helpers (verified gfx950 16x16x32 bf16 layouts).
// Split fp32 = hi+lo bf16: D += Ah*Bh + Ah*Bl + Al*Bh
// ---------------------------------------------------------------------------
template<int NT, int KS>
__device__ __forceinline__ void mfma_layer(
    const short* Aph, const short* Apl, const int sA,
    const short* __restrict__ Wph, const short* __restrict__ Wpl, const int sW,
    f32x4* acc, const int n0, const int mh, const int lr, const int lq) {
#pragma unroll
    for (int ks = 0; ks < KS; ks++) {
        const int ka = ks * 32 + lq * 8;
        short8 a_h[2], a_l[2];
#pragma unroll
        for (int mt = 0; mt < 2; mt++) {
            const int m = (mh * 2 + mt) * 16 + lr;
            a_h[mt] = *(const short8*)(Aph + m * sA + ka);
            a_l[mt] = *(const short8*)(Apl + m * sA + ka);
        }
#pragma unroll
        for (int nt = 0; nt < NT; nt++) {
            const int n = n0 + nt * 16 + lr;
            short8 b_h = *(const short8*)(Wph + (size_t)n * sW + ka);
            short8 b_l = *(const short8*)(Wpl + (size_t)n * sW + ka);
#pragma unroll
            for (int mt = 0; mt < 2; mt++) {
                f32x4 c = acc[mt * NT + nt];
                c = __builtin_amdgcn_mfma_f32_16x16x32_bf16(a_h[mt], b_h, c, 0, 0, 0);
                c = __builtin_amdgcn_mfma_f32_16x16x32_bf16(a_h[mt], b_l, c, 0, 0, 0);
                c = __builtin_amdgcn_mfma_f32_16x16x32_bf16(a_l[mt], b_h, c, 0, 0, 0);
                acc[mt * NT + nt] = c;
            }
        }
    }
}

template<int NT>
__device__ __forceinline__ void init_bias(f32x4* acc, const float* __restrict__ bias,
                                          const int n0, const int lr) {
#pragma unroll
    for (int nt = 0; nt < NT; nt++) {
        float bv = bias[n0 + nt * 16 + lr];
        f32x4 c = {bv, bv, bv, bv};
        acc[0 * NT + nt] = c;
        acc[1 * NT + nt] = c;
    }
}

template<int NT>
__device__ __forceinline__ void store_split(
    const f32x4* acc, short* Hp, short* Lp, const int stride,
    const int n0, const int mh, const int lr, const int lq) {
#pragma unroll
    for (int mt = 0; mt < 2; mt++)
#pragma unroll
        for (int nt = 0; nt < NT; nt++)
#pragma unroll
            for (int r = 0; r < 4; r++) {
                float v = fmaxf(acc[mt * NT + nt][r], 0.f);
                short h, l;
                f2bfpair(v, h, l);
                const int m = (mh * 2 + mt) * 16 + lq * 4 + r;
                const int n = n0 + nt * 16 + lr;
                Hp[m * stride + n] = h;
                Lp[m * stride + n] = l;
            }
}

// ---------------------------------------------------------------------------
// SA1 MFMA: outputs feat1 as split bf16 planes (producer-side split).
// ---------------------------------------------------------------------------
#define T1 72
__global__ __launch_bounds__(256) void sa1_mfma_kernel(
    const float* __restrict__ x, const float* __restrict__ nxyz1,
    const int* __restrict__ idx,
    const float* __restrict__ w0, const float* __restrict__ b0,
    const short* __restrict__ w1h, const short* __restrict__ w1l,
    const float* __restrict__ b1,
    const short* __restrict__ w2h, const short* __restrict__ w2l,
    const float* __restrict__ b2,
    short* __restrict__ feat1h, short* __restrict__ feat1l) {
    const int g0 = blockIdx.x * 2;
    const int b = g0 >> 9;
    const int t = threadIdx.x;
    const int lane = t & 63, wv = t >> 6;
    const int lr = lane & 15, lq = lane >> 4;
    const int mh = wv & 1, nh = wv >> 1;
    __shared__ float gx[64][4];
    __shared__ short H1h[64 * T1], H1l[64 * T1];
    __shared__ short H2h[64 * T1], H2l[64 * T1];
    if (t < 64) {
        int g = g0 + (t >> 5);
        int id = idx[(size_t)g * 32 + (t & 31)];
        const float* pp = x + ((size_t)b * N_ + id) * 3;
        const float* cc = nxyz1 + (size_t)g * 3;
        gx[t][0] = pp[0] - cc[0];
        gx[t][1] = pp[1] - cc[1];
        gx[t][2] = pp[2] - cc[2];
    }
    __syncthreads();
    {   // layer1 K=3 via VALU
        const int m = t >> 2, oc = (t & 3) * 16;
        float a0 = gx[m][0], a1 = gx[m][1], a2 = gx[m][2];
        short8 hv0, hv1, lv0, lv1;
#pragma unroll
        for (int i = 0; i < 16; i++) {
            int o = oc + i;
            float v = fmaf(w0[o * 3 + 0], a0,
                      fmaf(w0[o * 3 + 1], a1,
                      fmaf(w0[o * 3 + 2], a2, b0[o])));
            v = fmaxf(v, 0.f);
            short h, l;
            f2bfpair(v, h, l);
            if (i < 8) { hv0[i] = h; lv0[i] = l; }
            else       { hv1[i - 8] = h; lv1[i - 8] = l; }
        }
        *(short8*)&H1h[m * T1 + oc]     = hv0;
        *(short8*)&H1h[m * T1 + oc + 8] = hv1;
        *(short8*)&H1l[m * T1 + oc]     = lv0;
        *(short8*)&H1l[m * T1 + oc + 8] = lv1;
    }
    __syncthreads();
    {   // layer2: K=64, N=64
        f32x4 acc[4];
        init_bias<2>(acc, b1, nh * 32, lr);
        mfma_layer<2, 2>(H1h, H1l, T1, w1h, w1l, 64, acc, nh * 32, mh, lr, lq);
        store_split<2>(acc, H2h, H2l, T1, nh * 32, mh, lr, lq);
    }
    __syncthreads();
    {   // layer3: K=64, N=128 + per-group max, split output
        f32x4 acc[8];
        init_bias<4>(acc, b2, nh * 64, lr);
        mfma_layer<4, 2>(H2h, H2l, T1, w2h, w2l, 64, acc, nh * 64, mh, lr, lq);
#pragma unroll
        for (int nt = 0; nt < 4; nt++) {
            float v = 0.f;
#pragma unroll
            for (int mt = 0; mt < 2; mt++)
#pragma unroll
                for (int r = 0; r < 4; r++)
                    v = fmaxf(v, acc[mt * 4 + nt][r]);
            v = fmaxf(v, __shfl_xor(v, 16));
            v = fmaxf(v, __shfl_xor(v, 32));
            if (lane < 16) {
                short h, l;
                f2bfpair(v, h, l);
                size_t o = (size_t)(g0 + mh) * 128 + nh * 64 + nt * 16 + lane;
                feat1h[o] = h;
                feat1l[o] = l;
            }
        }
    }
}

// ---------------------------------------------------------------------------
// SA2 MFMA: consumes feat1 planes (feat-first layout), outputs a3 planes.
// ---------------------------------------------------------------------------
#define S1 168
#define S2 136
__global__ __launch_bounds__(256) void sa2_mfma_kernel(
    const float* __restrict__ xyz1,
    const short* __restrict__ feat1h, const short* __restrict__ feat1l,
    const float* __restrict__ newXyz, const int* __restrict__ idx,
    const short* __restrict__ w0h, const short* __restrict__ w0l,
    const float* __restrict__ b0,
    const short* __restrict__ w1h, const short* __restrict__ w1l,
    const float* __restrict__ b1,
    const short* __restrict__ w2h, const short* __restrict__ w2l,
    const float* __restrict__ b2,
    short* __restrict__ a3h, short* __restrict__ a3l) {
    const int g = blockIdx.x;
    const int b = g >> 7;
    const int t = threadIdx.x;
    const int lane = t & 63, wv = t >> 6;
    const int lr = lane & 15, lq = lane >> 4;
    const int mh = wv & 1, nh = wv >> 1;
    __shared__ short Ah[64 * S1], Al[64 * S1];
    __shared__ short Hh[64 * S2], Hl[64 * S2];
    __shared__ float pmax[2][256];
    __shared__ int ids[64];
    if (t < 64) ids[t] = idx[(size_t)g * 64 + t];
    __syncthreads();
    {   // gather: feat cols 0..127 via b128 plane copies; xyz at 128..130
        const int m = t >> 2, q = t & 3;
        const int id = ids[m];
        const size_t frow = ((size_t)b * 512 + id) * 128;
#pragma unroll
        for (int c8 = 0; c8 < 4; c8++) {
            const int k = q * 32 + c8 * 8;
            *(short8*)&Ah[m * S1 + k] = *(const short8*)(feat1h + frow + k);
            *(short8*)&Al[m * S1 + k] = *(const short8*)(feat1l + frow + k);
        }
        if (t < 64) {
            const int id2 = ids[t];
            short8 zz = {0, 0, 0, 0, 0, 0, 0, 0};
            *(short8*)&Ah[t * S1 + 128] = zz;
            *(short8*)&Ah[t * S1 + 136] = zz;
            *(short8*)&Ah[t * S1 + 144] = zz;
            *(short8*)&Ah[t * S1 + 152] = zz;
            *(short8*)&Al[t * S1 + 128] = zz;
            *(short8*)&Al[t * S1 + 136] = zz;
            *(short8*)&Al[t * S1 + 144] = zz;
            *(short8*)&Al[t * S1 + 152] = zz;
            const float* prow = xyz1 + ((size_t)b * 512 + id2) * 3;
            const float* crow = newXyz + (size_t)g * 3;
#pragma unroll
            for (int c = 0; c < 3; c++) {
                short h, l;
                f2bfpair(prow[c] - crow[c], h, l);
                Ah[t * S1 + 128 + c] = h;
                Al[t * S1 + 128 + c] = l;
            }
        }
    }
    __syncthreads();
    {   // layer1: K=160, N=128
        f32x4 acc[8];
        init_bias<4>(acc, b0, nh * 64, lr);
        mfma_layer<4, 5>(Ah, Al, S1, w0h, w0l, 160, acc, nh * 64, mh, lr, lq);
        store_split<4>(acc, Hh, Hl, S2, nh * 64, mh, lr, lq);
    }
    __syncthreads();
    {   // layer2: K=128, N=128
        f32x4 acc[8];
        init_bias<4>(acc, b1, nh * 64, lr);
        mfma_layer<4, 4>(Hh, Hl, S2, w1h, w1l, 128, acc, nh * 64, mh, lr, lq);
        store_split<4>(acc, Ah, Al, S2, nh * 64, mh, lr, lq);
    }
    __syncthreads();
    {   // layer3: K=128, N=256 + max over 64 rows
        f32x4 acc[16];
        init_bias<8>(acc, b2, nh * 128, lr);
        mfma_layer<8, 4>(Ah, Al, S2, w2h, w2l, 128, acc, nh * 128, mh, lr, lq);
#pragma unroll
        for (int nt = 0; nt < 8; nt++) {
            float v = 0.f;
#pragma unroll
            for (int mt = 0; mt < 2; mt++)
#pragma unroll
                for (int r = 0; r < 4; r++)
                    v = fmaxf(v, acc[mt * 8 + nt][r]);
            v = fmaxf(v, __shfl_xor(v, 16));
            v = fmaxf(v, __shfl_xor(v, 32));
            if (lane < 16) pmax[mh][nh * 128 + nt * 16 + lane] = v;
        }
    }
    __syncthreads();
    {   // write a3 row g: col 3+t = feat, cols 0..2 xyz, 259..287 zero
        float v = fmaxf(pmax[0][t], pmax[1][t]);
        short h, l;
        f2bfpair(v, h, l);
        a3h[(size_t)g * 288 + 3 + t] = h;
        a3l[(size_t)g * 288 + 3 + t] = l;
        if (t < 3) {
            f2bfpair(newXyz[(size_t)g * 3 + t], h, l);
            a3h[(size_t)g * 288 + t] = h;
            a3l[(size_t)g * 288 + t] = l;
        }
        if (t >= 227) {
            a3h[(size_t)g * 288 + t + 32] = 0;
            a3l[(size_t)g * 288 + t + 32] = 0;
        }
    }
}

// ---------------------------------------------------------------------------
// MFMA GEMM: A pre-split planes [M][Kp]; weights pre-split planes [N][Kp].
// OUT_MODE 1: relu + split-plane output.
// OUT_MODE 2: relu + per-column block max + atomicMax into gfeat (fused
//   maxpool; values >=0 so int-compare on float bits is order-correct).
// ---------------------------------------------------------------------------
template<int OUT_MODE>
__global__ __launch_bounds__(256) void mfma_gemm_kernel(
    const short* __restrict__ Agh, const short* __restrict__ Agl, const int Kp,
    const short* __restrict__ Wh, const short* __restrict__ Wl,
    const float* __restrict__ bias,
    float* __restrict__ outF, short* __restrict__ outH,
    short* __restrict__ outL, const int N) {
    const int t = threadIdx.x;
    const int lane = t & 63, wv = t >> 6;
    const int lr = lane & 15, lq = lane >> 4;
    const int mh = wv & 1, nh = wv >> 1;
    const int m0 = blockIdx.y * 64;
    const int n0 = blockIdx.x * 128 + nh * 64;
    __shared__ short Ah[64 * 40], Al[64 * 40];
    f32x4 acc[8];
#pragma unroll
    for (int nt = 0; nt < 4; nt++) {
        float bv = bias[n0 + nt * 16 + lr];
        f32x4 c = {bv, bv, bv, bv};
        acc[nt] = c; acc[4 + nt] = c;
    }
    const int srow = t >> 2, sk = (t & 3) * 8;
    for (int kt = 0; kt < Kp; kt += 32) {
        {   // stage A chunk: pure b128 copies (no conversion)
            const size_t src = (size_t)(m0 + srow) * Kp + kt + sk;
            *(short8*)&Ah[srow * 40 + sk] = *(const short8*)(Agh + src);
            *(short8*)&Al[srow * 40 + sk] = *(const short8*)(Agl + src);
        }
        __syncthreads();
        short8 a_h[2], a_l[2];
#pragma unroll
        for (int mt = 0; mt < 2; mt++) {
            const int m = mh * 32 + mt * 16 + lr;
            a_h[mt] = *(const short8*)&Ah[m * 40 + lq * 8];
            a_l[mt] = *(const short8*)&Al[m * 40 + lq * 8];
        }
#pragma unroll
        for (int nt = 0; nt < 4; nt++) {
            const int n = n0 + nt * 16 + lr;
            short8 b_h = *(const short8*)(Wh + (size_t)n * Kp + kt + lq * 8);
            short8 b_l = *(const short8*)(Wl + (size_t)n * Kp + kt + lq * 8);
#pragma unroll
            for (int mt = 0; mt < 2; mt++) {
                f32x4 c = acc[mt * 4 + nt];
                c = __builtin_amdgcn_mfma_f32_16x16x32_bf16(a_h[mt], b_h, c, 0, 0, 0);
                c = __builtin_amdgcn_mfma_f32_16x16x32_bf16(a_h[mt], b_l, c, 0, 0, 0);
                c = __builtin_amdgcn_mfma_f32_16x16x32_bf16(a_l[mt], b_h, c, 0, 0, 0);
                acc[mt * 4 + nt] = c;
            }
        }
        __syncthreads();
    }
    if (OUT_MODE == 2) {
        const int batch = blockIdx.y >> 1;
#pragma unroll
        for (int nt = 0; nt < 4; nt++) {
            float v = 0.f;
#pragma unroll
            for (int mt = 0; mt < 2; mt++)
#pragma unroll
                for (int r = 0; r < 4; r++)
                    v = fmaxf(v, acc[mt * 4 + nt][r]);
            v = fmaxf(v, __shfl_xor(v, 16));
            v = fmaxf(v, __shfl_xor(v, 32));
            if (lane < 16)
                atomicMax((int*)&outF[(size_t)batch * N + n0 + nt * 16 + lane],
                          __float_as_int(v));
        }
        return;
    }
#pragma unroll
    for (int mt = 0; mt < 2; mt++)
#pragma unroll
        for (int nt = 0; nt < 4; nt++)
#pragma unroll
            for (int r = 0; r < 4; r++) {
                const int m = m0 + mh * 32 + mt * 16 + lq * 4 + r;
                const int n = n0 + nt * 16 + lr;
                float v = fmaxf(acc[mt * 4 + nt][r], 0.f);
                short h, l;
                f2bfpair(v, h, l);
                outH[(size_t)m * N + n] = h;
                outL[(size_t)m * N + n] = l;
            }
}

// ---------------------------------------------------------------------------
// FC layer: grid (O/(4*OPW), B), block 256.
// ---------------------------------------------------------------------------
template<int K, int OPW, int ACT>
__global__ __launch_bounds__(256) void fc_kernel(
    const float* __restrict__ in, const float* __restrict__ w,
    const float* __restrict__ bias, float* __restrict__ out, const int O) {
    const int batch = blockIdx.y;
    const int t = threadIdx.x, lane = t & 63, wv = t >> 6;
    __shared__ float f[K];
    for (int j = t; j < K; j += 256) f[j] = in[batch * K + j];
    __syncthreads();
    const int o0 = blockIdx.x * (4 * OPW) + wv * OPW;
#pragma unroll
    for (int i = 0; i < OPW; i++) {
        const int o = o0 + i;
        const float* wr = w + (size_t)o * K;
        float a = 0.f;
#pragma unroll
        for (int c = lane; c < K; c += 64) a = fmaf(wr[c], f[c], a);
#pragma unroll
        for (int off = 32; off > 0; off >>= 1) a += __shfl_xor(a, off);
        if (lane == 0) {
            float v = a + bias[o];
            out[batch * O + o] = ACT ? fmaxf(v, 0.f) : v;
        }
    }
}

// fc3 (256->40) + softmax fused; one block per batch.
__global__ __launch_bounds__(256) void fc3_softmax_kernel(
    const float* __restrict__ in, const float* __restrict__ w3,
    const float* __restrict__ b3, float* __restrict__ out) {
    const int b = blockIdx.x, t = threadIdx.x, lane = t & 63, wv = t >> 6;
    __shared__ float f[256];
    __shared__ float lg[40];
    f[t] = in[b * 256 + t];
    __syncthreads();
#pragma unroll
    for (int i = 0; i < 10; i++) {
        const int o = wv * 10 + i;
        const float* wr = w3 + (size_t)o * 256;
        float a = 0.f;
#pragma unroll
        for (int c = lane; c < 256; c += 64) a = fmaf(wr[c], f[c], a);
#pragma unroll
        for (int off = 32; off > 0; off >>= 1) a += __shfl_xor(a, off);
        if (lane == 0) lg[o] = a + b3[o];
    }
    __syncthreads();
    if (t < 64) {
        float v = (t < 40) ? lg[t] : -INFINITY;
        float m = v;
#pragma unroll
        for (int off = 32; off > 0; off >>= 1) m = fmaxf(m, __shfl_xor(m, off));
        float e = (t < 40) ? expf(v - m) : 0.f;
        float s = e;
#pragma unroll
        for (int off = 32; off > 0; off >>= 1) s += __shfl_xor(s, off);
        if (t < 40) out[b * 40 + t] = e / s;
    }
}

// ---------------------------------------------------------------------------
extern "C" void kernel_launch(void* const* d_in, const int* in_sizes, int n_in,
                              void* d_out, int out_size, void* d_ws, size_t ws_size,
                              hipStream_t stream) {
    (void)in_sizes; (void)n_in; (void)out_size; (void)ws_size;
    const float* x      = (const float*)d_in[0];
    const float* sa1w0  = (const float*)d_in[1];
    const float* sa1b0  = (const float*)d_in[2];
    const float* sa1w1  = (const float*)d_in[3];
    const float* sa1b1  = (const float*)d_in[4];
    const float* sa1w2  = (const float*)d_in[5];
    const float* sa1b2  = (const float*)d_in[6];
    const float* sa2w0  = (const float*)d_in[7];
    const float* sa2b0  = (const float*)d_in[8];
    const float* sa2w1  = (const float*)d_in[9];
    const float* sa2b1  = (const float*)d_in[10];
    const float* sa2w2  = (const float*)d_in[11];
    const float* sa2b2  = (const float*)d_in[12];
    const float* sa3w0  = (const float*)d_in[13];
    const float* sa3b0  = (const float*)d_in[14];
    const float* sa3w1  = (const float*)d_in[15];
    const float* sa3b1  = (const float*)d_in[16];
    const float* sa3w2  = (const float*)d_in[17];
    const float* sa3b2  = (const float*)d_in[18];
    const float* fc1w   = (const float*)d_in[19];
    const float* fc1b   = (const float*)d_in[20];
    const float* fc2w   = (const float*)d_in[21];
    const float* fc2b   = (const float*)d_in[22];
    const float* fc3w   = (const float*)d_in[23];
    const float* fc3b   = (const float*)d_in[24];
    float* outp = (float*)d_out;

    char* ws = (char*)d_ws;
    size_t off = 0;
    auto alloc = [&](size_t bytes) {
        void* p = ws + off;
        off += (bytes + 255) & ~(size_t)255;
        return p;
    };
    int*   fidx1   = (int*)  alloc((size_t)B_ * 512 * 4);
    float* nxyz1   = (float*)alloc((size_t)B_ * 512 * 3 * 4);
    int*   idx1    = (int*)  alloc((size_t)B_ * 512 * 32 * 4);
    short* feat1h  = (short*)alloc((size_t)B_ * 512 * 128 * 2);
    short* feat1l  = (short*)alloc((size_t)B_ * 512 * 128 * 2);
    int*   fidx2   = (int*)  alloc((size_t)B_ * 128 * 4);
    float* nxyz2   = (float*)alloc((size_t)B_ * 128 * 3 * 4);
    int*   idx2    = (int*)  alloc((size_t)B_ * 128 * 64 * 4);
    short* a3h     = (short*)alloc((size_t)4096 * 288 * 2);
    short* a3l     = (short*)alloc((size_t)4096 * 288 * 2);
    short* h3ah    = (short*)alloc((size_t)4096 * 256 * 2);
    short* h3al    = (short*)alloc((size_t)4096 * 256 * 2);
    short* h3bh    = (short*)alloc((size_t)4096 * 512 * 2);
    short* h3bl    = (short*)alloc((size_t)4096 * 512 * 2);
    float* gfeat   = (float*)alloc((size_t)B_ * 1024 * 4);
    float* h1      = (float*)alloc((size_t)B_ * 512 * 4);
    float* h2      = (float*)alloc((size_t)B_ * 256 * 4);
    // split-bf16 weight planes
    short* w1h_s1 = (short*)alloc((size_t)64 * 64 * 2);
    short* w1l_s1 = (short*)alloc((size_t)64 * 64 * 2);
    short* w2h_s1 = (short*)alloc((size_t)128 * 64 * 2);
    short* w2l_s1 = (short*)alloc((size_t)128 * 64 * 2);
    short* w0h_s2 = (short*)alloc((size_t)128 * 160 * 2);
    short* w0l_s2 = (short*)alloc((size_t)128 * 160 * 2);
    short* w1h_s2 = (short*)alloc((size_t)128 * 128 * 2);
    short* w1l_s2 = (short*)alloc((size_t)128 * 128 * 2);
    short* w2h_s2 = (short*)alloc((size_t)256 * 128 * 2);
    short* w2l_s2 = (short*)alloc((size_t)256 * 128 * 2);
    short* w0h_s3 = (short*)alloc((size_t)256 * 288 * 2);
    short* w0l_s3 = (short*)alloc((size_t)256 * 288 * 2);
    short* w1h_s3 = (short*)alloc((size_t)512 * 256 * 2);
    short* w1l_s3 = (short*)alloc((size_t)512 * 256 * 2);
    short* w2h_s3 = (short*)alloc((size_t)1024 * 512 * 2);
    short* w2l_s3 = (short*)alloc((size_t)1024 * 512 * 2);

    // merged weight prep (one launch); entry 2 (sa2w0) uses feat-first perm
    {
        WDescs W;
        const float* srcs[8] = {sa1w1, sa1w2, sa2w0, sa2w1, sa2w2, sa3w0, sa3w1, sa3w2};
        short* dhs[8] = {w1h_s1, w2h_s1, w0h_s2, w1h_s2, w2h_s2, w0h_s3, w1h_s3, w2h_s3};
        short* dls[8] = {w1l_s1, w2l_s1, w0l_s2, w1l_s2, w2l_s2, w0l_s3, w1l_s3, w2l_s3};
        int Rs[8]  = {64, 128, 128, 128, 256, 256, 512, 1024};
        int Cs[8]  = {64, 64, 131, 128, 128, 259, 256, 512};
        int Cps[8] = {64, 64, 160, 128, 128, 288, 256, 512};
        int blk = 0;
        for (int k = 0; k < 8; k++) {
            W.d[k] = {srcs[k], dhs[k], dls[k], Rs[k], Cs[k], Cps[k], blk,
                      (k == 2) ? 1 : 0};
            blk += (Rs[k] * Cps[k] + 255) / 256;
        }
        wprep_all_kernel<<<blk, 256, 0, stream>>>(W);
    }
    // zero gfeat for the fused-maxpool atomics (0x0 == 0.0f)
    hipMemsetAsync(gfeat, 0, (size_t)B_ * 1024 * 4, stream);

    // SA1
    fps_kernel<4096, 512, 256><<<B_, 256, 0, stream>>>(x, fidx1, nxyz1);
    ballquery_kernel<4096, 32><<<B_ * 512 / 4, 256, 0, stream>>>(
        x, nxyz1, idx1, 512, 0.04f);
    sa1_mfma_kernel<<<B_ * 512 / 2, 256, 0, stream>>>(
        x, nxyz1, idx1, sa1w0, sa1b0,
        w1h_s1, w1l_s1, sa1b1, w2h_s1, w2l_s1, sa1b2, feat1h, feat1l);
    // SA2
    fps_kernel<512, 128, 64><<<B_, 64, 0, stream>>>(nxyz1, fidx2, nxyz2);
    ballquery_kernel<512, 64><<<B_ * 128 / 4, 256, 0, stream>>>(
        nxyz1, nxyz2, idx2, 128, 0.16f);
    sa2_mfma_kernel<<<B_ * 128, 256, 0, stream>>>(
        nxyz1, feat1h, feat1l, nxyz2, idx2,
        w0h_s2, w0l_s2, sa2b0, w1h_s2, w1l_s2, sa2b1, w2h_s2, w2l_s2, sa2b2,
        a3h, a3l);
    // SA3 (group-all): 3 MFMA GEMMs on planes; gemm3 fuses the maxpool
    mfma_gemm_kernel<1><<<dim3(2, 64), 256, 0, stream>>>(
        a3h, a3l, 288, w0h_s3, w0l_s3, sa3b0, nullptr, h3ah, h3al, 256);
    mfma_gemm_kernel<1><<<dim3(4, 64), 256, 0, stream>>>(
        h3ah, h3al, 256, w1h_s3, w1l_s3, sa3b1, nullptr, h3bh, h3bl, 512);
    mfma_gemm_kernel<2><<<dim3(8, 64), 256, 0, stream>>>(
        h3bh, h3bl, 512, w2h_s3, w2l_s3, sa3b2, gfeat, nullptr, nullptr, 1024);
    // FC head: fc1 (1024->512), fc2 (512->256), fc3+softmax
    fc_kernel<1024, 16, 1><<<dim3(8, B_), 256, 0, stream>>>(
        gfeat, fc1w, fc1b, h1, 512);
    fc_kernel<512, 16, 1><<<dim3(4, B_), 256, 0, stream>>>(
        h1, fc2w, fc2b, h2, 256);
    fc3_softmax_kernel<<<B_, 256, 0, stream>>>(h2, fc3w, fc3b, outp);
}

// Round 13
// 999.780 us; speedup vs baseline: 1.6401x; 1.0322x over previous
//
#include <hip/hip_runtime.h>
#include <math.h>

#define B_ 32
#define N_ 4096

typedef __attribute__((ext_vector_type(8))) short short8;
typedef __attribute__((ext_vector_type(4))) float f32x4;

// fp32 -> bf16 round-to-nearest-even, and split x = hi + lo (both bf16).
__device__ __forceinline__ unsigned short f2bf(float f) {
    unsigned u = __float_as_uint(f);
    unsigned r = 0x7FFFu + ((u >> 16) & 1u);
    return (unsigned short)((u + r) >> 16);
}
__device__ __forceinline__ float bf2f(unsigned short h) {
    return __uint_as_float(((unsigned)h) << 16);
}
__device__ __forceinline__ void f2bfpair(float v, short& h, short& l) {
    unsigned short hh = f2bf(v);
    h = (short)hh;
    l = (short)f2bf(v - bf2f(hh));
}

// ---------------------------------------------------------------------------
// Packed argmax: key = (float_bits(dist) << 32) | ~idx. dist >= 0 so float
// bits are monotone as unsigned; u64 max picks max dist, min idx on tie —
// bit-identical to reference first-index argmax. Keys are always > 0, so
// u64max with 0 (DPP bound_ctrl fill) is identity.
// ---------------------------------------------------------------------------
__device__ __forceinline__ unsigned long long u64max(unsigned long long a,
                                                     unsigned long long b) {
    return a > b ? a : b;
}
template<int CTRL>
__device__ __forceinline__ unsigned long long dpp_u64(unsigned long long k) {
    int lo = __builtin_amdgcn_mov_dpp((int)(unsigned)k, CTRL, 0xf, 0xf, true);
    int hi = __builtin_amdgcn_mov_dpp((int)(unsigned)(k >> 32), CTRL, 0xf, 0xf, true);
    return ((unsigned long long)(unsigned)hi << 32) | (unsigned)lo;
}
// All-lanes result (xor stages are ds_swizzle round-trips; used only where
// every lane needs the answer, i.e. single-wave fps2).
__device__ __forceinline__ unsigned long long wave_argmax_u64(unsigned long long key) {
    key = u64max(key, dpp_u64<0x128>(key));   // row_ror:8
    key = u64max(key, dpp_u64<0x124>(key));   // row_ror:4
    key = u64max(key, dpp_u64<0x122>(key));   // row_ror:2
    key = u64max(key, dpp_u64<0x121>(key));   // row_ror:1
    key = u64max(key, __shfl_xor(key, 16));
    key = u64max(key, __shfl_xor(key, 32));
    return key;
}
// Leader-only result in LANE 63, pure DPP (no LDS swizzle on the serial
// path): row_ror reduce within rows, then row_bcast15/31 across rows.
__device__ __forceinline__ unsigned long long wave_argmax_u64_leader(unsigned long long key) {
    key = u64max(key, dpp_u64<0x128>(key));   // row_ror:8
    key = u64max(key, dpp_u64<0x124>(key));   // row_ror:4
    key = u64max(key, dpp_u64<0x122>(key));   // row_ror:2
    key = u64max(key, dpp_u64<0x121>(key));   // row_ror:1
    key = u64max(key, dpp_u64<0x142>(key));   // row_bcast15
    key = u64max(key, dpp_u64<0x143>(key));   // row_bcast31 -> lane 63
    return key;
}

// ---------------------------------------------------------------------------
// FPS stage 1: one block per batch, exact fp32 math (index-critical).
// NT ladder measured: 128=591, 256=344, 512=363 -> NT=256. Interleaved
// ps[N][4]: coords via one broadcast ds_read_b128. Lane-63 leader posts the
// wave key; one barrier/iter; t==0 streams outputs. FPS indices are unused
// downstream (reference only uses gathered coords) -> no outIdx.
// ---------------------------------------------------------------------------
template<int N, int NPOINT, int NT>
__global__ __launch_bounds__(NT, 1) void fps_kernel(
    const float* __restrict__ xyz, float* __restrict__ outXyz) {
#pragma clang fp contract(off)
    const int b = blockIdx.x;
    const int t = threadIdx.x;
    constexpr int PPT = N / NT;
    constexpr int NW = (NT + 63) / 64;
    __shared__ float ps[N][4];
    __shared__ unsigned long long red[2][NW];
    const float* base = xyz + (size_t)b * N * 3;
    for (int j = t; j < N; j += NT) {
        ps[j][0] = base[j * 3 + 0];
        ps[j][1] = base[j * 3 + 1];
        ps[j][2] = base[j * 3 + 2];
    }
    __syncthreads();
    float px[PPT], py[PPT], pz[PPT], mind[PPT];
    unsigned notp[PPT];
#pragma unroll
    for (int i = 0; i < PPT; i++) {
        int p = t + i * NT;
        f32x4 c4 = *(const f32x4*)&ps[p][0];
        px[i] = c4[0]; py[i] = c4[1]; pz[i] = c4[2];
        mind[i] = 1e10f;
        notp[i] = ~(unsigned)p;
    }
#pragma unroll
    for (int i = 0; i < PPT; i++)
        asm volatile("" : "+v"(px[i]), "+v"(py[i]), "+v"(pz[i]));
    float lx = ps[0][0], ly = ps[0][1], lz = ps[0][2];
    if (t == 0) {
        outXyz[(size_t)b * NPOINT * 3 + 0] = lx;
        outXyz[(size_t)b * NPOINT * 3 + 1] = ly;
        outXyz[(size_t)b * NPOINT * 3 + 2] = lz;
    }
    for (int it = 1; it < NPOINT; it++) {
        unsigned long long key = 0;
#pragma unroll
        for (int i = 0; i < PPT; i++) {
            float dx = px[i] - lx, dy = py[i] - ly, dz = pz[i] - lz;
            float t0 = dx * dx, t1 = dy * dy, t2 = dz * dz;
            float d = (t0 + t1) + t2;
            float m = fminf(mind[i], d);
            mind[i] = m;
            unsigned long long k =
                ((unsigned long long)__float_as_uint(m) << 32) | notp[i];
            key = u64max(key, k);
        }
        key = wave_argmax_u64_leader(key);
        const int par = it & 1;
        if ((t & 63) == 63) red[par][t >> 6] = key;
        __syncthreads();
        unsigned long long best = red[par][0];
#pragma unroll
        for (int w = 1; w < NW; w++) best = u64max(best, red[par][w]);
        const int fi = (int)(~(unsigned)best);
        f32x4 c4 = *(const f32x4*)&ps[fi][0];
        lx = c4[0]; ly = c4[1]; lz = c4[2];
        if (t == 0) {
            outXyz[((size_t)b * NPOINT + it) * 3 + 0] = lx;
            outXyz[((size_t)b * NPOINT + it) * 3 + 1] = ly;
            outXyz[((size_t)b * NPOINT + it) * 3 + 2] = lz;
        }
    }
}

// ---------------------------------------------------------------------------
// Ball-query body: wave-per-query (ballot/mbcnt), exact fp32 math.
// ---------------------------------------------------------------------------
template<int N, int NS>
__device__ __forceinline__ void ballquery_body(
    const float* __restrict__ xyz, const float* __restrict__ newXyz,
    int* __restrict__ outIdx, int S, float r2, int qid, int lane) {
#pragma clang fp contract(off)
    const int b = qid / S;
    const float* q = newXyz + (size_t)qid * 3;
    const float qx = q[0], qy = q[1], qz = q[2];
    const float qn = (qx * qx + qy * qy) + qz * qz;
    const float* base = xyz + (size_t)b * N * 3;
    int* dst = outIdx + (size_t)qid * NS;
    int cnt = 0, first = 0;
    for (int p0 = 0; p0 < N; p0 += 64) {
        const int p = p0 + lane;
        const float x = base[p * 3 + 0];
        const float y = base[p * 3 + 1];
        const float z = base[p * 3 + 2];
        const float pn = (x * x + y * y) + z * z;
        const float dot = (qx * x + qy * y) + qz * z;
        const float sqd = (qn + pn) - 2.0f * dot;
        const unsigned long long mask = __ballot(sqd <= r2);
        if (mask) {
            if (cnt == 0) first = p0 + __ffsll((unsigned long long)mask) - 1;
            const int prefix = __builtin_amdgcn_mbcnt_hi(
                (unsigned)(mask >> 32),
                __builtin_amdgcn_mbcnt_lo((unsigned)mask, 0));
            const bool in = (mask >> lane) & 1ull;
            const int pos = cnt + prefix;
            if (in && pos < NS) dst[pos] = p;
            cnt += __popcll(mask);
            if (cnt >= NS) break;
        }
    }
    for (int i = cnt + lane; i < NS; i += 64) dst[i] = first;
}

// ---------------------------------------------------------------------------
// Merged launch: blocks [0, BQB) = ballquery1 (x -> idx1), blocks
// [BQB, BQB+B_) = fps stage 2 (nxyz1 -> nxyz2). fps2 only needs nxyz1 —
// independent of bq1 — so packing them hides fps2's 32-block serial tail.
// ---------------------------------------------------------------------------
template<int BQB, int NQ, int NS, int SQ, int NF, int NPF>
__global__ __launch_bounds__(256) void bq_fps_kernel(
    const float* __restrict__ xyzQ, const float* __restrict__ newXyzQ,
    int* __restrict__ outIdxQ, float r2,
    const float* __restrict__ xyzF, float* __restrict__ outXyzF) {
#pragma clang fp contract(off)
    const int t = threadIdx.x;
    const int lane = t & 63, wv = t >> 6;
    __shared__ float ps[NF][4];
    if (blockIdx.x < BQB) {
        ballquery_body<NQ, NS>(xyzQ, newXyzQ, outIdxQ, SQ, r2,
                               blockIdx.x * 4 + wv, lane);
        return;
    }
    // ---- fps2: single-wave serial FPS over NF points ----
    const int b = blockIdx.x - BQB;
    const float* base = xyzF + (size_t)b * NF * 3;
    for (int j = t; j < NF; j += 256) {
        ps[j][0] = base[j * 3 + 0];
        ps[j][1] = base[j * 3 + 1];
        ps[j][2] = base[j * 3 + 2];
    }
    __syncthreads();
    if (t >= 64) return;
    constexpr int PPT = NF / 64;
    float px[PPT], py[PPT], pz[PPT], mind[PPT];
    unsigned notp[PPT];
#pragma unroll
    for (int i = 0; i < PPT; i++) {
        int p = t + i * 64;
        f32x4 c4 = *(const f32x4*)&ps[p][0];
        px[i] = c4[0]; py[i] = c4[1]; pz[i] = c4[2];
        mind[i] = 1e10f;
        notp[i] = ~(unsigned)p;
    }
    float lx = ps[0][0], ly = ps[0][1], lz = ps[0][2];
    if (t == 0) {
        outXyzF[(size_t)b * NPF * 3 + 0] = lx;
        outXyzF[(size_t)b * NPF * 3 + 1] = ly;
        outXyzF[(size_t)b * NPF * 3 + 2] = lz;
    }
    for (int it = 1; it < NPF; it++) {
        unsigned long long key = 0;
#pragma unroll
        for (int i = 0; i < PPT; i++) {
            float dx = px[i] - lx, dy = py[i] - ly, dz = pz[i] - lz;
            float t0 = dx * dx, t1 = dy * dy, t2 = dz * dz;
            float d = (t0 + t1) + t2;
            float m = fminf(mind[i], d);
            mind[i] = m;
            unsigned long long k =
                ((unsigned long long)__float_as_uint(m) << 32) | notp[i];
            key = u64max(key, k);
        }
        key = wave_argmax_u64(key);
        const int fi = (int)(~(unsigned)key);
        f32x4 c4 = *(const f32x4*)&ps[fi][0];
        lx = c4[0]; ly = c4[1]; lz = c4[2];
        if (t == 0) {
            outXyzF[((size_t)b * NPF + it) * 3 + 0] = lx;
            outXyzF[((size_t)b * NPF + it) * 3 + 1] = ly;
            outXyzF[((size_t)b * NPF + it) * 3 + 2] = lz;
        }
    }
}

// ---------------------------------------------------------------------------
// Weight prep (merged): split 8 fp32 [R][C] mats into bf16 hi/lo [R][Cp].
// perm=1 (sa2w0): column remap feat-first to match sa2's activation layout.
// ---------------------------------------------------------------------------
struct WDesc { const float* src; short* dh; short* dl; int R, C, Cp, blk0, perm; };
struct WDescs { WDesc d[8]; };

__global__ void wprep_all_kernel(WDescs W) {
    const int blk = blockIdx.x;
    int di = 0;
#pragma unroll
    for (int k = 1; k < 8; k++) di = (blk >= W.d[k].blk0) ? k : di;
    const WDesc D = W.d[di];
    const int i = (blk - D.blk0) * 256 + threadIdx.x;
    if (i >= D.R * D.Cp) return;
    const int r = i / D.Cp, c = i % D.Cp;
    int cs;
    if (D.perm) cs = (c < 128) ? c + 3 : (c < 131 ? c - 128 : -1);
    else        cs = (c < D.C) ? c : -1;
    float v = (cs >= 0) ? D.src[r * D.C + cs] : 0.f;
    short h, l;
    f2bfpair(v, h, l);
    D.dh[i] = h; D.dl[i] = l;
}

// ---------------------------------------------------------------------------
// MFMA helpers (verified gfx950 16x16x32 bf16 layouts).
// Split fp32 = hi+lo bf16: D += Ah*Bh + Ah*Bl + Al*Bh
// ---------------------------------------------------------------------------
template<int NT, int KS>
__device__ __forceinline__ void mfma_layer(
    const short* Aph, const short* Apl, const int sA,
    const short* __restrict__ Wph, const short* __restrict__ Wpl, const int sW,
    f32x4* acc, const int n0, const int mh, const int lr, const int lq) {
#pragma unroll
    for (int ks = 0; ks < KS; ks++) {
        const int ka = ks * 32 + lq * 8;
        short8 a_h[2], a_l[2];
#pragma unroll
        for (int mt = 0; mt < 2; mt++) {
            const int m = (mh * 2 + mt) * 16 + lr;
            a_h[mt] = *(const short8*)(Aph + m * sA + ka);
            a_l[mt] = *(const short8*)(Apl + m * sA + ka);
        }
#pragma unroll
        for (int nt = 0; nt < NT; nt++) {
            const int n = n0 + nt * 16 + lr;
            short8 b_h = *(const short8*)(Wph + (size_t)n * sW + ka);
            short8 b_l = *(const short8*)(Wpl + (size_t)n * sW + ka);
#pragma unroll
            for (int mt = 0; mt < 2; mt++) {
                f32x4 c = acc[mt * NT + nt];
                c = __builtin_amdgcn_mfma_f32_16x16x32_bf16(a_h[mt], b_h, c, 0, 0, 0);
                c = __builtin_amdgcn_mfma_f32_16x16x32_bf16(a_h[mt], b_l, c, 0, 0, 0);
                c = __builtin_amdgcn_mfma_f32_16x16x32_bf16(a_l[mt], b_h, c, 0, 0, 0);
                acc[mt * NT + nt] = c;
            }
        }
    }
}

template<int NT>
__device__ __forceinline__ void init_bias(f32x4* acc, const float* __restrict__ bias,
                                          const int n0, const int lr) {
#pragma unroll
    for (int nt = 0; nt < NT; nt++) {
        float bv = bias[n0 + nt * 16 + lr];
        f32x4 c = {bv, bv, bv, bv};
        acc[0 * NT + nt] = c;
        acc[1 * NT + nt] = c;
    }
}

template<int NT>
__device__ __forceinline__ void store_split(
    const f32x4* acc, short* Hp, short* Lp, const int stride,
    const int n0, const int mh, const int lr, const int lq) {
#pragma unroll
    for (int mt = 0; mt < 2; mt++)
#pragma unroll
        for (int nt = 0; nt < NT; nt++)
#pragma unroll
            for (int r = 0; r < 4; r++) {
                float v = fmaxf(acc[mt * NT + nt][r], 0.f);
                short h, l;
                f2bfpair(v, h, l);
                const int m = (mh * 2 + mt) * 16 + lq * 4 + r;
                const int n = n0 + nt * 16 + lr;
                Hp[m * stride + n] = h;
                Lp[m * stride + n] = l;
            }
}

// ---------------------------------------------------------------------------
// SA1 MFMA (+ merged ballquery2 tail blocks): blocks [0, SAB) run sa1;
// blocks [SAB, SAB+256) run bq2 (needs only nxyz1/nxyz2, both ready).
// ---------------------------------------------------------------------------
#define T1 72
template<int SAB>
__global__ __launch_bounds__(256) void sa1_bq2_kernel(
    const float* __restrict__ x, const float* __restrict__ nxyz1,
    const int* __restrict__ idx,
    const float* __restrict__ w0, const float* __restrict__ b0,
    const short* __restrict__ w1h, const short* __restrict__ w1l,
    const float* __restrict__ b1,
    const short* __restrict__ w2h, const short* __restrict__ w2l,
    const float* __restrict__ b2,
    short* __restrict__ feat1h, short* __restrict__ feat1l,
    const float* __restrict__ nxyz2, int* __restrict__ idx2, float r2q) {
    const int t = threadIdx.x;
    const int lane = t & 63, wv = t >> 6;
    if (blockIdx.x >= SAB) {   // ballquery2: N=512, NS=64, S=128
        ballquery_body<512, 64>(nxyz1, nxyz2, idx2, 128, r2q,
                                (blockIdx.x - SAB) * 4 + wv, lane);
        return;
    }
    const int g0 = blockIdx.x * 2;
    const int b = g0 >> 9;
    const int lr = lane & 15, lq = lane >> 4;
    const int mh = wv & 1, nh = wv >> 1;
    __shared__ float gx[64][4];
    __shared__ short H1h[64 * T1], H1l[64 * T1];
    __shared__ short H2h[64 * T1], H2l[64 * T1];
    if (t < 64) {
        int g = g0 + (t >> 5);
        int id = idx[(size_t)g * 32 + (t & 31)];
        const float* pp = x + ((size_t)b * N_ + id) * 3;
        const float* cc = nxyz1 + (size_t)g * 3;
        gx[t][0] = pp[0] - cc[0];
        gx[t][1] = pp[1] - cc[1];
        gx[t][2] = pp[2] - cc[2];
    }
    __syncthreads();
    {   // layer1 K=3 via VALU
        const int m = t >> 2, oc = (t & 3) * 16;
        float a0 = gx[m][0], a1 = gx[m][1], a2 = gx[m][2];
        short8 hv0, hv1, lv0, lv1;
#pragma unroll
        for (int i = 0; i < 16; i++) {
            int o = oc + i;
            float v = fmaf(w0[o * 3 + 0], a0,
                      fmaf(w0[o * 3 + 1], a1,
                      fmaf(w0[o * 3 + 2], a2, b0[o])));
            v = fmaxf(v, 0.f);
            short h, l;
            f2bfpair(v, h, l);
            if (i < 8) { hv0[i] = h; lv0[i] = l; }
            else       { hv1[i - 8] = h; lv1[i - 8] = l; }
        }
        *(short8*)&H1h[m * T1 + oc]     = hv0;
        *(short8*)&H1h[m * T1 + oc + 8] = hv1;
        *(short8*)&H1l[m * T1 + oc]     = lv0;
        *(short8*)&H1l[m * T1 + oc + 8] = lv1;
    }
    __syncthreads();
    {   // layer2: K=64, N=64
        f32x4 acc[4];
        init_bias<2>(acc, b1, nh * 32, lr);
        mfma_layer<2, 2>(H1h, H1l, T1, w1h, w1l, 64, acc, nh * 32, mh, lr, lq);
        store_split<2>(acc, H2h, H2l, T1, nh * 32, mh, lr, lq);
    }
    __syncthreads();
    {   // layer3: K=64, N=128 + per-group max, split output
        f32x4 acc[8];
        init_bias<4>(acc, b2, nh * 64, lr);
        mfma_layer<4, 2>(H2h, H2l, T1, w2h, w2l, 64, acc, nh * 64, mh, lr, lq);
#pragma unroll
        for (int nt = 0; nt < 4; nt++) {
            float v = 0.f;
#pragma unroll
            for (int mt = 0; mt < 2; mt++)
#pragma unroll
                for (int r = 0; r < 4; r++)
                    v = fmaxf(v, acc[mt * 4 + nt][r]);
            v = fmaxf(v, __shfl_xor(v, 16));
            v = fmaxf(v, __shfl_xor(v, 32));
            if (lane < 16) {
                short h, l;
                f2bfpair(v, h, l);
                size_t o = (size_t)(g0 + mh) * 128 + nh * 64 + nt * 16 + lane;
                feat1h[o] = h;
                feat1l[o] = l;
            }
        }
    }
}

// ---------------------------------------------------------------------------
// SA2 MFMA: consumes feat1 planes (feat-first layout), outputs a3 planes.
// ---------------------------------------------------------------------------
#define S1 168
#define S2 136
__global__ __launch_bounds__(256) void sa2_mfma_kernel(
    const float* __restrict__ xyz1,
    const short* __restrict__ feat1h, const short* __restrict__ feat1l,
    const float* __restrict__ newXyz, const int* __restrict__ idx,
    const short* __restrict__ w0h, const short* __restrict__ w0l,
    const float* __restrict__ b0,
    const short* __restrict__ w1h, const short* __restrict__ w1l,
    const float* __restrict__ b1,
    const short* __restrict__ w2h, const short* __restrict__ w2l,
    const float* __restrict__ b2,
    short* __restrict__ a3h, short* __restrict__ a3l) {
    const int g = blockIdx.x;
    const int b = g >> 7;
    const int t = threadIdx.x;
    const int lane = t & 63, wv = t >> 6;
    const int lr = lane & 15, lq = lane >> 4;
    const int mh = wv & 1, nh = wv >> 1;
    __shared__ short Ah[64 * S1], Al[64 * S1];
    __shared__ short Hh[64 * S2], Hl[64 * S2];
    __shared__ float pmax[2][256];
    __shared__ int ids[64];
    if (t < 64) ids[t] = idx[(size_t)g * 64 + t];
    __syncthreads();
    {   // gather: feat cols 0..127 via b128 plane copies; xyz at 128..130
        const int m = t >> 2, q = t & 3;
        const int id = ids[m];
        const size_t frow = ((size_t)b * 512 + id) * 128;
#pragma unroll
        for (int c8 = 0; c8 < 4; c8++) {
            const int k = q * 32 + c8 * 8;
            *(short8*)&Ah[m * S1 + k] = *(const short8*)(feat1h + frow + k);
            *(short8*)&Al[m * S1 + k] = *(const short8*)(feat1l + frow + k);
        }
        if (t < 64) {
            const int id2 = ids[t];
            short8 zz = {0, 0, 0, 0, 0, 0, 0, 0};
            *(short8*)&Ah[t * S1 + 128] = zz;
            *(short8*)&Ah[t * S1 + 136] = zz;
            *(short8*)&Ah[t * S1 + 144] = zz;
            *(short8*)&Ah[t * S1 + 152] = zz;
            *(short8*)&Al[t * S1 + 128] = zz;
            *(short8*)&Al[t * S1 + 136] = zz;
            *(short8*)&Al[t * S1 + 144] = zz;
            *(short8*)&Al[t * S1 + 152] = zz;
            const float* prow = xyz1 + ((size_t)b * 512 + id2) * 3;
            const float* crow = newXyz + (size_t)g * 3;
#pragma unroll
            for (int c = 0; c < 3; c++) {
                short h, l;
                f2bfpair(prow[c] - crow[c], h, l);
                Ah[t * S1 + 128 + c] = h;
                Al[t * S1 + 128 + c] = l;
            }
        }
    }
    __syncthreads();
    {   // layer1: K=160, N=128
        f32x4 acc[8];
        init_bias<4>(acc, b0, nh * 64, lr);
        mfma_layer<4, 5>(Ah, Al, S1, w0h, w0l, 160, acc, nh * 64, mh, lr, lq);
        store_split<4>(acc, Hh, Hl, S2, nh * 64, mh, lr, lq);
    }
    __syncthreads();
    {   // layer2: K=128, N=128
        f32x4 acc[8];
        init_bias<4>(acc, b1, nh * 64, lr);
        mfma_layer<4, 4>(Hh, Hl, S2, w1h, w1l, 128, acc, nh * 64, mh, lr, lq);
        store_split<4>(acc, Ah, Al, S2, nh * 64, mh, lr, lq);
    }
    __syncthreads();
    {   // layer3: K=128, N=256 + max over 64 rows
        f32x4 acc[16];
        init_bias<8>(acc, b2, nh * 128, lr);
        mfma_layer<8, 4>(Ah, Al, S2, w2h, w2l, 128, acc, nh * 128, mh, lr, lq);
#pragma unroll
        for (int nt = 0; nt < 8; nt++) {
            float v = 0.f;
#pragma unroll
            for (int mt = 0; mt < 2; mt++)
#pragma unroll
                for (int r = 0; r < 4; r++)
                    v = fmaxf(v, acc[mt * 8 + nt][r]);
            v = fmaxf(v, __shfl_xor(v, 16));
            v = fmaxf(v, __shfl_xor(v, 32));
            if (lane < 16) pmax[mh][nh * 128 + nt * 16 + lane] = v;
        }
    }
    __syncthreads();
    {   // write a3 row g: col 3+t = feat, cols 0..2 xyz, 259..287 zero
        float v = fmaxf(pmax[0][t], pmax[1][t]);
        short h, l;
        f2bfpair(v, h, l);
        a3h[(size_t)g * 288 + 3 + t] = h;
        a3l[(size_t)g * 288 + 3 + t] = l;
        if (t < 3) {
            f2bfpair(newXyz[(size_t)g * 3 + t], h, l);
            a3h[(size_t)g * 288 + t] = h;
            a3l[(size_t)g * 288 + t] = l;
        }
        if (t >= 227) {
            a3h[(size_t)g * 288 + t + 32] = 0;
            a3l[(size_t)g * 288 + t + 32] = 0;
        }
    }
}

// ---------------------------------------------------------------------------
// MFMA GEMM: A pre-split planes [M][Kp]; weights pre-split planes [N][Kp].
// OUT_MODE 1: relu + split-plane output.
// OUT_MODE 2: relu + per-column block max + atomicMax into gfeat (fused
//   maxpool; values >=0 so int-compare on float bits is order-correct).
// ---------------------------------------------------------------------------
template<int OUT_MODE>
__global__ __launch_bounds__(256) void mfma_gemm_kernel(
    const short* __restrict__ Agh, const short* __restrict__ Agl, const int Kp,
    const short* __restrict__ Wh, const short* __restrict__ Wl,
    const float* __restrict__ bias,
    float* __restrict__ outF, short* __restrict__ outH,
    short* __restrict__ outL, const int N) {
    const int t = threadIdx.x;
    const int lane = t & 63, wv = t >> 6;
    const int lr = lane & 15, lq = lane >> 4;
    const int mh = wv & 1, nh = wv >> 1;
    const int m0 = blockIdx.y * 64;
    const int n0 = blockIdx.x * 128 + nh * 64;
    __shared__ short Ah[64 * 40], Al[64 * 40];
    f32x4 acc[8];
#pragma unroll
    for (int nt = 0; nt < 4; nt++) {
        float bv = bias[n0 + nt * 16 + lr];
        f32x4 c = {bv, bv, bv, bv};
        acc[nt] = c; acc[4 + nt] = c;
    }
    const int srow = t >> 2, sk = (t & 3) * 8;
    for (int kt = 0; kt < Kp; kt += 32) {
        {   // stage A chunk: pure b128 copies (no conversion)
            const size_t src = (size_t)(m0 + srow) * Kp + kt + sk;
            *(short8*)&Ah[srow * 40 + sk] = *(const short8*)(Agh + src);
            *(short8*)&Al[srow * 40 + sk] = *(const short8*)(Agl + src);
        }
        __syncthreads();
        short8 a_h[2], a_l[2];
#pragma unroll
        for (int mt = 0; mt < 2; mt++) {
            const int m = mh * 32 + mt * 16 + lr;
            a_h[mt] = *(const short8*)&Ah[m * 40 + lq * 8];
            a_l[mt] = *(const short8*)&Al[m * 40 + lq * 8];
        }
#pragma unroll
        for (int nt = 0; nt < 4; nt++) {
            const int n = n0 + nt * 16 + lr;
            short8 b_h = *(const short8*)(Wh + (size_t)n * Kp + kt + lq * 8);
            short8 b_l = *(const short8*)(Wl + (size_t)n * Kp + kt + lq * 8);
#pragma unroll
            for (int mt = 0; mt < 2; mt++) {
                f32x4 c = acc[mt * 4 + nt];
                c = __builtin_amdgcn_mfma_f32_16x16x32_bf16(a_h[mt], b_h, c, 0, 0, 0);
                c = __builtin_amdgcn_mfma_f32_16x16x32_bf16(a_h[mt], b_l, c, 0, 0, 0);
                c = __builtin_amdgcn_mfma_f32_16x16x32_bf16(a_l[mt], b_h, c, 0, 0, 0);
                acc[mt * 4 + nt] = c;
            }
        }
        __syncthreads();
    }
    if (OUT_MODE == 2) {
        const int batch = blockIdx.y >> 1;
#pragma unroll
        for (int nt = 0; nt < 4; nt++) {
            float v = 0.f;
#pragma unroll
            for (int mt = 0; mt < 2; mt++)
#pragma unroll
                for (int r = 0; r < 4; r++)
                    v = fmaxf(v, acc[mt * 4 + nt][r]);
            v = fmaxf(v, __shfl_xor(v, 16));
            v = fmaxf(v, __shfl_xor(v, 32));
            if (lane < 16)
                atomicMax((int*)&outF[(size_t)batch * N + n0 + nt * 16 + lane],
                          __float_as_int(v));
        }
        return;
    }
#pragma unroll
    for (int mt = 0; mt < 2; mt++)
#pragma unroll
        for (int nt = 0; nt < 4; nt++)
#pragma unroll
            for (int r = 0; r < 4; r++) {
                const int m = m0 + mh * 32 + mt * 16 + lq * 4 + r;
                const int n = n0 + nt * 16 + lr;
                float v = fmaxf(acc[mt * 4 + nt][r], 0.f);
                short h, l;
                f2bfpair(v, h, l);
                outH[(size_t)m * N + n] = h;
                outL[(size_t)m * N + n] = l;
            }
}

// ---------------------------------------------------------------------------
// FC layer: grid (O/(4*OPW), B), block 256.
// ---------------------------------------------------------------------------
template<int K, int OPW, int ACT>
__global__ __launch_bounds__(256) void fc_kernel(
    const float* __restrict__ in, const float* __restrict__ w,
    const float* __restrict__ bias, float* __restrict__ out, const int O) {
    const int batch = blockIdx.y;
    const int t = threadIdx.x, lane = t & 63, wv = t >> 6;
    __shared__ float f[K];
    for (int j = t; j < K; j += 256) f[j] = in[batch * K + j];
    __syncthreads();
    const int o0 = blockIdx.x * (4 * OPW) + wv * OPW;
#pragma unroll
    for (int i = 0; i < OPW; i++) {
        const int o = o0 + i;
        const float* wr = w + (size_t)o * K;
        float a = 0.f;
#pragma unroll
        for (int c = lane; c < K; c += 64) a = fmaf(wr[c], f[c], a);
#pragma unroll
        for (int off = 32; off > 0; off >>= 1) a += __shfl_xor(a, off);
        if (lane == 0) {
            float v = a + bias[o];
            out[batch * O + o] = ACT ? fmaxf(v, 0.f) : v;
        }
    }
}

// fc3 (256->40) + softmax fused; one block per batch.
__global__ __launch_bounds__(256) void fc3_softmax_kernel(
    const float* __restrict__ in, const float* __restrict__ w3,
    const float* __restrict__ b3, float* __restrict__ out) {
    const int b = blockIdx.x, t = threadIdx.x, lane = t & 63, wv = t >> 6;
    __shared__ float f[256];
    __shared__ float lg[40];
    f[t] = in[b * 256 + t];
    __syncthreads();
#pragma unroll
    for (int i = 0; i < 10; i++) {
        const int o = wv * 10 + i;
        const float* wr = w3 + (size_t)o * 256;
        float a = 0.f;
#pragma unroll
        for (int c = lane; c < 256; c += 64) a = fmaf(wr[c], f[c], a);
#pragma unroll
        for (int off = 32; off > 0; off >>= 1) a += __shfl_xor(a, off);
        if (lane == 0) lg[o] = a + b3[o];
    }
    __syncthreads();
    if (t < 64) {
        float v = (t < 40) ? lg[t] : -INFINITY;
        float m = v;
#pragma unroll
        for (int off = 32; off > 0; off >>= 1) m = fmaxf(m, __shfl_xor(m, off));
        float e = (t < 40) ? expf(v - m) : 0.f;
        float s = e;
#pragma unroll
        for (int off = 32; off > 0; off >>= 1) s += __shfl_xor(s, off);
        if (t < 40) out[b * 40 + t] = e / s;
    }
}

// ---------------------------------------------------------------------------
extern "C" void kernel_launch(void* const* d_in, const int* in_sizes, int n_in,
                              void* d_out, int out_size, void* d_ws, size_t ws_size,
                              hipStream_t stream) {
    (void)in_sizes; (void)n_in; (void)out_size; (void)ws_size;
    const float* x      = (const float*)d_in[0];
    const float* sa1w0  = (const float*)d_in[1];
    const float* sa1b0  = (const float*)d_in[2];
    const float* sa1w1  = (const float*)d_in[3];
    const float* sa1b1  = (const float*)d_in[4];
    const float* sa1w2  = (const float*)d_in[5];
    const float* sa1b2  = (const float*)d_in[6];
    const float* sa2w0  = (const float*)d_in[7];
    const float* sa2b0  = (const float*)d_in[8];
    const float* sa2w1  = (const float*)d_in[9];
    const float* sa2b1  = (const float*)d_in[10];
    const float* sa2w2  = (const float*)d_in[11];
    const float* sa2b2  = (const float*)d_in[12];
    const float* sa3w0  = (const float*)d_in[13];
    const float* sa3b0  = (const float*)d_in[14];
    const float* sa3w1  = (const float*)d_in[15];
    const float* sa3b1  = (const float*)d_in[16];
    const float* sa3w2  = (const float*)d_in[17];
    const float* sa3b2  = (const float*)d_in[18];
    const float* fc1w   = (const float*)d_in[19];
    const float* fc1b   = (const float*)d_in[20];
    const float* fc2w   = (const float*)d_in[21];
    const float* fc2b   = (const float*)d_in[22];
    const float* fc3w   = (const float*)d_in[23];
    const float* fc3b   = (const float*)d_in[24];
    float* outp = (float*)d_out;

    char* ws = (char*)d_ws;
    size_t off = 0;
    auto alloc = [&](size_t bytes) {
        void* p = ws + off;
        off += (bytes + 255) & ~(size_t)255;
        return p;
    };
    float* nxyz1   = (float*)alloc((size_t)B_ * 512 * 3 * 4);
    int*   idx1    = (int*)  alloc((size_t)B_ * 512 * 32 * 4);
    short* feat1h  = (short*)alloc((size_t)B_ * 512 * 128 * 2);
    short* feat1l  = (short*)alloc((size_t)B_ * 512 * 128 * 2);
    float* nxyz2   = (float*)alloc((size_t)B_ * 128 * 3 * 4);
    int*   idx2    = (int*)  alloc((size_t)B_ * 128 * 64 * 4);
    short* a3h     = (short*)alloc((size_t)4096 * 288 * 2);
    short* a3l     = (short*)alloc((size_t)4096 * 288 * 2);
    short* h3ah    = (short*)alloc((size_t)4096 * 256 * 2);
    short* h3al    = (short*)alloc((size_t)4096 * 256 * 2);
    short* h3bh    = (short*)alloc((size_t)4096 * 512 * 2);
    short* h3bl    = (short*)alloc((size_t)4096 * 512 * 2);
    float* gfeat   = (float*)alloc((size_t)B_ * 1024 * 4);
    float* h1      = (float*)alloc((size_t)B_ * 512 * 4);
    float* h2      = (float*)alloc((size_t)B_ * 256 * 4);
    // split-bf16 weight planes
    short* w1h_s1 = (short*)alloc((size_t)64 * 64 * 2);
    short* w1l_s1 = (short*)alloc((size_t)64 * 64 * 2);
    short* w2h_s1 = (short*)alloc((size_t)128 * 64 * 2);
    short* w2l_s1 = (short*)alloc((size_t)128 * 64 * 2);
    short* w0h_s2 = (short*)alloc((size_t)128 * 160 * 2);
    short* w0l_s2 = (short*)alloc((size_t)128 * 160 * 2);
    short* w1h_s2 = (short*)alloc((size_t)128 * 128 * 2);
    short* w1l_s2 = (short*)alloc((size_t)128 * 128 * 2);
    short* w2h_s2 = (short*)alloc((size_t)256 * 128 * 2);
    short* w2l_s2 = (short*)alloc((size_t)256 * 128 * 2);
    short* w0h_s3 = (short*)alloc((size_t)256 * 288 * 2);
    short* w0l_s3 = (short*)alloc((size_t)256 * 288 * 2);
    short* w1h_s3 = (short*)alloc((size_t)512 * 256 * 2);
    short* w1l_s3 = (short*)alloc((size_t)512 * 256 * 2);
    short* w2h_s3 = (short*)alloc((size_t)1024 * 512 * 2);
    short* w2l_s3 = (short*)alloc((size_t)1024 * 512 * 2);

    // merged weight prep (one launch); entry 2 (sa2w0) uses feat-first perm
    {
        WDescs W;
        const float* srcs[8] = {sa1w1, sa1w2, sa2w0, sa2w1, sa2w2, sa3w0, sa3w1, sa3w2};
        short* dhs[8] = {w1h_s1, w2h_s1, w0h_s2, w1h_s2, w2h_s2, w0h_s3, w1h_s3, w2h_s3};
        short* dls[8] = {w1l_s1, w2l_s1, w0l_s2, w1l_s2, w2l_s2, w0l_s3, w1l_s3, w2l_s3};
        int Rs[8]  = {64, 128, 128, 128, 256, 256, 512, 1024};
        int Cs[8]  = {64, 64, 131, 128, 128, 259, 256, 512};
        int Cps[8] = {64, 64, 160, 128, 128, 288, 256, 512};
        int blk = 0;
        for (int k = 0; k < 8; k++) {
            W.d[k] = {srcs[k], dhs[k], dls[k], Rs[k], Cs[k], Cps[k], blk,
                      (k == 2) ? 1 : 0};
            blk += (Rs[k] * Cps[k] + 255) / 256;
        }
        wprep_all_kernel<<<blk, 256, 0, stream>>>(W);
    }
    // zero gfeat for the fused-maxpool atomics (0x0 == 0.0f)
    hipMemsetAsync(gfeat, 0, (size_t)B_ * 1024 * 4, stream);

    // SA1: fps1, then {ballquery1 + fps2} merged, then {sa1 + ballquery2}
    fps_kernel<4096, 512, 256><<<B_, 256, 0, stream>>>(x, nxyz1);
    bq_fps_kernel<4096, 4096, 32, 512, 512, 128>
        <<<4096 + B_, 256, 0, stream>>>(
            x, nxyz1, idx1, 0.04f, nxyz1, nxyz2);
    sa1_bq2_kernel<8192><<<8192 + 1024, 256, 0, stream>>>(
        x, nxyz1, idx1, sa1w0, sa1b0,
        w1h_s1, w1l_s1, sa1b1, w2h_s1, w2l_s1, sa1b2, feat1h, feat1l,
        nxyz2, idx2, 0.16f);
    // SA2
    sa2_mfma_kernel<<<B_ * 128, 256, 0, stream>>>(
        nxyz1, feat1h, feat1l, nxyz2, idx2,
        w0h_s2, w0l_s2, sa2b0, w1h_s2, w1l_s2, sa2b1, w2h_s2, w2l_s2, sa2b2,
        a3h, a3l);
    // SA3 (group-all): 3 MFMA GEMMs on planes; gemm3 fuses the maxpool
    mfma_gemm_kernel<1><<<dim3(2, 64), 256, 0, stream>>>(
        a3h, a3l, 288, w0h_s3, w0l_s3, sa3b0, nullptr, h3ah, h3al, 256);
    mfma_gemm_kernel<1><<<dim3(4, 64), 256, 0, stream>>>(
        h3ah, h3al, 256, w1h_s3, w1l_s3, sa3b1, nullptr, h3bh, h3bl, 512);
    mfma_gemm_kernel<2><<<dim3(8, 64), 256, 0, stream>>>(
        h3bh, h3bl, 512, w2h_s3, w2l_s3, sa3b2, gfeat, nullptr, nullptr, 1024);
    // FC head: fc1 (1024->512), fc2 (512->256), fc3+softmax
    fc_kernel<1024, 16, 1><<<dim3(8, B_), 256, 0, stream>>>(
        gfeat, fc1w, fc1b, h1, 512);
    fc_kernel<512, 16, 1><<<dim3(4, B_), 256, 0, stream>>>(
        h1, fc2w, fc2b, h2, 256);
    fc3_softmax_kernel<<<B_, 256, 0, stream>>>(h2, fc3w, fc3b, outp);
}

// Round 14
// 994.762 us; speedup vs baseline: 1.6484x; 1.0050x over previous
//
#include <hip/hip_runtime.h>
#include <math.h>

#define B_ 32
#define N_ 4096

typedef __attribute__((ext_vector_type(8))) short short8;
typedef __attribute__((ext_vector_type(4))) float f32x4;
typedef __attribute__((ext_vector_type(2))) unsigned long long u64x2;

// fp32 -> bf16 round-to-nearest-even, and split x = hi + lo (both bf16).
__device__ __forceinline__ unsigned short f2bf(float f) {
    unsigned u = __float_as_uint(f);
    unsigned r = 0x7FFFu + ((u >> 16) & 1u);
    return (unsigned short)((u + r) >> 16);
}
__device__ __forceinline__ float bf2f(unsigned short h) {
    return __uint_as_float(((unsigned)h) << 16);
}
__device__ __forceinline__ void f2bfpair(float v, short& h, short& l) {
    unsigned short hh = f2bf(v);
    h = (short)hh;
    l = (short)f2bf(v - bf2f(hh));
}

// ---------------------------------------------------------------------------
// Packed argmax: key = (float_bits(dist) << 32) | ~idx. dist >= 0 so float
// bits are monotone as unsigned; u64 max picks max dist, min idx on tie —
// bit-identical to reference first-index argmax. Keys are always > 0, so
// u64max with 0 (DPP bound_ctrl fill) is identity.
// ---------------------------------------------------------------------------
__device__ __forceinline__ unsigned long long u64max(unsigned long long a,
                                                     unsigned long long b) {
    return a > b ? a : b;
}
template<int CTRL>
__device__ __forceinline__ unsigned long long dpp_u64(unsigned long long k) {
    int lo = __builtin_amdgcn_mov_dpp((int)(unsigned)k, CTRL, 0xf, 0xf, true);
    int hi = __builtin_amdgcn_mov_dpp((int)(unsigned)(k >> 32), CTRL, 0xf, 0xf, true);
    return ((unsigned long long)(unsigned)hi << 32) | (unsigned)lo;
}
// Leader-only result in LANE 63, pure DPP (no LDS swizzle on the serial
// path): row_ror reduce within rows, then row_bcast15/31 across rows.
__device__ __forceinline__ unsigned long long wave_argmax_u64_leader(unsigned long long key) {
    key = u64max(key, dpp_u64<0x128>(key));   // row_ror:8
    key = u64max(key, dpp_u64<0x124>(key));   // row_ror:4
    key = u64max(key, dpp_u64<0x122>(key));   // row_ror:2
    key = u64max(key, dpp_u64<0x121>(key));   // row_ror:1
    key = u64max(key, dpp_u64<0x142>(key));   // row_bcast15
    key = u64max(key, dpp_u64<0x143>(key));   // row_bcast31 -> lane 63
    return key;
}

// ---------------------------------------------------------------------------
// FPS stage 1: one block per batch, exact fp32 math (index-critical).
// NT ladder measured: 128=591, 256=344, 512=363 -> NT=256. Interleaved
// ps[N][4]: coords via one broadcast ds_read_b128. Lane-63 leader posts the
// wave key; one barrier/iter; slot scan via 2x b128; t==0 streams outputs.
// ---------------------------------------------------------------------------
template<int N, int NPOINT, int NT>
__global__ __launch_bounds__(NT, 1) void fps_kernel(
    const float* __restrict__ xyz, float* __restrict__ outXyz) {
#pragma clang fp contract(off)
    const int b = blockIdx.x;
    const int t = threadIdx.x;
    constexpr int PPT = N / NT;
    constexpr int NW = (NT + 63) / 64;    // == 4
    __shared__ float ps[N][4];
    __shared__ __align__(16) unsigned long long red[2][NW];
    const float* base = xyz + (size_t)b * N * 3;
    for (int j = t; j < N; j += NT) {
        ps[j][0] = base[j * 3 + 0];
        ps[j][1] = base[j * 3 + 1];
        ps[j][2] = base[j * 3 + 2];
    }
    __syncthreads();
    float px[PPT], py[PPT], pz[PPT], mind[PPT];
    unsigned notp[PPT];
#pragma unroll
    for (int i = 0; i < PPT; i++) {
        int p = t + i * NT;
        f32x4 c4 = *(const f32x4*)&ps[p][0];
        px[i] = c4[0]; py[i] = c4[1]; pz[i] = c4[2];
        mind[i] = 1e10f;
        notp[i] = ~(unsigned)p;
    }
#pragma unroll
    for (int i = 0; i < PPT; i++)
        asm volatile("" : "+v"(px[i]), "+v"(py[i]), "+v"(pz[i]));
    float lx = ps[0][0], ly = ps[0][1], lz = ps[0][2];
    if (t == 0) {
        outXyz[(size_t)b * NPOINT * 3 + 0] = lx;
        outXyz[(size_t)b * NPOINT * 3 + 1] = ly;
        outXyz[(size_t)b * NPOINT * 3 + 2] = lz;
    }
    for (int it = 1; it < NPOINT; it++) {
        unsigned long long key = 0;
#pragma unroll
        for (int i = 0; i < PPT; i++) {
            float dx = px[i] - lx, dy = py[i] - ly, dz = pz[i] - lz;
            float t0 = dx * dx, t1 = dy * dy, t2 = dz * dz;
            float d = (t0 + t1) + t2;
            float m = fminf(mind[i], d);
            mind[i] = m;
            unsigned long long k =
                ((unsigned long long)__float_as_uint(m) << 32) | notp[i];
            key = u64max(key, k);
        }
        key = wave_argmax_u64_leader(key);
        const int par = it & 1;
        if ((t & 63) == 63) red[par][t >> 6] = key;
        __syncthreads();
        u64x2 r01 = *(const u64x2*)&red[par][0];
        u64x2 r23 = *(const u64x2*)&red[par][2];
        unsigned long long best =
            u64max(u64max(r01[0], r01[1]), u64max(r23[0], r23[1]));
        const int fi = (int)(~(unsigned)best);
        f32x4 c4 = *(const f32x4*)&ps[fi][0];
        lx = c4[0]; ly = c4[1]; lz = c4[2];
        if (t == 0) {
            outXyz[((size_t)b * NPOINT + it) * 3 + 0] = lx;
            outXyz[((size_t)b * NPOINT + it) * 3 + 1] = ly;
            outXyz[((size_t)b * NPOINT + it) * 3 + 2] = lz;
        }
    }
}

// ---------------------------------------------------------------------------
// Ball-query body: wave-per-query (ballot/mbcnt), exact fp32 math.
// ---------------------------------------------------------------------------
template<int N, int NS>
__device__ __forceinline__ void ballquery_body(
    const float* __restrict__ xyz, const float* __restrict__ newXyz,
    int* __restrict__ outIdx, int S, float r2, int qid, int lane) {
#pragma clang fp contract(off)
    const int b = qid / S;
    const float* q = newXyz + (size_t)qid * 3;
    const float qx = q[0], qy = q[1], qz = q[2];
    const float qn = (qx * qx + qy * qy) + qz * qz;
    const float* base = xyz + (size_t)b * N * 3;
    int* dst = outIdx + (size_t)qid * NS;
    int cnt = 0, first = 0;
    for (int p0 = 0; p0 < N; p0 += 64) {
        const int p = p0 + lane;
        const float x = base[p * 3 + 0];
        const float y = base[p * 3 + 1];
        const float z = base[p * 3 + 2];
        const float pn = (x * x + y * y) + z * z;
        const float dot = (qx * x + qy * y) + qz * z;
        const float sqd = (qn + pn) - 2.0f * dot;
        const unsigned long long mask = __ballot(sqd <= r2);
        if (mask) {
            if (cnt == 0) first = p0 + __ffsll((unsigned long long)mask) - 1;
            const int prefix = __builtin_amdgcn_mbcnt_hi(
                (unsigned)(mask >> 32),
                __builtin_amdgcn_mbcnt_lo((unsigned)mask, 0));
            const bool in = (mask >> lane) & 1ull;
            const int pos = cnt + prefix;
            if (in && pos < NS) dst[pos] = p;
            cnt += __popcll(mask);
            if (cnt >= NS) break;
        }
    }
    for (int i = cnt + lane; i < NS; i += 64) dst[i] = first;
}

// ---------------------------------------------------------------------------
// Merged launch: blocks [0, BQB) = ballquery1 (x -> idx1), blocks
// [BQB, BQB+B_) = fps stage 2 (nxyz1 -> nxyz2). fps2 only needs nxyz1 —
// independent of bq1 — so packing them hides fps2's 32-block serial tail.
// fps2 reduction: leader DPP chain + single shfl of the low word (fi only
// needs lo 32 bits) — one ds-swizzle round-trip instead of two.
// ---------------------------------------------------------------------------
template<int BQB, int NQ, int NS, int SQ, int NF, int NPF>
__global__ __launch_bounds__(256) void bq_fps_kernel(
    const float* __restrict__ xyzQ, const float* __restrict__ newXyzQ,
    int* __restrict__ outIdxQ, float r2,
    const float* __restrict__ xyzF, float* __restrict__ outXyzF) {
#pragma clang fp contract(off)
    const int t = threadIdx.x;
    const int lane = t & 63, wv = t >> 6;
    __shared__ float ps[NF][4];
    if (blockIdx.x < BQB) {
        ballquery_body<NQ, NS>(xyzQ, newXyzQ, outIdxQ, SQ, r2,
                               blockIdx.x * 4 + wv, lane);
        return;
    }
    // ---- fps2: single-wave serial FPS over NF points ----
    const int b = blockIdx.x - BQB;
    const float* base = xyzF + (size_t)b * NF * 3;
    for (int j = t; j < NF; j += 256) {
        ps[j][0] = base[j * 3 + 0];
        ps[j][1] = base[j * 3 + 1];
        ps[j][2] = base[j * 3 + 2];
    }
    __syncthreads();
    if (t >= 64) return;
    constexpr int PPT = NF / 64;
    float px[PPT], py[PPT], pz[PPT], mind[PPT];
    unsigned notp[PPT];
#pragma unroll
    for (int i = 0; i < PPT; i++) {
        int p = t + i * 64;
        f32x4 c4 = *(const f32x4*)&ps[p][0];
        px[i] = c4[0]; py[i] = c4[1]; pz[i] = c4[2];
        mind[i] = 1e10f;
        notp[i] = ~(unsigned)p;
    }
    float lx = ps[0][0], ly = ps[0][1], lz = ps[0][2];
    if (t == 0) {
        outXyzF[(size_t)b * NPF * 3 + 0] = lx;
        outXyzF[(size_t)b * NPF * 3 + 1] = ly;
        outXyzF[(size_t)b * NPF * 3 + 2] = lz;
    }
    for (int it = 1; it < NPF; it++) {
        unsigned long long key = 0;
#pragma unroll
        for (int i = 0; i < PPT; i++) {
            float dx = px[i] - lx, dy = py[i] - ly, dz = pz[i] - lz;
            float t0 = dx * dx, t1 = dy * dy, t2 = dz * dz;
            float d = (t0 + t1) + t2;
            float m = fminf(mind[i], d);
            mind[i] = m;
            unsigned long long k =
                ((unsigned long long)__float_as_uint(m) << 32) | notp[i];
            key = u64max(key, k);
        }
        key = wave_argmax_u64_leader(key);
        const int lo = __shfl((int)(unsigned)key, 63);
        const int fi = (int)(~(unsigned)lo);
        f32x4 c4 = *(const f32x4*)&ps[fi][0];
        lx = c4[0]; ly = c4[1]; lz = c4[2];
        if (t == 0) {
            outXyzF[((size_t)b * NPF + it) * 3 + 0] = lx;
            outXyzF[((size_t)b * NPF + it) * 3 + 1] = ly;
            outXyzF[((size_t)b * NPF + it) * 3 + 2] = lz;
        }
    }
}

// ---------------------------------------------------------------------------
// Weight prep (merged): split 8 fp32 [R][C] mats into bf16 hi/lo [R][Cp].
// perm=1 (sa2w0): column remap feat-first to match sa2's activation layout.
// Tail blocks (>= gblk0) zero gfeat for the fused-maxpool atomics.
// ---------------------------------------------------------------------------
struct WDesc { const float* src; short* dh; short* dl; int R, C, Cp, blk0, perm; };
struct WDescs { WDesc d[8]; float* gfeat; int gblk0, gtotal; };

__global__ void wprep_all_kernel(WDescs W) {
    const int blk = blockIdx.x;
    if (blk >= W.gblk0) {
        const int i = (blk - W.gblk0) * 256 + threadIdx.x;
        if (i < W.gtotal) W.gfeat[i] = 0.f;
        return;
    }
    int di = 0;
#pragma unroll
    for (int k = 1; k < 8; k++) di = (blk >= W.d[k].blk0) ? k : di;
    const WDesc D = W.d[di];
    const int i = (blk - D.blk0) * 256 + threadIdx.x;
    if (i >= D.R * D.Cp) return;
    const int r = i / D.Cp, c = i % D.Cp;
    int cs;
    if (D.perm) cs = (c < 128) ? c + 3 : (c < 131 ? c - 128 : -1);
    else        cs = (c < D.C) ? c : -1;
    float v = (cs >= 0) ? D.src[r * D.C + cs] : 0.f;
    short h, l;
    f2bfpair(v, h, l);
    D.dh[i] = h; D.dl[i] = l;
}

// ---------------------------------------------------------------------------
// MFMA helpers (verified gfx950 16x16x32 bf16 layouts).
// Split fp32 = hi+lo bf16: D += Ah*Bh + Ah*Bl + Al*Bh
// ---------------------------------------------------------------------------
template<int NT, int KS>
__device__ __forceinline__ void mfma_layer(
    const short* Aph, const short* Apl, const int sA,
    const short* __restrict__ Wph, const short* __restrict__ Wpl, const int sW,
    f32x4* acc, const int n0, const int mh, const int lr, const int lq) {
#pragma unroll
    for (int ks = 0; ks < KS; ks++) {
        const int ka = ks * 32 + lq * 8;
        short8 a_h[2], a_l[2];
#pragma unroll
        for (int mt = 0; mt < 2; mt++) {
            const int m = (mh * 2 + mt) * 16 + lr;
            a_h[mt] = *(const short8*)(Aph + m * sA + ka);
            a_l[mt] = *(const short8*)(Apl + m * sA + ka);
        }
#pragma unroll
        for (int nt = 0; nt < NT; nt++) {
            const int n = n0 + nt * 16 + lr;
            short8 b_h = *(const short8*)(Wph + (size_t)n * sW + ka);
            short8 b_l = *(const short8*)(Wpl + (size_t)n * sW + ka);
#pragma unroll
            for (int mt = 0; mt < 2; mt++) {
                f32x4 c = acc[mt * NT + nt];
                c = __builtin_amdgcn_mfma_f32_16x16x32_bf16(a_h[mt], b_h, c, 0, 0, 0);
                c = __builtin_amdgcn_mfma_f32_16x16x32_bf16(a_h[mt], b_l, c, 0, 0, 0);
                c = __builtin_amdgcn_mfma_f32_16x16x32_bf16(a_l[mt], b_h, c, 0, 0, 0);
                acc[mt * NT + nt] = c;
            }
        }
    }
}

template<int NT>
__device__ __forceinline__ void init_bias(f32x4* acc, const float* __restrict__ bias,
                                          const int n0, const int lr) {
#pragma unroll
    for (int nt = 0; nt < NT; nt++) {
        float bv = bias[n0 + nt * 16 + lr];
        f32x4 c = {bv, bv, bv, bv};
        acc[0 * NT + nt] = c;
        acc[1 * NT + nt] = c;
    }
}

template<int NT>
__device__ __forceinline__ void store_split(
    const f32x4* acc, short* Hp, short* Lp, const int stride,
    const int n0, const int mh, const int lr, const int lq) {
#pragma unroll
    for (int mt = 0; mt < 2; mt++)
#pragma unroll
        for (int nt = 0; nt < NT; nt++)
#pragma unroll
            for (int r = 0; r < 4; r++) {
                float v = fmaxf(acc[mt * NT + nt][r], 0.f);
                short h, l;
                f2bfpair(v, h, l);
                const int m = (mh * 2 + mt) * 16 + lq * 4 + r;
                const int n = n0 + nt * 16 + lr;
                Hp[m * stride + n] = h;
                Lp[m * stride + n] = l;
            }
}

// ---------------------------------------------------------------------------
// SA1 MFMA (+ merged ballquery2 tail blocks): blocks [0, SAB) run sa1;
// blocks [SAB, SAB+256) run bq2 (needs only nxyz1/nxyz2, both ready).
// ---------------------------------------------------------------------------
#define T1 72
template<int SAB>
__global__ __launch_bounds__(256) void sa1_bq2_kernel(
    const float* __restrict__ x, const float* __restrict__ nxyz1,
    const int* __restrict__ idx,
    const float* __restrict__ w0, const float* __restrict__ b0,
    const short* __restrict__ w1h, const short* __restrict__ w1l,
    const float* __restrict__ b1,
    const short* __restrict__ w2h, const short* __restrict__ w2l,
    const float* __restrict__ b2,
    short* __restrict__ feat1h, short* __restrict__ feat1l,
    const float* __restrict__ nxyz2, int* __restrict__ idx2, float r2q) {
    const int t = threadIdx.x;
    const int lane = t & 63, wv = t >> 6;
    if (blockIdx.x >= SAB) {   // ballquery2: N=512, NS=64, S=128
        ballquery_body<512, 64>(nxyz1, nxyz2, idx2, 128, r2q,
                                (blockIdx.x - SAB) * 4 + wv, lane);
        return;
    }
    const int g0 = blockIdx.x * 2;
    const int b = g0 >> 9;
    const int lr = lane & 15, lq = lane >> 4;
    const int mh = wv & 1, nh = wv >> 1;
    __shared__ float gx[64][4];
    __shared__ short H1h[64 * T1], H1l[64 * T1];
    __shared__ short H2h[64 * T1], H2l[64 * T1];
    if (t < 64) {
        int g = g0 + (t >> 5);
        int id = idx[(size_t)g * 32 + (t & 31)];
        const float* pp = x + ((size_t)b * N_ + id) * 3;
        const float* cc = nxyz1 + (size_t)g * 3;
        gx[t][0] = pp[0] - cc[0];
        gx[t][1] = pp[1] - cc[1];
        gx[t][2] = pp[2] - cc[2];
    }
    __syncthreads();
    {   // layer1 K=3 via VALU
        const int m = t >> 2, oc = (t & 3) * 16;
        float a0 = gx[m][0], a1 = gx[m][1], a2 = gx[m][2];
        short8 hv0, hv1, lv0, lv1;
#pragma unroll
        for (int i = 0; i < 16; i++) {
            int o = oc + i;
            float v = fmaf(w0[o * 3 + 0], a0,
                      fmaf(w0[o * 3 + 1], a1,
                      fmaf(w0[o * 3 + 2], a2, b0[o])));
            v = fmaxf(v, 0.f);
            short h, l;
            f2bfpair(v, h, l);
            if (i < 8) { hv0[i] = h; lv0[i] = l; }
            else       { hv1[i - 8] = h; lv1[i - 8] = l; }
        }
        *(short8*)&H1h[m * T1 + oc]     = hv0;
        *(short8*)&H1h[m * T1 + oc + 8] = hv1;
        *(short8*)&H1l[m * T1 + oc]     = lv0;
        *(short8*)&H1l[m * T1 + oc + 8] = lv1;
    }
    __syncthreads();
    {   // layer2: K=64, N=64
        f32x4 acc[4];
        init_bias<2>(acc, b1, nh * 32, lr);
        mfma_layer<2, 2>(H1h, H1l, T1, w1h, w1l, 64, acc, nh * 32, mh, lr, lq);
        store_split<2>(acc, H2h, H2l, T1, nh * 32, mh, lr, lq);
    }
    __syncthreads();
    {   // layer3: K=64, N=128 + per-group max, split output
        f32x4 acc[8];
        init_bias<4>(acc, b2, nh * 64, lr);
        mfma_layer<4, 2>(H2h, H2l, T1, w2h, w2l, 64, acc, nh * 64, mh, lr, lq);
#pragma unroll
        for (int nt = 0; nt < 4; nt++) {
            float v = 0.f;
#pragma unroll
            for (int mt = 0; mt < 2; mt++)
#pragma unroll
                for (int r = 0; r < 4; r++)
                    v = fmaxf(v, acc[mt * 4 + nt][r]);
            v = fmaxf(v, __shfl_xor(v, 16));
            v = fmaxf(v, __shfl_xor(v, 32));
            if (lane < 16) {
                short h, l;
                f2bfpair(v, h, l);
                size_t o = (size_t)(g0 + mh) * 128 + nh * 64 + nt * 16 + lane;
                feat1h[o] = h;
                feat1l[o] = l;
            }
        }
    }
}

// ---------------------------------------------------------------------------
// SA2 MFMA: consumes feat1 planes (feat-first layout), outputs a3 planes.
// ---------------------------------------------------------------------------
#define S1 168
#define S2 136
__global__ __launch_bounds__(256) void sa2_mfma_kernel(
    const float* __restrict__ xyz1,
    const short* __restrict__ feat1h, const short* __restrict__ feat1l,
    const float* __restrict__ newXyz, const int* __restrict__ idx,
    const short* __restrict__ w0h, const short* __restrict__ w0l,
    const float* __restrict__ b0,
    const short* __restrict__ w1h, const short* __restrict__ w1l,
    const float* __restrict__ b1,
    const short* __restrict__ w2h, const short* __restrict__ w2l,
    const float* __restrict__ b2,
    short* __restrict__ a3h, short* __restrict__ a3l) {
    const int g = blockIdx.x;
    const int b = g >> 7;
    const int t = threadIdx.x;
    const int lane = t & 63, wv = t >> 6;
    const int lr = lane & 15, lq = lane >> 4;
    const int mh = wv & 1, nh = wv >> 1;
    __shared__ short Ah[64 * S1], Al[64 * S1];
    __shared__ short Hh[64 * S2], Hl[64 * S2];
    __shared__ float pmax[2][256];
    __shared__ int ids[64];
    if (t < 64) ids[t] = idx[(size_t)g * 64 + t];
    __syncthreads();
    {   // gather: feat cols 0..127 via b128 plane copies; xyz at 128..130
        const int m = t >> 2, q = t & 3;
        const int id = ids[m];
        const size_t frow = ((size_t)b * 512 + id) * 128;
#pragma unroll
        for (int c8 = 0; c8 < 4; c8++) {
            const int k = q * 32 + c8 * 8;
            *(short8*)&Ah[m * S1 + k] = *(const short8*)(feat1h + frow + k);
            *(short8*)&Al[m * S1 + k] = *(const short8*)(feat1l + frow + k);
        }
        if (t < 64) {
            const int id2 = ids[t];
            short8 zz = {0, 0, 0, 0, 0, 0, 0, 0};
            *(short8*)&Ah[t * S1 + 128] = zz;
            *(short8*)&Ah[t * S1 + 136] = zz;
            *(short8*)&Ah[t * S1 + 144] = zz;
            *(short8*)&Ah[t * S1 + 152] = zz;
            *(short8*)&Al[t * S1 + 128] = zz;
            *(short8*)&Al[t * S1 + 136] = zz;
            *(short8*)&Al[t * S1 + 144] = zz;
            *(short8*)&Al[t * S1 + 152] = zz;
            const float* prow = xyz1 + ((size_t)b * 512 + id2) * 3;
            const float* crow = newXyz + (size_t)g * 3;
#pragma unroll
            for (int c = 0; c < 3; c++) {
                short h, l;
                f2bfpair(prow[c] - crow[c], h, l);
                Ah[t * S1 + 128 + c] = h;
                Al[t * S1 + 128 + c] = l;
            }
        }
    }
    __syncthreads();
    {   // layer1: K=160, N=128
        f32x4 acc[8];
        init_bias<4>(acc, b0, nh * 64, lr);
        mfma_layer<4, 5>(Ah, Al, S1, w0h, w0l, 160, acc, nh * 64, mh, lr, lq);
        store_split<4>(acc, Hh, Hl, S2, nh * 64, mh, lr, lq);
    }
    __syncthreads();
    {   // layer2: K=128, N=128
        f32x4 acc[8];
        init_bias<4>(acc, b1, nh * 64, lr);
        mfma_layer<4, 4>(Hh, Hl, S2, w1h, w1l, 128, acc, nh * 64, mh, lr, lq);
        store_split<4>(acc, Ah, Al, S2, nh * 64, mh, lr, lq);
    }
    __syncthreads();
    {   // layer3: K=128, N=256 + max over 64 rows
        f32x4 acc[16];
        init_bias<8>(acc, b2, nh * 128, lr);
        mfma_layer<8, 4>(Ah, Al, S2, w2h, w2l, 128, acc, nh * 128, mh, lr, lq);
#pragma unroll
        for (int nt = 0; nt < 8; nt++) {
            float v = 0.f;
#pragma unroll
            for (int mt = 0; mt < 2; mt++)
#pragma unroll
                for (int r = 0; r < 4; r++)
                    v = fmaxf(v, acc[mt * 8 + nt][r]);
            v = fmaxf(v, __shfl_xor(v, 16));
            v = fmaxf(v, __shfl_xor(v, 32));
            if (lane < 16) pmax[mh][nh * 128 + nt * 16 + lane] = v;
        }
    }
    __syncthreads();
    {   // write a3 row g: col 3+t = feat, cols 0..2 xyz, 259..287 zero
        float v = fmaxf(pmax[0][t], pmax[1][t]);
        short h, l;
        f2bfpair(v, h, l);
        a3h[(size_t)g * 288 + 3 + t] = h;
        a3l[(size_t)g * 288 + 3 + t] = l;
        if (t < 3) {
            f2bfpair(newXyz[(size_t)g * 3 + t], h, l);
            a3h[(size_t)g * 288 + t] = h;
            a3l[(size_t)g * 288 + t] = l;
        }
        if (t >= 227) {
            a3h[(size_t)g * 288 + t + 32] = 0;
            a3l[(size_t)g * 288 + t + 32] = 0;
        }
    }
}

// ---------------------------------------------------------------------------
// MFMA GEMM: A pre-split planes [M][Kp]; weights pre-split planes [N][Kp].
// OUT_MODE 1: relu + split-plane output.
// OUT_MODE 2: relu + per-column block max + atomicMax into gfeat (fused
//   maxpool; values >=0 so int-compare on float bits is order-correct).
// ---------------------------------------------------------------------------
template<int OUT_MODE>
__global__ __launch_bounds__(256) void mfma_gemm_kernel(
    const short* __restrict__ Agh, const short* __restrict__ Agl, const int Kp,
    const short* __restrict__ Wh, const short* __restrict__ Wl,
    const float* __restrict__ bias,
    float* __restrict__ outF, short* __restrict__ outH,
    short* __restrict__ outL, const int N) {
    const int t = threadIdx.x;
    const int lane = t & 63, wv = t >> 6;
    const int lr = lane & 15, lq = lane >> 4;
    const int mh = wv & 1, nh = wv >> 1;
    const int m0 = blockIdx.y * 64;
    const int n0 = blockIdx.x * 128 + nh * 64;
    __shared__ short Ah[64 * 40], Al[64 * 40];
    f32x4 acc[8];
#pragma unroll
    for (int nt = 0; nt < 4; nt++) {
        float bv = bias[n0 + nt * 16 + lr];
        f32x4 c = {bv, bv, bv, bv};
        acc[nt] = c; acc[4 + nt] = c;
    }
    const int srow = t >> 2, sk = (t & 3) * 8;
    for (int kt = 0; kt < Kp; kt += 32) {
        {   // stage A chunk: pure b128 copies (no conversion)
            const size_t src = (size_t)(m0 + srow) * Kp + kt + sk;
            *(short8*)&Ah[srow * 40 + sk] = *(const short8*)(Agh + src);
            *(short8*)&Al[srow * 40 + sk] = *(const short8*)(Agl + src);
        }
        __syncthreads();
        short8 a_h[2], a_l[2];
#pragma unroll
        for (int mt = 0; mt < 2; mt++) {
            const int m = mh * 32 + mt * 16 + lr;
            a_h[mt] = *(const short8*)&Ah[m * 40 + lq * 8];
            a_l[mt] = *(const short8*)&Al[m * 40 + lq * 8];
        }
#pragma unroll
        for (int nt = 0; nt < 4; nt++) {
            const int n = n0 + nt * 16 + lr;
            short8 b_h = *(const short8*)(Wh + (size_t)n * Kp + kt + lq * 8);
            short8 b_l = *(const short8*)(Wl + (size_t)n * Kp + kt + lq * 8);
#pragma unroll
            for (int mt = 0; mt < 2; mt++) {
                f32x4 c = acc[mt * 4 + nt];
                c = __builtin_amdgcn_mfma_f32_16x16x32_bf16(a_h[mt], b_h, c, 0, 0, 0);
                c = __builtin_amdgcn_mfma_f32_16x16x32_bf16(a_h[mt], b_l, c, 0, 0, 0);
                c = __builtin_amdgcn_mfma_f32_16x16x32_bf16(a_l[mt], b_h, c, 0, 0, 0);
                acc[mt * 4 + nt] = c;
            }
        }
        __syncthreads();
    }
    if (OUT_MODE == 2) {
        const int batch = blockIdx.y >> 1;
#pragma unroll
        for (int nt = 0; nt < 4; nt++) {
            float v = 0.f;
#pragma unroll
            for (int mt = 0; mt < 2; mt++)
#pragma unroll
                for (int r = 0; r < 4; r++)
                    v = fmaxf(v, acc[mt * 4 + nt][r]);
            v = fmaxf(v, __shfl_xor(v, 16));
            v = fmaxf(v, __shfl_xor(v, 32));
            if (lane < 16)
                atomicMax((int*)&outF[(size_t)batch * N + n0 + nt * 16 + lane],
                          __float_as_int(v));
        }
        return;
    }
#pragma unroll
    for (int mt = 0; mt < 2; mt++)
#pragma unroll
        for (int nt = 0; nt < 4; nt++)
#pragma unroll
            for (int r = 0; r < 4; r++) {
                const int m = m0 + mh * 32 + mt * 16 + lq * 4 + r;
                const int n = n0 + nt * 16 + lr;
                float v = fmaxf(acc[mt * 4 + nt][r], 0.f);
                short h, l;
                f2bfpair(v, h, l);
                outH[(size_t)m * N + n] = h;
                outL[(size_t)m * N + n] = l;
            }
}

// ---------------------------------------------------------------------------
// FC layer: grid (O/(4*OPW), B), block 256.
// ---------------------------------------------------------------------------
template<int K, int OPW, int ACT>
__global__ __launch_bounds__(256) void fc_kernel(
    const float* __restrict__ in, const float* __restrict__ w,
    const float* __restrict__ bias, float* __restrict__ out, const int O) {
    const int batch = blockIdx.y;
    const int t = threadIdx.x, lane = t & 63, wv = t >> 6;
    __shared__ float f[K];
    for (int j = t; j < K; j += 256) f[j] = in[batch * K + j];
    __syncthreads();
    const int o0 = blockIdx.x * (4 * OPW) + wv * OPW;
#pragma unroll
    for (int i = 0; i < OPW; i++) {
        const int o = o0 + i;
        const float* wr = w + (size_t)o * K;
        float a = 0.f;
#pragma unroll
        for (int c = lane; c < K; c += 64) a = fmaf(wr[c], f[c], a);
#pragma unroll
        for (int off = 32; off > 0; off >>= 1) a += __shfl_xor(a, off);
        if (lane == 0) {
            float v = a + bias[o];
            out[batch * O + o] = ACT ? fmaxf(v, 0.f) : v;
        }
    }
}

// fc3 (256->40) + softmax fused; one block per batch.
__global__ __launch_bounds__(256) void fc3_softmax_kernel(
    const float* __restrict__ in, const float* __restrict__ w3,
    const float* __restrict__ b3, float* __restrict__ out) {
    const int b = blockIdx.x, t = threadIdx.x, lane = t & 63, wv = t >> 6;
    __shared__ float f[256];
    __shared__ float lg[40];
    f[t] = in[b * 256 + t];
    __syncthreads();
#pragma unroll
    for (int i = 0; i < 10; i++) {
        const int o = wv * 10 + i;
        const float* wr = w3 + (size_t)o * 256;
        float a = 0.f;
#pragma unroll
        for (int c = lane; c < 256; c += 64) a = fmaf(wr[c], f[c], a);
#pragma unroll
        for (int off = 32; off > 0; off >>= 1) a += __shfl_xor(a, off);
        if (lane == 0) lg[o] = a + b3[o];
    }
    __syncthreads();
    if (t < 64) {
        float v = (t < 40) ? lg[t] : -INFINITY;
        float m = v;
#pragma unroll
        for (int off = 32; off > 0; off >>= 1) m = fmaxf(m, __shfl_xor(m, off));
        float e = (t < 40) ? expf(v - m) : 0.f;
        float s = e;
#pragma unroll
        for (int off = 32; off > 0; off >>= 1) s += __shfl_xor(s, off);
        if (t < 40) out[b * 40 + t] = e / s;
    }
}

// ---------------------------------------------------------------------------
extern "C" void kernel_launch(void* const* d_in, const int* in_sizes, int n_in,
                              void* d_out, int out_size, void* d_ws, size_t ws_size,
                              hipStream_t stream) {
    (void)in_sizes; (void)n_in; (void)out_size; (void)ws_size;
    const float* x      = (const float*)d_in[0];
    const float* sa1w0  = (const float*)d_in[1];
    const float* sa1b0  = (const float*)d_in[2];
    const float* sa1w1  = (const float*)d_in[3];
    const float* sa1b1  = (const float*)d_in[4];
    const float* sa1w2  = (const float*)d_in[5];
    const float* sa1b2  = (const float*)d_in[6];
    const float* sa2w0  = (const float*)d_in[7];
    const float* sa2b0  = (const float*)d_in[8];
    const float* sa2w1  = (const float*)d_in[9];
    const float* sa2b1  = (const float*)d_in[10];
    const float* sa2w2  = (const float*)d_in[11];
    const float* sa2b2  = (const float*)d_in[12];
    const float* sa3w0  = (const float*)d_in[13];
    const float* sa3b0  = (const float*)d_in[14];
    const float* sa3w1  = (const float*)d_in[15];
    const float* sa3b1  = (const float*)d_in[16];
    const float* sa3w2  = (const float*)d_in[17];
    const float* sa3b2  = (const float*)d_in[18];
    const float* fc1w   = (const float*)d_in[19];
    const float* fc1b   = (const float*)d_in[20];
    const float* fc2w   = (const float*)d_in[21];
    const float* fc2b   = (const float*)d_in[22];
    const float* fc3w   = (const float*)d_in[23];
    const float* fc3b   = (const float*)d_in[24];
    float* outp = (float*)d_out;

    char* ws = (char*)d_ws;
    size_t off = 0;
    auto alloc = [&](size_t bytes) {
        void* p = ws + off;
        off += (bytes + 255) & ~(size_t)255;
        return p;
    };
    float* nxyz1   = (float*)alloc((size_t)B_ * 512 * 3 * 4);
    int*   idx1    = (int*)  alloc((size_t)B_ * 512 * 32 * 4);
    short* feat1h  = (short*)alloc((size_t)B_ * 512 * 128 * 2);
    short* feat1l  = (short*)alloc((size_t)B_ * 512 * 128 * 2);
    float* nxyz2   = (float*)alloc((size_t)B_ * 128 * 3 * 4);
    int*   idx2    = (int*)  alloc((size_t)B_ * 128 * 64 * 4);
    short* a3h     = (short*)alloc((size_t)4096 * 288 * 2);
    short* a3l     = (short*)alloc((size_t)4096 * 288 * 2);
    short* h3ah    = (short*)alloc((size_t)4096 * 256 * 2);
    short* h3al    = (short*)alloc((size_t)4096 * 256 * 2);
    short* h3bh    = (short*)alloc((size_t)4096 * 512 * 2);
    short* h3bl    = (short*)alloc((size_t)4096 * 512 * 2);
    float* gfeat   = (float*)alloc((size_t)B_ * 1024 * 4);
    float* h1      = (float*)alloc((size_t)B_ * 512 * 4);
    float* h2      = (float*)alloc((size_t)B_ * 256 * 4);
    // split-bf16 weight planes
    short* w1h_s1 = (short*)alloc((size_t)64 * 64 * 2);
    short* w1l_s1 = (short*)alloc((size_t)64 * 64 * 2);
    short* w2h_s1 = (short*)alloc((size_t)128 * 64 * 2);
    short* w2l_s1 = (short*)alloc((size_t)128 * 64 * 2);
    short* w0h_s2 = (short*)alloc((size_t)128 * 160 * 2);
    short* w0l_s2 = (short*)alloc((size_t)128 * 160 * 2);
    short* w1h_s2 = (short*)alloc((size_t)128 * 128 * 2);
    short* w1l_s2 = (short*)alloc((size_t)128 * 128 * 2);
    short* w2h_s2 = (short*)alloc((size_t)256 * 128 * 2);
    short* w2l_s2 = (short*)alloc((size_t)256 * 128 * 2);
    short* w0h_s3 = (short*)alloc((size_t)256 * 288 * 2);
    short* w0l_s3 = (short*)alloc((size_t)256 * 288 * 2);
    short* w1h_s3 = (short*)alloc((size_t)512 * 256 * 2);
    short* w1l_s3 = (short*)alloc((size_t)512 * 256 * 2);
    short* w2h_s3 = (short*)alloc((size_t)1024 * 512 * 2);
    short* w2l_s3 = (short*)alloc((size_t)1024 * 512 * 2);

    // merged weight prep + gfeat zero-init (one launch); entry 2 (sa2w0)
    // uses feat-first perm
    {
        WDescs W;
        const float* srcs[8] = {sa1w1, sa1w2, sa2w0, sa2w1, sa2w2, sa3w0, sa3w1, sa3w2};
        short* dhs[8] = {w1h_s1, w2h_s1, w0h_s2, w1h_s2, w2h_s2, w0h_s3, w1h_s3, w2h_s3};
        short* dls[8] = {w1l_s1, w2l_s1, w0l_s2, w1l_s2, w2l_s2, w0l_s3, w1l_s3, w2l_s3};
        int Rs[8]  = {64, 128, 128, 128, 256, 256, 512, 1024};
        int Cs[8]  = {64, 64, 131, 128, 128, 259, 256, 512};
        int Cps[8] = {64, 64, 160, 128, 128, 288, 256, 512};
        int blk = 0;
        for (int k = 0; k < 8; k++) {
            W.d[k] = {srcs[k], dhs[k], dls[k], Rs[k], Cs[k], Cps[k], blk,
                      (k == 2) ? 1 : 0};
            blk += (Rs[k] * Cps[k] + 255) / 256;
        }
        W.gfeat = gfeat;
        W.gblk0 = blk;
        W.gtotal = B_ * 1024;
        blk += (B_ * 1024 + 255) / 256;
        wprep_all_kernel<<<blk, 256, 0, stream>>>(W);
    }

    // SA1: fps1, then {ballquery1 + fps2} merged, then {sa1 + ballquery2}
    fps_kernel<4096, 512, 256><<<B_, 256, 0, stream>>>(x, nxyz1);
    bq_fps_kernel<4096, 4096, 32, 512, 512, 128>
        <<<4096 + B_, 256, 0, stream>>>(
            x, nxyz1, idx1, 0.04f, nxyz1, nxyz2);
    sa1_bq2_kernel<8192><<<8192 + 1024, 256, 0, stream>>>(
        x, nxyz1, idx1, sa1w0, sa1b0,
        w1h_s1, w1l_s1, sa1b1, w2h_s1, w2l_s1, sa1b2, feat1h, feat1l,
        nxyz2, idx2, 0.16f);
    // SA2
    sa2_mfma_kernel<<<B_ * 128, 256, 0, stream>>>(
        nxyz1, feat1h, feat1l, nxyz2, idx2,
        w0h_s2, w0l_s2, sa2b0, w1h_s2, w1l_s2, sa2b1, w2h_s2, w2l_s2, sa2b2,
        a3h, a3l);
    // SA3 (group-all): 3 MFMA GEMMs on planes; gemm3 fuses the maxpool
    mfma_gemm_kernel<1><<<dim3(2, 64), 256, 0, stream>>>(
        a3h, a3l, 288, w0h_s3, w0l_s3, sa3b0, nullptr, h3ah, h3al, 256);
    mfma_gemm_kernel<1><<<dim3(4, 64), 256, 0, stream>>>(
        h3ah, h3al, 256, w1h_s3, w1l_s3, sa3b1, nullptr, h3bh, h3bl, 512);
    mfma_gemm_kernel<2><<<dim3(8, 64), 256, 0, stream>>>(
        h3bh, h3bl, 512, w2h_s3, w2l_s3, sa3b2, gfeat, nullptr, nullptr, 1024);
    // FC head: fc1 (1024->512), fc2 (512->256), fc3+softmax
    fc_kernel<1024, 16, 1><<<dim3(8, B_), 256, 0, stream>>>(
        gfeat, fc1w, fc1b, h1, 512);
    fc_kernel<512, 16, 1><<<dim3(4, B_), 256, 0, stream>>>(
        h1, fc2w, fc2b, h2, 256);
    fc3_softmax_kernel<<<B_, 256, 0, stream>>>(h2, fc3w, fc3b, outp);
}